// Round 2
// baseline (3936.342 us; speedup 1.0000x reference)
//
#include <hip/hip_runtime.h>
#include <math.h>

#define NN 64
#define LDW 68      // padded LDS stride (float4-aligned)
#define LCH 32      // mean-scan chunk length
#define N1CAP 144   // smoother-cov tail length (closed-form, parallel)
#define N0MAX 144   // forward Riccati cap
#define EPS_HARD 1e-5f
#define EPS_GATE 5e-2f
#define STALL_WIN 5
#define STALL_IMP 0.75f

struct KP {
  const float *Y, *A, *b, *Q, *H, *c, *R, *pm0, *P0;
  float *out_mean, *out_cov, *out_ll;
  int *meta; float *metaF;
  float *fm;
  float *AT, *HT, *HA, *Hb;
  float *Fss, *Kss, *Sinvss, *Css, *CsTss, *pPss, *sPss, *Fpow, *Cpow32, *Cpow31, *uss;
  float *Pw2, *Pw4, *Pw8, *Pw16, *Pw64, *Pw128;
  float *u_chunk, *startstate, *ub_chunk, *endstate;
  float *ld_pref, *u_pref;
  double *llbuf;
  float *E0g;
  // scan-element powers E^(2^j), j=0..7: A, C, J, L=chol(J)
  float *EA, *EC, *EJ, *EL;
  float *astat, *dstat;
  float *fP, *pP, *Kp, *Sinvp, *Fp, *Cp, *CsTp;
  int N0cap, T, NC;
};

union F4 { float4 v; float f[4]; };

// ---------- helpers, templated on block size NT ----------

template<int NT>
__device__ __forceinline__ void g2l(float* W, const float* G) {
  for (int e = threadIdx.x*4; e < 4096; e += NT*4) {
    float4 v = *(const float4*)(G + e);
    *(float4*)(W + (e>>6)*LDW + (e&63)) = v;
  }
  __syncthreads();
}
template<int NT>
__device__ __forceinline__ void l2g(float* G, const float* W) {
  for (int e = threadIdx.x*4; e < 4096; e += NT*4)
    *(float4*)(G + e) = *(const float4*)(W + (e>>6)*LDW + (e&63));
  __syncthreads();
}
template<int NT>
__device__ __forceinline__ void l2g_T(float* G, const float* W) {
  for (int e = threadIdx.x; e < 4096; e += NT)
    G[e] = W[(e&63)*LDW + (e>>6)];
  __syncthreads();
}
template<int NT>
__device__ __forceinline__ void copyW(float* D, const float* S) {
  for (int e = threadIdx.x*4; e < 4096; e += NT*4) {
    int base = (e>>6)*LDW + (e&63);
    *(float4*)(D + base) = *(const float4*)(S + base);
  }
  __syncthreads();
}
template<int NT>
__device__ __forceinline__ void set_id(float* W) {
  for (int e = threadIdx.x; e < 4096; e += NT)
    W[(e>>6)*LDW + (e&63)] = ((e>>6) == (e&63)) ? 1.f : 0.f;
  __syncthreads();
}
template<int NT>
__device__ __forceinline__ void sub_lg(float* D, const float* Wa, const float* G) {
  for (int e = threadIdx.x*4; e < 4096; e += NT*4) {
    int base = (e>>6)*LDW + (e&63);
    F4 a, g; a.v = *(const float4*)(Wa + base); g.v = *(const float4*)(G + e);
    F4 o; o.f[0]=a.f[0]-g.f[0]; o.f[1]=a.f[1]-g.f[1]; o.f[2]=a.f[2]-g.f[2]; o.f[3]=a.f[3]-g.f[3];
    *(float4*)(D + base) = o.v;
  }
  __syncthreads();
}
// G_dst = G_src - W
template<int NT>
__device__ __forceinline__ void rsub_store(float* Gd, const float* Gs, const float* W) {
  for (int e = threadIdx.x*4; e < 4096; e += NT*4) {
    int base = (e>>6)*LDW + (e&63);
    F4 a, g; a.v = *(const float4*)(W + base); g.v = *(const float4*)(Gs + e);
    F4 o; o.f[0]=g.f[0]-a.f[0]; o.f[1]=g.f[1]-a.f[1]; o.f[2]=g.f[2]-a.f[2]; o.f[3]=g.f[3]-a.f[3];
    *(float4*)(Gd + e) = o.v;
  }
  __syncthreads();
}

// 2-value max reduction (256 threads)
__device__ __forceinline__ void redpair(float& ma, float& md, float* red) {
  #pragma unroll
  for (int off = 32; off; off >>= 1) {
    ma = fmaxf(ma, __shfl_xor(ma, off, 64));
    md = fmaxf(md, __shfl_xor(md, off, 64));
  }
  const int w = threadIdx.x >> 6;
  if ((threadIdx.x & 63) == 0) { red[w] = ma; red[4 + w] = md; }
  __syncthreads();
  ma = fmaxf(fmaxf(red[0], red[1]), fmaxf(red[2], red[3]));
  md = fmaxf(fmaxf(red[4], red[5]), fmaxf(red[6], red[7]));
  __syncthreads();
}

// D(=LDS,stride LDD) = [ADD +/-] op(A)*op(B).
// NT=256: 4x4 tiles; NT=512: 2x4 tiles (identical per-cell FP order).
template<int TRANSA, int TRANSB, int MODE, int LDD, int NT>
__device__ __forceinline__ void mm(float* __restrict__ D,
    const float* __restrict__ A, int lda,
    const float* __restrict__ B, int ldb,
    const float* __restrict__ ADD, int ldadd)
{
  constexpr int RI = (NT == 512) ? 2 : 4;
  const int tid = threadIdx.x;
  const int i0 = (tid >> 4) * RI, j0 = (tid & 15) << 2;
  float acc[RI][4] = {};
  for (int k0 = 0; k0 < NN; k0 += 4) {
    float bvf[4][4];
    #pragma unroll
    for (int u = 0; u < 4; ++u) {
      F4 bv;
      bv.v = TRANSB ? *(const float4*)(B + (j0+u)*ldb + k0)
                    : *(const float4*)(B + (k0+u)*ldb + j0);
      #pragma unroll
      for (int q = 0; q < 4; ++q) bvf[u][q] = bv.f[q];
    }
    float avf[4][RI];   // [kk][di]
    if constexpr (TRANSA) {
      #pragma unroll
      for (int u = 0; u < 4; ++u) {
        if constexpr (RI == 4) {
          F4 av; av.v = *(const float4*)(A + (k0+u)*lda + i0);
          #pragma unroll
          for (int di = 0; di < RI; ++di) avf[u][di] = av.f[di];
        } else {
          float2 av2 = *(const float2*)(A + (k0+u)*lda + i0);
          avf[u][0] = av2.x; avf[u][1] = av2.y;
        }
      }
    } else {
      #pragma unroll
      for (int di = 0; di < RI; ++di) {
        F4 av; av.v = *(const float4*)(A + (i0+di)*lda + k0);
        #pragma unroll
        for (int kk = 0; kk < 4; ++kk) avf[kk][di] = av.f[kk];
      }
    }
    #pragma unroll
    for (int kk = 0; kk < 4; ++kk) {
      #pragma unroll
      for (int di = 0; di < RI; ++di) {
        float a = avf[kk][di];
        #pragma unroll
        for (int dj = 0; dj < 4; ++dj) {
          float bb = TRANSB ? bvf[dj][kk] : bvf[kk][dj];
          acc[di][dj] += a * bb;
        }
      }
    }
  }
  #pragma unroll
  for (int di = 0; di < RI; ++di) {
    if (MODE == 0 && (LDD & 3) == 0) {
      F4 o;
      #pragma unroll
      for (int dj = 0; dj < 4; ++dj) o.f[dj] = acc[di][dj];
      *(float4*)(D + (i0+di)*LDD + j0) = o.v;
    } else {
      #pragma unroll
      for (int dj = 0; dj < 4; ++dj) {
        float v = acc[di][dj];
        if (MODE == 1) v = ADD[(i0+di)*ldadd + j0+dj] + v;
        if (MODE == 2) v = ADD[(i0+di)*ldadd + j0+dj] - v;
        D[(i0+di)*LDD + j0+dj] = v;
      }
    }
  }
  __syncthreads();
}

// panel-16 Cholesky in stride-LDW buffer. upper zeroed.
template<bool WANTLOG, int NT>
__device__ __forceinline__ void chol68(float* __restrict__ Sm, float* part, float* invd) {
  constexpr int CPT = 1024 / NT;   // trailing-update cols per thread
  const int tid = threadIdx.x;
  const int lane = tid & 63;
  #pragma unroll
  for (int p = 0; p < 4; ++p) {
    const int j0 = p * 16;
    if (p > 0) {
      const int i = tid & 63;
      const int jq = (tid >> 6) * CPT;
      float acc[CPT] = {};
      for (int kb = 0; kb < j0; kb += 4) {
        F4 av; av.v = *(const float4*)(Sm + i*LDW + kb);
        #pragma unroll
        for (int q = 0; q < CPT; ++q) {
          F4 bv; bv.v = *(const float4*)(Sm + (j0 + jq + q)*LDW + kb);
          acc[q] += av.f[0]*bv.f[0] + av.f[1]*bv.f[1] + av.f[2]*bv.f[2] + av.f[3]*bv.f[3];
        }
      }
      #pragma unroll
      for (int q = 0; q < CPT; ++q)
        Sm[i*LDW + j0 + jq + q] -= acc[q];
      __syncthreads();
    }
    if (tid < 64) {
      float t[16];
      F4 tv;
      #pragma unroll
      for (int q4 = 0; q4 < 4; ++q4) {
        tv.v = *(const float4*)(Sm + lane*LDW + j0 + 4*q4);
        t[4*q4] = tv.f[0]; t[4*q4+1] = tv.f[1]; t[4*q4+2] = tv.f[2]; t[4*q4+3] = tv.f[3];
      }
      #pragma unroll
      for (int jj = 0; jj < 16; ++jj) {
        float acc = t[jj];
        #pragma unroll
        for (int kk = 0; kk < jj; ++kk)
          acc -= __shfl(t[kk], j0 + jj, 64) * t[kk];
        float piv = __shfl(acc, j0 + jj, 64);
        float sq = sqrtf(fmaxf(piv, 1e-30f));
        float inv = 1.0f / sq;
        if (lane == j0 + jj) {
          t[jj] = sq;
          invd[j0 + jj] = inv;
          if (WANTLOG) part[j0 + jj] = logf(sq);
        } else {
          t[jj] = (lane > j0 + jj) ? acc * inv : 0.f;
        }
      }
      #pragma unroll
      for (int q4 = 0; q4 < 4; ++q4) {
        tv.f[0] = t[4*q4]; tv.f[1] = t[4*q4+1]; tv.f[2] = t[4*q4+2]; tv.f[3] = t[4*q4+3];
        *(float4*)(Sm + lane*LDW + j0 + 4*q4) = tv.v;
      }
    }
    __syncthreads();
  }
}

// forward triangular solve DST <- L^-1 op(SRC); threads 0..255 active.
template<int TR, int NT>
__device__ __forceinline__ void tri_fwd_ld(const float* __restrict__ L,
                                           const float* __restrict__ invd,
                                           const float* __restrict__ SRC, int lds,
                                           float* __restrict__ DST, int ldd) {
  if (threadIdx.x < 256) {
    const int col = threadIdx.x >> 2, p = threadIdx.x & 3;
    const int gbase = (threadIdx.x & 63) & ~3;
    float xr[16];
    #pragma unroll
    for (int u = 0; u < 16; ++u)
      xr[u] = TR ? SRC[col*lds + (4*u+p)] : SRC[(4*u+p)*lds + col];
    #pragma unroll
    for (int i = 0; i < NN; ++i) {
      const int idx = i >> 2, ow = i & 3;
      float yi = xr[idx] * invd[i];
      yi = __shfl(yi, gbase + ow, 64);
      if (p == ow) xr[idx] = yi;
      else if (p > ow) xr[idx] -= L[(4*idx+p)*LDW + i] * yi;
      #pragma unroll
      for (int u = idx+1; u < 16; ++u)
        xr[u] -= L[(4*u+p)*LDW + i] * yi;
    }
    #pragma unroll
    for (int u = 0; u < 16; ++u) DST[(4*u+p)*ldd + col] = xr[u];
  }
  __syncthreads();
}

// backward triangular solve DST <- L^-T SRC; threads 0..255 active.
template<int NT>
__device__ __forceinline__ void tri_bwd_ld(const float* __restrict__ L,
                                           const float* __restrict__ invd,
                                           const float* __restrict__ SRC, int lds,
                                           float* __restrict__ DST, int ldd) {
  if (threadIdx.x < 256) {
    const int col = threadIdx.x >> 2, p = threadIdx.x & 3;
    const int gbase = (threadIdx.x & 63) & ~3;
    float xr[16];
    #pragma unroll
    for (int u = 0; u < 16; ++u) xr[u] = SRC[(4*u+p)*lds + col];
    #pragma unroll
    for (int i = NN-1; i >= 0; --i) {
      const int idx = i >> 2, ow = i & 3;
      float zi = xr[idx] * invd[i];
      zi = __shfl(zi, gbase + ow, 64);
      if (p == ow) xr[idx] = zi;
      else if (p < ow) xr[idx] -= L[i*LDW + 4*idx+p] * zi;
      #pragma unroll
      for (int u = 0; u < idx; ++u)
        xr[u] -= L[i*LDW + 4*u+p] * zi;
    }
    #pragma unroll
    for (int u = 0; u < 16; ++u) DST[(4*u+p)*ldd + col] = xr[u];
  }
  __syncthreads();
}

// two-sided triangular solve: DST <- L^-T L^-1 SRC (strides LDW); threads 0..255.
template<int NT>
__device__ __forceinline__ void tri_solve2(const float* __restrict__ L,
                                           const float* __restrict__ invd,
                                           const float* __restrict__ SRC,
                                           float* __restrict__ DST) {
  if (threadIdx.x < 256) {
    const int col = threadIdx.x >> 2, p = threadIdx.x & 3;
    const int gbase = (threadIdx.x & 63) & ~3;
    float xr[16];
    #pragma unroll
    for (int u = 0; u < 16; ++u) xr[u] = SRC[(4*u+p)*LDW + col];
    #pragma unroll
    for (int i = 0; i < NN; ++i) {
      const int idx = i >> 2, ow = i & 3;
      float yi = xr[idx] * invd[i];
      yi = __shfl(yi, gbase + ow, 64);
      if (p == ow) xr[idx] = yi;
      else if (p > ow) xr[idx] -= L[(4*idx+p)*LDW + i] * yi;
      #pragma unroll
      for (int u = idx+1; u < 16; ++u)
        xr[u] -= L[(4*u+p)*LDW + i] * yi;
    }
    #pragma unroll
    for (int i = NN-1; i >= 0; --i) {
      const int idx = i >> 2, ow = i & 3;
      float zi = xr[idx] * invd[i];
      zi = __shfl(zi, gbase + ow, 64);
      if (p == ow) xr[idx] = zi;
      else if (p < ow) xr[idx] -= L[i*LDW + 4*idx+p] * zi;
      #pragma unroll
      for (int u = 0; u < idx; ++u)
        xr[u] -= L[i*LDW + 4*u+p] * zi;
    }
    #pragma unroll
    for (int u = 0; u < 16; ++u) DST[(4*u+p)*LDW + col] = xr[u];
  }
  __syncthreads();
}

// y(LDS 64-vec) = Mg(64x64 row-major)*x + addv (nullable). 256 threads.
__device__ __forceinline__ void matvec256(float* __restrict__ y, const float* __restrict__ Mg,
    const float* __restrict__ x, const float* __restrict__ addv, float* __restrict__ red) {
  const int r = threadIdx.x & 63, p = threadIdx.x >> 6;
  const int kb = p*16;
  float s = 0.f;
  #pragma unroll
  for (int q = 0; q < 4; ++q) {
    F4 mv; mv.v = *(const float4*)(Mg + r*NN + kb + q*4);
    s += mv.f[0]*x[kb+q*4] + mv.f[1]*x[kb+q*4+1] + mv.f[2]*x[kb+q*4+2] + mv.f[3]*x[kb+q*4+3];
  }
  red[p*64 + r] = s;
  __syncthreads();
  if (threadIdx.x < 64) {
    float t = red[r] + red[64+r] + red[128+r] + red[192+r];
    y[r] = t + (addv ? addv[r] : 0.f);
  }
  __syncthreads();
}

// ---------- kernels ----------

__global__ __launch_bounds__(256) void k0(KP P) {
  __shared__ __align__(16) float W0[LDW*NN];
  const int tid = threadIdx.x;
  for (int e = tid; e < 4096; e += 256) {
    int r = e>>6, cc = e&63;
    P.AT[e] = P.A[cc*64+r];
    P.HT[e] = P.H[cc*64+r];
  }
  if (tid < 64) {
    float s = 0.f;
    for (int k = 0; k < 64; ++k) s += P.H[tid*64+k]*P.b[k];
    P.Hb[tid] = s;
  }
  __syncthreads();
  mm<0,0,0,LDW,256>(W0, P.H, NN, P.A, NN, nullptr, 0);   // HA = H*A
  l2g<256>(P.HA, W0);
}

// ---------------------------------------------------------------------------
// Parallel Riccati prefix via associative filtering elements (Sarkka-style).
//   E = (At, Ct, Jt); combine via Woodbury (see round-1 notes).
// kA: leaf + fP0 + 7 doublings, with A/C/L LDS-resident across doublings
// (512 threads = 8 waves for latency hiding; no global round-trips).
// ---------------------------------------------------------------------------

__global__ __launch_bounds__(512) void kA(KP P) {
  constexpr int NT = 512;
  __shared__ __align__(16) float LA[LDW*NN], LC[LDW*NN], LL[LDW*NN];
  __shared__ __align__(16) float W0[LDW*NN], W1[LDW*NN], W2[LDW*NN], W3[LDW*NN];
  __shared__ float part[64], iv1[64], iv2[64];
  const int tid = threadIdx.x;
  // ---- generic element E^1 (into LA/LC/LL + global level 0) ----
  mm<0,0,0,LDW,NT>(W0, P.H, NN, P.Q, NN, nullptr, 0);      // T = H Q
  mm<0,1,1,LDW,NT>(W1, W0, LDW, P.H, NN, P.R, NN);         // St = T H^T + R
  chol68<false,NT>(W1, part, iv1);                          // Ls
  tri_fwd_ld<0,NT>(W1, iv1, P.HA, NN, W2, LDW);            // U = Ls^-1 HA
  mm<1,0,0,LDW,NT>(W3, W2, LDW, W2, LDW, nullptr, 0);      // Jt = U^T U
  l2g<NT>(P.EJ, W3);
  copyW<NT>(LL, W3);
  chol68<false,NT>(LL, part, iv2);                          // Lt = chol(Jt)
  l2g<NT>(P.EL, LL);
  tri_bwd_ld<NT>(W1, iv1, W2, LDW, W2, LDW);               // X = St^-1 HA
  mm<1,0,2,LDW,NT>(LA, W0, LDW, W2, LDW, P.A, NN);         // At = A - (HQ)^T X
  l2g<NT>(P.EA, LA);
  tri_fwd_ld<0,NT>(W1, iv1, W0, LDW, W2, LDW);             // V = Ls^-1 T
  mm<1,0,2,LDW,NT>(LC, W2, LDW, W2, LDW, P.Q, NN);         // Ct = Q - V^T V
  l2g<NT>(P.EC, LC);
  // ---- a1: fP0 ----
  mm<0,0,0,LDW,NT>(W0, P.H, NN, P.P0, NN, nullptr, 0);     // HP0
  mm<0,1,1,LDW,NT>(W1, W0, LDW, P.H, NN, P.R, NN);         // S0
  chol68<false,NT>(W1, part, iv1);
  tri_fwd_ld<0,NT>(W1, iv1, W0, LDW, W2, LDW);             // U0
  mm<1,0,2,LDW,NT>(W3, W2, LDW, W2, LDW, P.P0, NN);        // fP0
  l2g<NT>(P.fP, W3);
  // ---- doublings: E^(2^(j+1)) = E^(2^j) ∘ E^(2^j), state in LA/LC/LL ----
  for (int j = 0; j < 7 && (2 << j) <= P.N0cap - 1; ++j) {
    mm<0,0,0,LDW,NT>(W0, LC, LDW, LL, LDW, nullptr, 0);    // Pm = C L
    mm<1,0,0,LDW,NT>(W1, LL, LDW, W0, LDW, nullptr, 0);    // W = L^T Pm
    if (tid < 64) W1[tid*LDW + tid] += 1.f;
    __syncthreads();
    chol68<false,NT>(W1, part, iv1);                        // Lw = chol(I+W)
    mm<1,0,0,LDW,NT>(W2, LL, LDW, LA, LDW, nullptr, 0);    // T1 = L^T A
    tri_fwd_ld<0,NT>(W1, iv1, W2, LDW, W2, LDW);           // T2f = Lw^-1 T1
    mm<1,0,1,LDW,NT>(W3, W2, LDW, W2, LDW, P.EJ + j*4096, NN); // Jn = T2f^T T2f + J
    l2g<NT>(P.EJ + (j+1)*4096, W3);
    copyW<NT>(LL, W3);                                      // LL free (Pm,T1 done)
    chol68<false,NT>(LL, part, iv2);                        // Ln
    l2g<NT>(P.EL + (j+1)*4096, LL);
    tri_bwd_ld<NT>(W1, iv1, W2, LDW, W2, LDW);             // T2 = (I+W)^-1 T1
    mm<0,0,2,LDW,NT>(W3, W0, LDW, W2, LDW, LA, LDW);       // ZA = A - Pm T2
    mm<0,0,0,LDW,NT>(W2, LA, LDW, W3, LDW, nullptr, 0);    // An = A ZA (stash W2)
    tri_fwd_ld<1,NT>(W1, iv1, W0, LDW, W3, LDW);           // T5 = Lw^-1 Pm^T
    mm<1,0,2,LDW,NT>(W0, W3, LDW, W3, LDW, LC, LDW);       // ZC = C - T5^T T5
    mm<0,0,0,LDW,NT>(W3, LA, LDW, W0, LDW, nullptr, 0);    // T7 = A ZC
    mm<0,1,1,LDW,NT>(W0, W3, LDW, LA, LDW, LC, LDW);       // Cn = T7 A^T + C
    copyW<NT>(LC, W0); l2g<NT>(P.EC + (j+1)*4096, LC);
    copyW<NT>(LA, W2); l2g<NT>(P.EA + (j+1)*4096, LA);
  }
}

// block t: fP_t = C of a1 ∘ E^t, combining set bits of t (ascending).
__global__ __launch_bounds__(512) void kB(KP P) {
  constexpr int NT = 512;
  __shared__ __align__(16) float Wc[LDW*NN], W0[LDW*NN], W1[LDW*NN], W2[LDW*NN];
  __shared__ float part[64], ivw[64];
  const int t = blockIdx.x;
  if (t == 0) return;                       // fP0 written by kA
  g2l<NT>(Wc, P.fP);                        // acc.C = fP0
  int rem = t;
  for (int j = 0; rem; ++j, rem >>= 1) {
    if (!(rem & 1)) continue;
    const float* Ag = P.EA + j*4096;
    const float* Cg = P.EC + j*4096;
    const float* Lg = P.EL + j*4096;
    mm<0,0,0,LDW,NT>(W0, Wc, LDW, Lg, NN, nullptr, 0);     // Pm = C L
    mm<1,0,0,LDW,NT>(W1, Lg, NN, W0, LDW, nullptr, 0);     // W = L^T Pm
    if (threadIdx.x < 64) W1[threadIdx.x*LDW + threadIdx.x] += 1.f;
    __syncthreads();
    chol68<false,NT>(W1, part, ivw);                        // Lw
    tri_fwd_ld<1,NT>(W1, ivw, W0, LDW, W2, LDW);           // T5 = Lw^-1 Pm^T
    mm<1,0,2,LDW,NT>(W1, W2, LDW, W2, LDW, Wc, LDW);       // ZC = C - T5^T T5
    mm<0,0,0,LDW,NT>(W0, Ag, NN, W1, LDW, nullptr, 0);     // T7 = A ZC
    mm<0,1,1,LDW,NT>(Wc, W0, LDW, Ag, NN, Cg, NN);         // C' = T7 A^T + C
  }
  l2g<NT>(P.fP + (size_t)t*4096, Wc);
}

// per-t maxabs + maxdiff of fP (parallel, 256 threads)
__global__ __launch_bounds__(256) void kC(KP P) {
  __shared__ float red[16];
  const int t = blockIdx.x;
  const float* cur = P.fP + (size_t)t*4096;
  const float* prv = P.fP + (size_t)(t > 0 ? t-1 : 0)*4096;
  float a = 0.f, d = 0.f;
  for (int e = threadIdx.x*4; e < 4096; e += 1024) {
    F4 v, pv; v.v = *(const float4*)(cur + e); pv.v = *(const float4*)(prv + e);
    #pragma unroll
    for (int q = 0; q < 4; ++q) {
      a = fmaxf(a, fabsf(v.f[q]));
      d = fmaxf(d, fabsf(v.f[q] - pv.f[q]));
    }
  }
  redpair(a, d, red);
  if (threadIdx.x == 0) { P.astat[t] = a; P.dstat[t] = (t > 0) ? d : 0.f; }
}

// replicate the original stall/convergence selection of N0
__global__ __launch_bounds__(256) void kN(KP P) {
  __shared__ float as_[N0MAX], ds_[N0MAX];
  const int cap = P.N0cap;
  for (int i = threadIdx.x; i < cap; i += 256) { as_[i] = P.astat[i]; ds_[i] = P.dstat[i]; }
  __syncthreads();
  if (threadIdx.x == 0) {
    float mabs = 1e-20f, dref = 1e30f;
    int tref = 0, N0 = cap;
    bool conv = false;
    for (int t = 0; t < cap; ++t) {
      mabs = fmaxf(mabs, as_[t]);
      if (t > 0) {
        float d = ds_[t];
        if (d <= EPS_HARD*mabs) { N0 = t+1; conv = true; }
        if (d < STALL_IMP*dref) { dref = d; tref = t; }
        else if (t - tref >= STALL_WIN && t >= 12 && d < EPS_GATE*mabs) { N0 = t+1; conv = true; }
      }
      if (conv) break;
    }
    P.meta[0] = N0; P.metaF[1] = mabs;
  }
}

// pP_t for t in [0, cap]: pP_0 = P0; pP_t = A fP_{t-1} A^T + Q  (parallel)
__global__ __launch_bounds__(512) void kP(KP P) {
  constexpr int NT = 512;
  __shared__ __align__(16) float W0[LDW*NN], W1[LDW*NN];
  const int t = blockIdx.x;
  if (t == 0) {
    for (int e = threadIdx.x*4; e < 4096; e += NT*4)
      *(float4*)(P.pP + e) = *(const float4*)(P.P0 + e);
    return;
  }
  g2l<NT>(W0, P.fP + (size_t)(t-1)*4096);
  mm<0,0,0,LDW,NT>(W1, P.A, NN, W0, LDW, nullptr, 0);
  mm<0,0,1,LDW,NT>(W0, W1, LDW, P.AT, NN, P.Q, NN);
  l2g<NT>(P.pP + (size_t)t*4096, W0);
}

// steady-state derived quantities + Stein solve
__global__ __launch_bounds__(512) void k1ss(KP P) {
  constexpr int NT = 512;
  __shared__ __align__(16) float W0[LDW*NN], W1[LDW*NN], W2[LDW*NN], CH[LDW*NN];
  __shared__ float part[64], invd[64];
  const int tid = threadIdx.x;
  const int N0 = P.meta[0];
  const float* fPssG = P.fP + (size_t)(N0-1)*4096;
  g2l<NT>(CH, fPssG);                                          // fP_ss
  mm<0,0,0,LDW,NT>(W1, P.A, NN, CH, LDW, nullptr, 0);          // A*fP_ss
  mm<0,0,1,LDW,NT>(W0, W1, LDW, P.AT, NN, P.Q, NN);            // pP_ss
  l2g<NT>(P.pPss, W0);
  mm<0,0,0,LDW,NT>(W1, P.H, NN, W0, LDW, nullptr, 0);          // HP
  mm<0,0,1,LDW,NT>(CH, W1, LDW, P.HT, NN, P.R, NN);            // S
  chol68<true,NT>(CH, part, invd);
  if (tid == 0) { float s=0.f; for (int j=0;j<64;++j) s += part[j]; P.metaF[0] = s; }
  tri_solve2<NT>(CH, invd, W1, W1);                            // X
  l2g_T<NT>(P.Kss, W1);                                        // K_ss = X^T
  if (tid < 64) {
    float s = P.b[tid];
    for (int k = 0; k < 64; ++k) s -= W1[k*LDW + tid]*P.Hb[k];
    P.uss[tid] = s;                                            // u_ss = (I-KH) b
  }
  __syncthreads();
  set_id<NT>(W0); tri_solve2<NT>(CH, invd, W0, W0);            // Sinv
  l2g<NT>(P.Sinvss, W0);
  mm<1,0,2,LDW,NT>(W0, W1, LDW, P.HA, NN, P.A, NN);            // F_ss
  l2g<NT>(P.Fss, W0);
  // C_ss = (pP_ss^{-1} A fP_ss)^T
  g2l<NT>(W0, fPssG);
  mm<0,0,0,LDW,NT>(W1, P.A, NN, W0, LDW, nullptr, 0);          // AF
  g2l<NT>(CH, P.pPss);
  chol68<false,NT>(CH, part, invd);
  tri_solve2<NT>(CH, invd, W1, W1);                            // X2 = C^T
  l2g<NT>(P.CsTss, W1);
  l2g_T<NT>(P.Css, W1);
  // C powers
  g2l<NT>(W0, P.Css);
  mm<0,0,0,LDW,NT>(W1, W0, LDW, W0, LDW, nullptr, 0); l2g<NT>(P.Pw2,  W1);
  mm<0,0,0,LDW,NT>(W0, W1, LDW, W1, LDW, nullptr, 0); l2g<NT>(P.Pw4,  W0);
  mm<0,0,0,LDW,NT>(W1, W0, LDW, W0, LDW, nullptr, 0); l2g<NT>(P.Pw8,  W1);
  mm<0,0,0,LDW,NT>(W0, W1, LDW, W1, LDW, nullptr, 0); l2g<NT>(P.Pw16, W0);  // C^16
  mm<0,0,0,LDW,NT>(W1, W0, LDW, W0, LDW, nullptr, 0); l2g<NT>(P.Cpow32, W1);
  mm<0,0,0,LDW,NT>(W2, W1, LDW, W1, LDW, nullptr, 0); l2g<NT>(P.Pw64, W2);
  mm<0,0,0,LDW,NT>(CH, W2, LDW, W2, LDW, nullptr, 0); l2g<NT>(P.Pw128, CH);
  mm<0,0,0,LDW,NT>(W1, W0, LDW, P.Pw8, NN, nullptr, 0);        // C^24
  mm<0,0,0,LDW,NT>(W0, W1, LDW, P.Pw4, NN, nullptr, 0);        // C^28
  mm<0,0,0,LDW,NT>(W1, W0, LDW, P.Pw2, NN, nullptr, 0);        // C^30
  mm<0,0,0,LDW,NT>(W0, W1, LDW, P.Css, NN, nullptr, 0);        // C^31
  l2g<NT>(P.Cpow31, W0);
  // F^32
  g2l<NT>(W0, P.Fss);
  mm<0,0,0,LDW,NT>(W1, W0, LDW, W0, LDW, nullptr, 0);
  mm<0,0,0,LDW,NT>(W0, W1, LDW, W1, LDW, nullptr, 0);
  mm<0,0,0,LDW,NT>(W1, W0, LDW, W0, LDW, nullptr, 0);
  mm<0,0,0,LDW,NT>(W0, W1, LDW, W1, LDW, nullptr, 0);
  mm<0,0,0,LDW,NT>(W1, W0, LDW, W0, LDW, nullptr, 0);
  l2g<NT>(P.Fpow, W1);
  // ---- Stein solve ----
  g2l<NT>(W1, P.Css);                                          // M
  g2l<NT>(W2, P.CsTss);                                        // M'
  g2l<NT>(W0, P.pPss);
  mm<0,0,0,LDW,NT>(CH, W1, LDW, W0, LDW, nullptr, 0);          // C*pPss
  mm<0,0,2,LDW,NT>(W0, CH, LDW, W2, LDW, fPssG, NN);           // X = fPss - (C pPss) C'
  for (int it = 0; it < 7; ++it) {
    mm<0,0,0,LDW,NT>(CH, W1, LDW, W0, LDW, nullptr, 0);        // M*X
    mm<0,0,1,LDW,NT>(W0, CH, LDW, W2, LDW, W0, LDW);           // X += (M X) M'
    mm<0,0,0,LDW,NT>(CH, W1, LDW, W1, LDW, nullptr, 0);        // M^2
    copyW<NT>(W1, CH);
    mm<0,0,0,LDW,NT>(CH, W2, LDW, W2, LDW, nullptr, 0);        // (M')^2
    copyW<NT>(W2, CH);
  }
  l2g<NT>(P.sPss, W0);
  rsub_store<NT>(P.E0g, fPssG, W0);                            // E0 = fPss - sPss
}

// parallel closed-form tail: sP_{T-1-k} = sPss + C^k E0 C'^k
__global__ __launch_bounds__(512) void k1d(KP P) {
  constexpr int NT = 512;
  __shared__ __align__(16) float W0[LDW*NN], W1[LDW*NN], W2[LDW*NN];
  const int k = blockIdx.x;
  float* dst = P.out_cov + (size_t)(P.T-1-k)*4096;
  if (k == 0) {
    const float* src = P.fP + (size_t)(P.meta[0]-1)*4096;
    for (int e = threadIdx.x*4; e < 4096; e += NT*4)
      *(float4*)(dst+e) = *(const float4*)(src+e);
    return;
  }
  const float* pw[8] = {P.Css, P.Pw2, P.Pw4, P.Pw8, P.Pw16, P.Cpow32, P.Pw64, P.Pw128};
  int b = __ffs(k) - 1;
  g2l<NT>(W1, pw[b]);
  float* cur = W1; float* oth = W0;
  for (int j = b+1; j < 8; ++j) {
    if ((k >> j) & 1) {
      mm<0,0,0,LDW,NT>(oth, pw[j], NN, cur, LDW, nullptr, 0);
      float* tmp = cur; cur = oth; oth = tmp;
    }
  }
  mm<0,0,0,LDW,NT>(W2, cur, LDW, P.E0g, NN, nullptr, 0);       // M*E0
  mm<0,1,1,LDW,NT>(oth, W2, LDW, cur, LDW, P.sPss, NN);        // + (M E0) M^T + sPss
  l2g<NT>(dst, oth);
}

// parallel per-prefix-t derived quantities (+ per-t logdet)
__global__ __launch_bounds__(512) void k1b(KP P) {
  constexpr int NT = 512;
  __shared__ __align__(16) float W0[LDW*NN], W1[LDW*NN], CH[LDW*NN];
  __shared__ float part[64], invd[64];
  const int t = blockIdx.x;
  if (t >= P.meta[0]) return;
  g2l<NT>(W0, P.pP + (size_t)t*4096);
  mm<0,0,0,LDW,NT>(W1, P.H, NN, W0, LDW, nullptr, 0);          // HP
  mm<0,0,1,LDW,NT>(CH, W1, LDW, P.HT, NN, P.R, NN);            // S
  chol68<true,NT>(CH, part, invd);
  if (threadIdx.x == 0) { float s=0.f; for (int j=0;j<64;++j) s += part[j]; P.ld_pref[t] = s; }
  tri_solve2<NT>(CH, invd, W1, W1);                            // X
  l2g_T<NT>(P.Kp + (size_t)t*4096, W1);
  if (threadIdx.x < 64) {
    float s = P.b[threadIdx.x];
    for (int k = 0; k < 64; ++k) s -= W1[k*LDW + threadIdx.x]*P.Hb[k];
    P.u_pref[t*64 + threadIdx.x] = s;
  }
  __syncthreads();
  set_id<NT>(W0); tri_solve2<NT>(CH, invd, W0, W0);            // Sinv
  l2g<NT>(P.Sinvp + (size_t)t*4096, W0);
  mm<1,0,2,LDW,NT>(W0, W1, LDW, P.HA, NN, P.A, NN);            // F_t
  l2g<NT>(P.Fp + (size_t)t*4096, W0);
  // C_t
  g2l<NT>(W0, P.fP + (size_t)t*4096);
  mm<0,0,0,LDW,NT>(W1, P.A, NN, W0, LDW, nullptr, 0);          // AF
  g2l<NT>(CH, P.pP + (size_t)(t+1)*4096);
  chol68<false,NT>(CH, part, invd);
  tri_solve2<NT>(CH, invd, W1, W1);                            // X2
  l2g<NT>(P.CsTp + (size_t)t*4096, W1);
  l2g_T<NT>(P.Cp + (size_t)t*4096, W1);
}

// sequential backward smoothed-cov prefix
__global__ __launch_bounds__(512) void k1c(KP P) {
  constexpr int NT = 512;
  __shared__ __align__(16) float W0[LDW*NN], W1[LDW*NN];
  const int N0 = P.meta[0];
  float* cur = W0; float* oth = W1;
  g2l<NT>(cur, P.sPss);
  for (int t = N0-1; t >= 0; --t) {
    sub_lg<NT>(oth, cur, P.pP + (size_t)(t+1)*4096);
    mm<0,0,0,LDW,NT>(cur, P.Cp + (size_t)t*4096, NN, oth, LDW, nullptr, 0);
    mm<0,0,1,LDW,NT>(oth, cur, LDW, P.CsTp + (size_t)t*4096, NN, P.fP + (size_t)t*4096, NN);
    l2g<NT>(P.out_cov + (size_t)t*4096, oth);
    float* tmp = cur; cur = oth; oth = tmp;
  }
}

// fill steady middle region of smoothed covs
__global__ __launch_bounds__(256) void k4(KP P) {
  const int t = blockIdx.x;
  if (t < P.meta[0] || t >= P.T - N1CAP) return;
  float* dst = P.out_cov + (size_t)t*4096;
  for (int e = threadIdx.x*4; e < 4096; e += 1024)
    *(float4*)(dst+e) = *(const float4*)(P.sPss + e);
}

// forward mean scan: local pass (steady chunks, zero init)
__global__ __launch_bounds__(256) void k2a(KP P) {
  __shared__ float xv[64], gv[64], ty[64], red[256];
  const int c = blockIdx.x;
  const int N0 = P.meta[0];
  const int PB = (N0 + LCH - 1)/LCH;
  if (c < PB) return;
  const int tid = threadIdx.x;
  if (tid < 64) xv[tid] = 0.f;
  __syncthreads();
  for (int s = 0; s < LCH; ++s) {
    int t = c*LCH + s;
    if (tid < 64) ty[tid] = P.Y[(size_t)t*64+tid] - P.c[tid];
    __syncthreads();
    matvec256(gv, P.Kss, ty, P.uss, red);
    matvec256(xv, P.Fss, xv, gv, red);
  }
  if (tid < 64) P.u_chunk[c*64+tid] = xv[tid];
}

// forward mean scan: sequential prefix + chunk carries
__global__ __launch_bounds__(256) void k2b(KP P) {
  __shared__ float xv[64], gv[64], ty[64], hp[64], red[256];
  const int tid = threadIdx.x;
  const int N0 = P.meta[0];
  const int PB = (N0 + LCH - 1)/LCH;
  const int PE = PB*LCH;
  if (tid < 64) xv[tid] = P.pm0[tid];
  __syncthreads();
  matvec256(hp, P.H, xv, nullptr, red);
  if (tid < 64) ty[tid] = P.Y[tid] - hp[tid] - P.c[tid];
  __syncthreads();
  matvec256(xv, P.Kp, ty, xv, red);            // fm0 = pm0 + K0*r0
  if (tid < 64) P.fm[tid] = xv[tid];
  __syncthreads();
  for (int t = 1; t < PE; ++t) {
    const float* Kt = (t < N0) ? P.Kp + (size_t)t*4096 : P.Kss;
    const float* Ft = (t < N0) ? P.Fp + (size_t)t*4096 : P.Fss;
    const float* ut = (t < N0) ? P.u_pref + t*64 : P.uss;
    if (tid < 64) ty[tid] = P.Y[(size_t)t*64+tid] - P.c[tid];
    __syncthreads();
    matvec256(gv, Kt, ty, ut, red);
    matvec256(xv, Ft, xv, gv, red);
    if (tid < 64) P.fm[(size_t)t*64+tid] = xv[tid];
    __syncthreads();
  }
  for (int c = PB; c < P.NC; ++c) {
    if (tid < 64) P.startstate[c*64+tid] = xv[tid];
    __syncthreads();
    matvec256(xv, P.Fpow, xv, P.u_chunk + c*64, red);
  }
}

// forward mean scan: replay steady chunks with true start states
__global__ __launch_bounds__(256) void k2c(KP P) {
  __shared__ float xv[64], gv[64], ty[64], red[256];
  const int c = blockIdx.x;
  const int N0 = P.meta[0];
  const int PB = (N0 + LCH - 1)/LCH;
  if (c < PB) return;
  const int tid = threadIdx.x;
  if (tid < 64) xv[tid] = P.startstate[c*64+tid];
  __syncthreads();
  for (int s = 0; s < LCH; ++s) {
    int t = c*LCH + s;
    if (tid < 64) ty[tid] = P.Y[(size_t)t*64+tid] - P.c[tid];
    __syncthreads();
    matvec256(gv, P.Kss, ty, P.uss, red);
    matvec256(xv, P.Fss, xv, gv, red);
    if (tid < 64) P.fm[(size_t)t*64+tid] = xv[tid];
    __syncthreads();
  }
}

// log-likelihood terms (one wave per t) -> llbuf
__global__ __launch_bounds__(64) void k5(KP P) {
  __shared__ float pmv[64], rv[64];
  const int t = blockIdx.x;
  const int N0 = P.meta[0];
  const int r = threadIdx.x;
  float pm;
  if (t == 0) {
    pm = P.pm0[r];
  } else {
    pmv[r] = P.fm[(size_t)(t-1)*64 + r];
    __syncthreads();
    float s = P.b[r];
    const float* Ar = P.A + r*64;
    for (int k = 0; k < 64; k += 4)
      s += Ar[k]*pmv[k] + Ar[k+1]*pmv[k+1] + Ar[k+2]*pmv[k+2] + Ar[k+3]*pmv[k+3];
    pm = s;
    __syncthreads();
  }
  pmv[r] = pm; __syncthreads();
  float rr = P.Y[(size_t)t*64 + r] - P.c[r];
  const float* Hr = P.H + r*64;
  for (int k = 0; k < 64; ++k) rr -= Hr[k]*pmv[k];
  rv[r] = rr; __syncthreads();
  const float* Sv = ((t < N0) ? P.Sinvp + (size_t)t*4096 : P.Sinvss) + r*64;
  float wv = 0.f;
  for (int k = 0; k < 64; ++k) wv += Sv[k]*rv[k];
  float qq = rr*wv;
  #pragma unroll
  for (int off = 32; off > 0; off >>= 1) qq += __shfl_xor(qq, off, 64);
  if (r == 0) {
    float ldt = (t < N0) ? P.ld_pref[t] : P.metaF[0];
    P.llbuf[t] = -58.8120661250990555 - (double)ldt - 0.5*(double)qq;
  }
}

// backward mean scan: local pass
__global__ __launch_bounds__(256) void k3a(KP P) {
  __shared__ float sv[64], wv[64], vv[64], fmv[64], red[256];
  const int c = blockIdx.x;
  const int N0 = P.meta[0];
  const int PB = (N0 + LCH - 1)/LCH;
  if (c < PB) return;
  const int tid = threadIdx.x;
  if (tid < 64) sv[tid] = 0.f;
  __syncthreads();
  int hi = (c == P.NC-1) ? P.T-2 : c*LCH + LCH - 1;
  for (int t = hi; t >= c*LCH; --t) {
    if (tid < 64) fmv[tid] = P.fm[(size_t)t*64+tid];
    __syncthreads();
    matvec256(wv, P.A, fmv, P.b, red);
    if (tid < 64) vv[tid] = sv[tid] - wv[tid];
    __syncthreads();
    matvec256(sv, P.Css, vv, fmv, red);
  }
  if (tid < 64) P.ub_chunk[c*64+tid] = sv[tid];
}

// backward mean scan: carries + sequential prefix
__global__ __launch_bounds__(256) void k3b(KP P) {
  __shared__ float sv[64], wv[64], vv[64], fmv[64], red[256];
  const int tid = threadIdx.x;
  const int N0 = P.meta[0];
  const int PB = (N0 + LCH - 1)/LCH;
  const int PE = PB*LCH;
  if (tid < 64) {
    float v = P.fm[(size_t)(P.T-1)*64+tid];
    sv[tid] = v;
    P.out_mean[(size_t)(P.T-1)*64+tid] = v;
  }
  __syncthreads();
  for (int c = P.NC-1; c >= PB; --c) {
    if (tid < 64) P.endstate[c*64+tid] = sv[tid];
    __syncthreads();
    matvec256(sv, (c == P.NC-1) ? P.Cpow31 : P.Cpow32, sv, P.ub_chunk + c*64, red);
  }
  for (int t = PE-1; t >= 0; --t) {
    const float* Ct = (t < N0) ? P.Cp + (size_t)t*4096 : P.Css;
    if (tid < 64) fmv[tid] = P.fm[(size_t)t*64+tid];
    __syncthreads();
    matvec256(wv, P.A, fmv, P.b, red);
    if (tid < 64) vv[tid] = sv[tid] - wv[tid];
    __syncthreads();
    matvec256(sv, Ct, vv, fmv, red);
    if (tid < 64) P.out_mean[(size_t)t*64+tid] = sv[tid];
    __syncthreads();
  }
}

// backward mean scan: replay steady chunks
__global__ __launch_bounds__(256) void k3c(KP P) {
  __shared__ float sv[64], wv[64], vv[64], fmv[64], red[256];
  const int c = blockIdx.x;
  const int N0 = P.meta[0];
  const int PB = (N0 + LCH - 1)/LCH;
  if (c < PB) return;
  const int tid = threadIdx.x;
  if (tid < 64) sv[tid] = P.endstate[c*64+tid];
  __syncthreads();
  int hi = (c == P.NC-1) ? P.T-2 : c*LCH + LCH - 1;
  for (int t = hi; t >= c*LCH; --t) {
    if (tid < 64) fmv[tid] = P.fm[(size_t)t*64+tid];
    __syncthreads();
    matvec256(wv, P.A, fmv, P.b, red);
    if (tid < 64) vv[tid] = sv[tid] - wv[tid];
    __syncthreads();
    matvec256(sv, P.Css, vv, fmv, red);
    if (tid < 64) P.out_mean[(size_t)t*64+tid] = sv[tid];
    __syncthreads();
  }
}

// reduce per-t ll terms
__global__ __launch_bounds__(256) void k6(KP P) {
  __shared__ double rd[256];
  double s = 0.0;
  for (int t = threadIdx.x; t < P.T; t += 256) s += P.llbuf[t];
  rd[threadIdx.x] = s; __syncthreads();
  #pragma unroll
  for (int off = 128; off > 0; off >>= 1) {
    if ((int)threadIdx.x < off) rd[threadIdx.x] += rd[threadIdx.x + off];
    __syncthreads();
  }
  if (threadIdx.x == 0) P.out_ll[0] = (float)rd[0];
}

// ---------- host ----------

extern "C" void kernel_launch(void* const* d_in, const int* in_sizes, int n_in,
                              void* d_out, int out_size, void* d_ws, size_t ws_size,
                              hipStream_t stream) {
  (void)n_in; (void)out_size;
  KP P;
  P.Y   = (const float*)d_in[0];
  P.A   = (const float*)d_in[1];
  P.b   = (const float*)d_in[2];
  P.Q   = (const float*)d_in[3];
  P.H   = (const float*)d_in[4];
  P.c   = (const float*)d_in[5];
  P.R   = (const float*)d_in[6];
  P.pm0 = (const float*)d_in[7];
  P.P0  = (const float*)d_in[8];
  const int T = in_sizes[0] / 64;
  const int NC = T / LCH;
  P.T = T; P.NC = NC;

  float* out = (float*)d_out;
  P.out_mean = out;
  P.out_cov  = out + (size_t)T*64;
  P.out_ll   = out + (size_t)T*64 + (size_t)T*4096;

  float* w = (float*)d_ws;
  size_t off = 0;
  auto alloc = [&](size_t n) { float* p = w + off; off += n; return p; };
  P.meta   = (int*)alloc(8);
  P.metaF  = alloc(8);
  P.llbuf  = (double*)alloc((size_t)2*T);
  P.fm     = alloc((size_t)T*64);
  P.AT = alloc(4096); P.HT = alloc(4096); P.HA = alloc(4096); P.Hb = alloc(64);
  P.Fss = alloc(4096); P.Kss = alloc(4096); P.Sinvss = alloc(4096);
  P.Css = alloc(4096); P.CsTss = alloc(4096); P.pPss = alloc(4096); P.sPss = alloc(4096);
  P.Fpow = alloc(4096); P.Cpow32 = alloc(4096); P.Cpow31 = alloc(4096); P.uss = alloc(64);
  P.Pw2 = alloc(4096); P.Pw4 = alloc(4096); P.Pw8 = alloc(4096); P.Pw16 = alloc(4096);
  P.Pw64 = alloc(4096); P.Pw128 = alloc(4096);
  P.u_chunk = alloc((size_t)NC*64); P.startstate = alloc((size_t)NC*64);
  P.ub_chunk = alloc((size_t)NC*64); P.endstate = alloc((size_t)NC*64);
  P.E0g = alloc(4096);
  P.EA = alloc((size_t)8*4096); P.EC = alloc((size_t)8*4096);
  P.EJ = alloc((size_t)8*4096); P.EL = alloc((size_t)8*4096);
  P.astat = alloc(256); P.dstat = alloc(256);
  // prefix arrays sized by remaining workspace
  size_t fixed = off;
  size_t per_t = 7*4096 + 64 + 1;
  size_t total_f = ws_size / 4;
  long long avail = (long long)total_f - (long long)fixed - 4096 - 64;
  int cap = (avail > 0) ? (int)(avail / (long long)per_t) : 8;
  if (cap > N0MAX) cap = N0MAX;
  if (cap < 8) cap = 8;
  P.N0cap = cap;
  P.ld_pref = alloc(cap);
  P.u_pref  = alloc((size_t)cap*64);
  P.fP    = alloc((size_t)cap*4096);
  P.pP    = alloc((size_t)(cap+1)*4096);
  P.Kp    = alloc((size_t)cap*4096);
  P.Sinvp = alloc((size_t)cap*4096);
  P.Fp    = alloc((size_t)cap*4096);
  P.Cp    = alloc((size_t)cap*4096);
  P.CsTp  = alloc((size_t)cap*4096);

  k0<<<1, 256, 0, stream>>>(P);
  kA<<<1, 512, 0, stream>>>(P);          // leaf + fP0 + doublings (LDS-resident)
  kB<<<cap, 512, 0, stream>>>(P);        // all prefix fP_t in parallel
  kC<<<cap, 256, 0, stream>>>(P);        // per-t maxabs/maxdiff
  kN<<<1, 256, 0, stream>>>(P);          // N0 selection
  kP<<<cap+1, 512, 0, stream>>>(P);      // pP_t in parallel
  k1ss<<<1, 512, 0, stream>>>(P);        // steady-state derived + Stein
  k1b<<<cap, 512, 0, stream>>>(P);
  k1d<<<N1CAP, 512, 0, stream>>>(P);
  k4<<<T, 256, 0, stream>>>(P);
  k1c<<<1, 512, 0, stream>>>(P);
  k2a<<<NC, 256, 0, stream>>>(P);
  k2b<<<1, 256, 0, stream>>>(P);
  k2c<<<NC, 256, 0, stream>>>(P);
  k5<<<T, 64, 0, stream>>>(P);
  k3a<<<NC, 256, 0, stream>>>(P);
  k3b<<<1, 256, 0, stream>>>(P);
  k3c<<<NC, 256, 0, stream>>>(P);
  k6<<<1, 256, 0, stream>>>(P);
}

// Round 3
// 2429.107 us; speedup vs baseline: 1.6205x; 1.6205x over previous
//
#include <hip/hip_runtime.h>
#include <math.h>

#define NN 64
#define LDW 68      // padded LDS stride (float4-aligned)
#define LCH 32      // mean-scan chunk length
#define N1CAP 144   // smoother-cov tail length (closed-form, parallel)
#define N0MAX 144   // forward Riccati cap
#define EPS_HARD 1e-5f
#define EPS_GATE 5e-2f
#define STALL_WIN 5
#define STALL_IMP 0.75f

struct KP {
  const float *Y, *A, *b, *Q, *H, *c, *R, *pm0, *P0;
  float *out_mean, *out_cov, *out_ll;
  int *meta; float *metaF;
  float *fm;
  float *AT, *HT, *HA, *Hb;
  float *Fss, *Kss, *Sinvss, *Css, *CsTss, *pPss, *sPss, *Fpow, *Cpow32, *Cpow31, *uss;
  float *Pw2, *Pw4, *Pw8, *Pw16, *Pw64, *Pw128;
  float *u_chunk, *startstate, *ub_chunk, *endstate;
  float *ld_pref, *u_pref;
  double *llbuf;
  float *E0g;
  // scan-element powers E^(2^j), j=0..7: A, C, J, L=chol(J)
  float *EA, *EC, *EJ, *EL;
  float *astat, *dstat;
  // smoothed-cov suffix-scan ping-pong buffers
  float *scM0, *scM1, *scG0, *scG1;
  float *fP, *pP, *Kp, *Sinvp, *Fp, *Cp, *CsTp;
  int N0cap, T, NC;
};

union F4 { float4 v; float f[4]; };

// ---------- helpers (blockDim.x == 256 unless noted) ----------

__device__ __forceinline__ void g2l(float* W, const float* G) {
  for (int e = threadIdx.x*4; e < 4096; e += 1024) {
    float4 v = *(const float4*)(G + e);
    *(float4*)(W + (e>>6)*LDW + (e&63)) = v;
  }
  __syncthreads();
}
__device__ __forceinline__ void l2g(float* G, const float* W) {
  for (int e = threadIdx.x*4; e < 4096; e += 1024)
    *(float4*)(G + e) = *(const float4*)(W + (e>>6)*LDW + (e&63));
  __syncthreads();
}
__device__ __forceinline__ void l2g_T(float* G, const float* W) {
  for (int e = threadIdx.x; e < 4096; e += 256)
    G[e] = W[(e&63)*LDW + (e>>6)];
  __syncthreads();
}
__device__ __forceinline__ void copyW(float* D, const float* S) {
  for (int e = threadIdx.x*4; e < 4096; e += 1024) {
    int base = (e>>6)*LDW + (e&63);
    *(float4*)(D + base) = *(const float4*)(S + base);
  }
  __syncthreads();
}
__device__ __forceinline__ void set_id(float* W) {
  for (int e = threadIdx.x; e < 4096; e += 256)
    W[(e>>6)*LDW + (e&63)] = ((e>>6) == (e&63)) ? 1.f : 0.f;
  __syncthreads();
}
__device__ __forceinline__ void sub_lg(float* D, const float* Wa, const float* G) {
  for (int e = threadIdx.x*4; e < 4096; e += 1024) {
    int base = (e>>6)*LDW + (e&63);
    F4 a, g; a.v = *(const float4*)(Wa + base); g.v = *(const float4*)(G + e);
    F4 o; o.f[0]=a.f[0]-g.f[0]; o.f[1]=a.f[1]-g.f[1]; o.f[2]=a.f[2]-g.f[2]; o.f[3]=a.f[3]-g.f[3];
    *(float4*)(D + base) = o.v;
  }
  __syncthreads();
}
// G_dst = G_src - W
__device__ __forceinline__ void rsub_store(float* Gd, const float* Gs, const float* W) {
  for (int e = threadIdx.x*4; e < 4096; e += 1024) {
    int base = (e>>6)*LDW + (e&63);
    F4 a, g; a.v = *(const float4*)(W + base); g.v = *(const float4*)(Gs + e);
    F4 o; o.f[0]=g.f[0]-a.f[0]; o.f[1]=g.f[1]-a.f[1]; o.f[2]=g.f[2]-a.f[2]; o.f[3]=g.f[3]-a.f[3];
    *(float4*)(Gd + e) = o.v;
  }
  __syncthreads();
}

// 2-value max reduction
__device__ __forceinline__ void redpair(float& ma, float& md, float* red) {
  #pragma unroll
  for (int off = 32; off; off >>= 1) {
    ma = fmaxf(ma, __shfl_xor(ma, off, 64));
    md = fmaxf(md, __shfl_xor(md, off, 64));
  }
  const int w = threadIdx.x >> 6;
  if ((threadIdx.x & 63) == 0) { red[w] = ma; red[4 + w] = md; }
  __syncthreads();
  ma = fmaxf(fmaxf(red[0], red[1]), fmaxf(red[2], red[3]));
  md = fmaxf(fmaxf(red[4], red[5]), fmaxf(red[6], red[7]));
  __syncthreads();
}

// D(=LDS,stride LDD) = [ADD +/-] op(A)*op(B)
template<int TRANSA, int TRANSB, int MODE, int LDD>
__device__ __forceinline__ void mm(float* __restrict__ D,
    const float* __restrict__ A, int lda,
    const float* __restrict__ B, int ldb,
    const float* __restrict__ ADD, int ldadd)
{
  const int tid = threadIdx.x;
  const int i0 = (tid >> 4) << 2, j0 = (tid & 15) << 2;
  float acc[4][4] = {};
  for (int k0 = 0; k0 < NN; k0 += 4) {
    F4 av[4], bv[4];
    #pragma unroll
    for (int u = 0; u < 4; ++u) {
      bv[u].v = TRANSB ? *(const float4*)(B + (j0+u)*ldb + k0)
                       : *(const float4*)(B + (k0+u)*ldb + j0);
      av[u].v = TRANSA ? *(const float4*)(A + (k0+u)*lda + i0)
                       : *(const float4*)(A + (i0+u)*lda + k0);
    }
    #pragma unroll
    for (int kk = 0; kk < 4; ++kk) {
      #pragma unroll
      for (int di = 0; di < 4; ++di) {
        float a = TRANSA ? av[kk].f[di] : av[di].f[kk];
        #pragma unroll
        for (int dj = 0; dj < 4; ++dj) {
          float bb = TRANSB ? bv[dj].f[kk] : bv[kk].f[dj];
          acc[di][dj] += a * bb;
        }
      }
    }
  }
  #pragma unroll
  for (int di = 0; di < 4; ++di) {
    if (MODE == 0 && (LDD & 3) == 0) {
      F4 o;
      #pragma unroll
      for (int dj = 0; dj < 4; ++dj) o.f[dj] = acc[di][dj];
      *(float4*)(D + (i0+di)*LDD + j0) = o.v;
    } else {
      #pragma unroll
      for (int dj = 0; dj < 4; ++dj) {
        float v = acc[di][dj];
        if (MODE == 1) v = ADD[(i0+di)*ldadd + j0+dj] + v;
        if (MODE == 2) v = ADD[(i0+di)*ldadd + j0+dj] - v;
        D[(i0+di)*LDD + j0+dj] = v;
      }
    }
  }
  __syncthreads();
}

// panel-16 Cholesky in stride-LDW buffer (256 threads). upper zeroed.
template<bool WANTLOG>
__device__ __forceinline__ void chol68(float* __restrict__ Sm, float* part, float* invd) {
  const int tid = threadIdx.x;
  const int lane = tid & 63;
  #pragma unroll
  for (int p = 0; p < 4; ++p) {
    const int j0 = p * 16;
    if (p > 0) {
      const int i = tid & 63;
      const int jq = (tid >> 6) * 4;
      float acc[4] = {0.f, 0.f, 0.f, 0.f};
      for (int kb = 0; kb < j0; kb += 4) {
        F4 av; av.v = *(const float4*)(Sm + i*LDW + kb);
        #pragma unroll
        for (int q = 0; q < 4; ++q) {
          F4 bv; bv.v = *(const float4*)(Sm + (j0 + jq + q)*LDW + kb);
          acc[q] += av.f[0]*bv.f[0] + av.f[1]*bv.f[1] + av.f[2]*bv.f[2] + av.f[3]*bv.f[3];
        }
      }
      #pragma unroll
      for (int q = 0; q < 4; ++q)
        Sm[i*LDW + j0 + jq + q] -= acc[q];
      __syncthreads();
    }
    if (tid < 64) {
      float t[16];
      F4 tv;
      #pragma unroll
      for (int q4 = 0; q4 < 4; ++q4) {
        tv.v = *(const float4*)(Sm + lane*LDW + j0 + 4*q4);
        t[4*q4] = tv.f[0]; t[4*q4+1] = tv.f[1]; t[4*q4+2] = tv.f[2]; t[4*q4+3] = tv.f[3];
      }
      #pragma unroll
      for (int jj = 0; jj < 16; ++jj) {
        float acc = t[jj];
        #pragma unroll
        for (int kk = 0; kk < jj; ++kk)
          acc -= __shfl(t[kk], j0 + jj, 64) * t[kk];
        float piv = __shfl(acc, j0 + jj, 64);
        float sq = sqrtf(fmaxf(piv, 1e-30f));
        float inv = 1.0f / sq;
        if (lane == j0 + jj) {
          t[jj] = sq;
          invd[j0 + jj] = inv;
          if (WANTLOG) part[j0 + jj] = logf(sq);
        } else {
          t[jj] = (lane > j0 + jj) ? acc * inv : 0.f;
        }
      }
      #pragma unroll
      for (int q4 = 0; q4 < 4; ++q4) {
        tv.f[0] = t[4*q4]; tv.f[1] = t[4*q4+1]; tv.f[2] = t[4*q4+2]; tv.f[3] = t[4*q4+3];
        *(float4*)(Sm + lane*LDW + j0 + 4*q4) = tv.v;
      }
    }
    __syncthreads();
  }
}

// forward triangular solve DST <- L^-1 op(SRC); TR=1 reads SRC transposed.
template<int TR>
__device__ __forceinline__ void tri_fwd_ld(const float* __restrict__ L,
                                           const float* __restrict__ invd,
                                           const float* __restrict__ SRC, int lds,
                                           float* __restrict__ DST, int ldd) {
  const int col = threadIdx.x >> 2, p = threadIdx.x & 3;
  const int gbase = (threadIdx.x & 63) & ~3;
  float xr[16];
  #pragma unroll
  for (int u = 0; u < 16; ++u)
    xr[u] = TR ? SRC[col*lds + (4*u+p)] : SRC[(4*u+p)*lds + col];
  #pragma unroll
  for (int i = 0; i < NN; ++i) {
    const int idx = i >> 2, ow = i & 3;
    float yi = xr[idx] * invd[i];
    yi = __shfl(yi, gbase + ow, 64);
    if (p == ow) xr[idx] = yi;
    else if (p > ow) xr[idx] -= L[(4*idx+p)*LDW + i] * yi;
    #pragma unroll
    for (int u = idx+1; u < 16; ++u)
      xr[u] -= L[(4*u+p)*LDW + i] * yi;
  }
  #pragma unroll
  for (int u = 0; u < 16; ++u) DST[(4*u+p)*ldd + col] = xr[u];
  __syncthreads();
}

// backward triangular solve DST <- L^-T SRC
__device__ __forceinline__ void tri_bwd_ld(const float* __restrict__ L,
                                           const float* __restrict__ invd,
                                           const float* __restrict__ SRC, int lds,
                                           float* __restrict__ DST, int ldd) {
  const int col = threadIdx.x >> 2, p = threadIdx.x & 3;
  const int gbase = (threadIdx.x & 63) & ~3;
  float xr[16];
  #pragma unroll
  for (int u = 0; u < 16; ++u) xr[u] = SRC[(4*u+p)*lds + col];
  #pragma unroll
  for (int i = NN-1; i >= 0; --i) {
    const int idx = i >> 2, ow = i & 3;
    float zi = xr[idx] * invd[i];
    zi = __shfl(zi, gbase + ow, 64);
    if (p == ow) xr[idx] = zi;
    else if (p < ow) xr[idx] -= L[i*LDW + 4*idx+p] * zi;
    #pragma unroll
    for (int u = 0; u < idx; ++u)
      xr[u] -= L[i*LDW + 4*u+p] * zi;
  }
  #pragma unroll
  for (int u = 0; u < 16; ++u) DST[(4*u+p)*ldd + col] = xr[u];
  __syncthreads();
}

// two-sided triangular solve: DST <- L^-T L^-1 SRC
__device__ __forceinline__ void tri_solve2(const float* __restrict__ L,
                                           const float* __restrict__ invd,
                                           const float* __restrict__ SRC,
                                           float* __restrict__ DST) {
  const int col = threadIdx.x >> 2, p = threadIdx.x & 3;
  const int gbase = (threadIdx.x & 63) & ~3;
  float xr[16];
  #pragma unroll
  for (int u = 0; u < 16; ++u) xr[u] = SRC[(4*u+p)*LDW + col];
  #pragma unroll
  for (int i = 0; i < NN; ++i) {
    const int idx = i >> 2, ow = i & 3;
    float yi = xr[idx] * invd[i];
    yi = __shfl(yi, gbase + ow, 64);
    if (p == ow) xr[idx] = yi;
    else if (p > ow) xr[idx] -= L[(4*idx+p)*LDW + i] * yi;
    #pragma unroll
    for (int u = idx+1; u < 16; ++u)
      xr[u] -= L[(4*u+p)*LDW + i] * yi;
  }
  #pragma unroll
  for (int i = NN-1; i >= 0; --i) {
    const int idx = i >> 2, ow = i & 3;
    float zi = xr[idx] * invd[i];
    zi = __shfl(zi, gbase + ow, 64);
    if (p == ow) xr[idx] = zi;
    else if (p < ow) xr[idx] -= L[i*LDW + 4*idx+p] * zi;
    #pragma unroll
    for (int u = 0; u < idx; ++u)
      xr[u] -= L[i*LDW + 4*u+p] * zi;
  }
  #pragma unroll
  for (int u = 0; u < 16; ++u) DST[(4*u+p)*LDW + col] = xr[u];
  __syncthreads();
}

// y(LDS 64-vec) = Mg(64x64 row-major)*x + addv (nullable). y may alias x.
__device__ __forceinline__ void matvec256(float* __restrict__ y, const float* __restrict__ Mg,
    const float* __restrict__ x, const float* __restrict__ addv, float* __restrict__ red) {
  const int r = threadIdx.x & 63, p = threadIdx.x >> 6;
  const int kb = p*16;
  float s = 0.f;
  #pragma unroll
  for (int q = 0; q < 4; ++q) {
    F4 mv; mv.v = *(const float4*)(Mg + r*NN + kb + q*4);
    s += mv.f[0]*x[kb+q*4] + mv.f[1]*x[kb+q*4+1] + mv.f[2]*x[kb+q*4+2] + mv.f[3]*x[kb+q*4+3];
  }
  red[p*64 + r] = s;
  __syncthreads();
  if (threadIdx.x < 64) {
    float t = red[r] + red[64+r] + red[128+r] + red[192+r];
    y[r] = t + (addv ? addv[r] : 0.f);
  }
  __syncthreads();
}

// ---------- kernels ----------

__global__ __launch_bounds__(256) void k0(KP P) {
  __shared__ __align__(16) float W0[LDW*NN];
  const int tid = threadIdx.x;
  for (int e = tid; e < 4096; e += 256) {
    int r = e>>6, cc = e&63;
    P.AT[e] = P.A[cc*64+r];
    P.HT[e] = P.H[cc*64+r];
  }
  if (tid < 64) {
    float s = 0.f;
    for (int k = 0; k < 64; ++k) s += P.H[tid*64+k]*P.b[k];
    P.Hb[tid] = s;
  }
  __syncthreads();
  mm<0,0,0,LDW>(W0, P.H, NN, P.A, NN, nullptr, 0);   // HA = H*A
  l2g(P.HA, W0);
}

// ---------------------------------------------------------------------------
// Parallel Riccati prefix via associative filtering elements (Sarkka-style).
//   E = (At, Ct, Jt); combine via Woodbury; prefix fP_t = C of (a1 ∘ E^t).
// kA: leaf + fP0 + 7 sequential doublings E^(2^j).  kB: per-t bit combines.
// ---------------------------------------------------------------------------

__global__ __launch_bounds__(256) void kA(KP P) {
  __shared__ __align__(16) float W0[LDW*NN], W1[LDW*NN], W2[LDW*NN], W3[LDW*NN];
  __shared__ float part[64], iv1[64], iv2[64];
  const int tid = threadIdx.x;
  // ---- generic element E^1 ----
  mm<0,0,0,LDW>(W0, P.H, NN, P.Q, NN, nullptr, 0);      // T = H Q
  mm<0,1,1,LDW>(W1, W0, LDW, P.H, NN, P.R, NN);         // St = T H^T + R
  chol68<false>(W1, part, iv1);                          // Ls
  tri_fwd_ld<0>(W1, iv1, P.HA, NN, W2, LDW);            // U = Ls^-1 HA
  mm<1,0,0,LDW>(W3, W2, LDW, W2, LDW, nullptr, 0);      // Jt = U^T U
  l2g(P.EJ, W3);
  chol68<false>(W3, part, iv2);
  l2g(P.EL, W3);                                         // Lt = chol(Jt)
  tri_bwd_ld(W1, iv1, W2, LDW, W2, LDW);                // X = St^-1 HA
  mm<1,0,2,LDW>(W3, W0, LDW, W2, LDW, P.A, NN);         // At = A - (HQ)^T X
  l2g(P.EA, W3);
  tri_fwd_ld<0>(W1, iv1, W0, LDW, W2, LDW);             // V = Ls^-1 T
  mm<1,0,2,LDW>(W3, W2, LDW, W2, LDW, P.Q, NN);         // Ct = Q - V^T V
  l2g(P.EC, W3);
  // ---- a1: fP0 = P0 - (L0^-1 H P0)^T (L0^-1 H P0) ----
  mm<0,0,0,LDW>(W0, P.H, NN, P.P0, NN, nullptr, 0);     // HP0
  mm<0,1,1,LDW>(W1, W0, LDW, P.H, NN, P.R, NN);         // S0
  chol68<false>(W1, part, iv1);
  tri_fwd_ld<0>(W1, iv1, W0, LDW, W2, LDW);             // U0
  mm<1,0,2,LDW>(W3, W2, LDW, W2, LDW, P.P0, NN);        // fP0
  l2g(P.fP, W3);
  // ---- doubling: E^(2^(j+1)) = E^(2^j) ∘ E^(2^j) ----
  for (int j = 0; j < 7 && (2 << j) <= P.N0cap - 1; ++j) {
    const float* Ag = P.EA + j*4096;
    const float* Cg = P.EC + j*4096;
    const float* Jg = P.EJ + j*4096;
    const float* Lg = P.EL + j*4096;
    mm<0,0,0,LDW>(W0, Cg, NN, Lg, NN, nullptr, 0);      // Pm = C L
    mm<1,0,0,LDW>(W1, Lg, NN, W0, LDW, nullptr, 0);     // W = L^T Pm
    if (tid < 64) W1[tid*LDW + tid] += 1.f;
    __syncthreads();
    chol68<false>(W1, part, iv1);                        // Lw = chol(I+W)
    mm<1,0,0,LDW>(W2, Lg, NN, Ag, NN, nullptr, 0);      // T1 = L^T A
    tri_fwd_ld<0>(W1, iv1, W2, LDW, W2, LDW);           // T2f = Lw^-1 T1
    mm<1,0,1,LDW>(W3, W2, LDW, W2, LDW, Jg, NN);        // Jn = T2f^T T2f + J
    l2g(P.EJ + (j+1)*4096, W3);
    chol68<false>(W3, part, iv2);
    l2g(P.EL + (j+1)*4096, W3);                          // Ln
    tri_bwd_ld(W1, iv1, W2, LDW, W2, LDW);              // T2 = (I+W)^-1 T1
    mm<0,0,2,LDW>(W3, W0, LDW, W2, LDW, Ag, NN);        // ZA = A - Pm T2
    mm<0,0,0,LDW>(W2, Ag, NN, W3, LDW, nullptr, 0);     // An = A ZA
    l2g(P.EA + (j+1)*4096, W2);
    tri_fwd_ld<1>(W1, iv1, W0, LDW, W2, LDW);           // T5 = Lw^-1 Pm^T
    mm<1,0,2,LDW>(W3, W2, LDW, W2, LDW, Cg, NN);        // ZC = C - T5^T T5
    mm<0,0,0,LDW>(W0, Ag, NN, W3, LDW, nullptr, 0);     // T7 = A ZC
    mm<0,1,1,LDW>(W3, W0, LDW, Ag, NN, Cg, NN);         // Cn = T7 A^T + C
    l2g(P.EC + (j+1)*4096, W3);
  }
}

// block t: fP_t = C of a1 ∘ E^t, by combining set bits of t (ascending).
__global__ __launch_bounds__(256) void kB(KP P) {
  __shared__ __align__(16) float Wc[LDW*NN], W0[LDW*NN], W1[LDW*NN], W2[LDW*NN];
  __shared__ float part[64], ivw[64];
  const int t = blockIdx.x;
  if (t == 0) return;                       // fP0 written by kA
  g2l(Wc, P.fP);                            // acc.C = fP0
  int rem = t;
  for (int j = 0; rem; ++j, rem >>= 1) {
    if (!(rem & 1)) continue;
    const float* Ag = P.EA + j*4096;
    const float* Cg = P.EC + j*4096;
    const float* Lg = P.EL + j*4096;
    mm<0,0,0,LDW>(W0, Wc, LDW, Lg, NN, nullptr, 0);     // Pm = C L
    mm<1,0,0,LDW>(W1, Lg, NN, W0, LDW, nullptr, 0);     // W = L^T Pm
    if (threadIdx.x < 64) W1[threadIdx.x*LDW + threadIdx.x] += 1.f;
    __syncthreads();
    chol68<false>(W1, part, ivw);                        // Lw
    tri_fwd_ld<1>(W1, ivw, W0, LDW, W2, LDW);           // T5 = Lw^-1 Pm^T
    mm<1,0,2,LDW>(W1, W2, LDW, W2, LDW, Wc, LDW);       // ZC = C - T5^T T5
    mm<0,0,0,LDW>(W0, Ag, NN, W1, LDW, nullptr, 0);     // T7 = A ZC
    mm<0,1,1,LDW>(Wc, W0, LDW, Ag, NN, Cg, NN);         // C' = T7 A^T + C
  }
  l2g(P.fP + (size_t)t*4096, Wc);
}

// per-t maxabs + maxdiff of fP (parallel)
__global__ __launch_bounds__(256) void kC(KP P) {
  __shared__ float red[16];
  const int t = blockIdx.x;
  const float* cur = P.fP + (size_t)t*4096;
  const float* prv = P.fP + (size_t)(t > 0 ? t-1 : 0)*4096;
  float a = 0.f, d = 0.f;
  for (int e = threadIdx.x*4; e < 4096; e += 1024) {
    F4 v, pv; v.v = *(const float4*)(cur + e); pv.v = *(const float4*)(prv + e);
    #pragma unroll
    for (int q = 0; q < 4; ++q) {
      a = fmaxf(a, fabsf(v.f[q]));
      d = fmaxf(d, fabsf(v.f[q] - pv.f[q]));
    }
  }
  redpair(a, d, red);
  if (threadIdx.x == 0) { P.astat[t] = a; P.dstat[t] = (t > 0) ? d : 0.f; }
}

// replicate the original stall/convergence selection of N0 (scalar, tiny)
__global__ __launch_bounds__(256) void kN(KP P) {
  __shared__ float as_[N0MAX], ds_[N0MAX];
  const int cap = P.N0cap;
  for (int i = threadIdx.x; i < cap; i += 256) { as_[i] = P.astat[i]; ds_[i] = P.dstat[i]; }
  __syncthreads();
  if (threadIdx.x == 0) {
    float mabs = 1e-20f, dref = 1e30f;
    int tref = 0, N0 = cap;
    bool conv = false;
    for (int t = 0; t < cap; ++t) {
      mabs = fmaxf(mabs, as_[t]);
      if (t > 0) {
        float d = ds_[t];
        if (d <= EPS_HARD*mabs) { N0 = t+1; conv = true; }
        if (d < STALL_IMP*dref) { dref = d; tref = t; }
        else if (t - tref >= STALL_WIN && t >= 12 && d < EPS_GATE*mabs) { N0 = t+1; conv = true; }
      }
      if (conv) break;
    }
    P.meta[0] = N0; P.metaF[1] = mabs;
  }
}

// pP_t for t in [0, cap]: pP_0 = P0; pP_t = A fP_{t-1} A^T + Q  (parallel)
__global__ __launch_bounds__(256) void kP(KP P) {
  __shared__ __align__(16) float W0[LDW*NN], W1[LDW*NN];
  const int t = blockIdx.x;
  if (t == 0) {
    for (int e = threadIdx.x*4; e < 4096; e += 1024)
      *(float4*)(P.pP + e) = *(const float4*)(P.P0 + e);
    return;
  }
  g2l(W0, P.fP + (size_t)(t-1)*4096);
  mm<0,0,0,LDW>(W1, P.A, NN, W0, LDW, nullptr, 0);
  mm<0,0,1,LDW>(W0, W1, LDW, P.AT, NN, P.Q, NN);
  l2g(P.pP + (size_t)t*4096, W0);
}

// steady-state derived quantities + Stein solve (former k1 Phase B)
__global__ __launch_bounds__(256) void k1ss(KP P) {
  __shared__ __align__(16) float W0[LDW*NN], W1[LDW*NN], W2[LDW*NN], CH[LDW*NN];
  __shared__ float part[64], invd[64];
  const int tid = threadIdx.x;
  const int N0 = P.meta[0];
  const float* fPssG = P.fP + (size_t)(N0-1)*4096;
  g2l(CH, fPssG);                                             // fP_ss
  mm<0,0,0,LDW>(W1, P.A, NN, CH, LDW, nullptr, 0);            // A*fP_ss
  mm<0,0,1,LDW>(W0, W1, LDW, P.AT, NN, P.Q, NN);              // pP_ss
  l2g(P.pPss, W0);
  mm<0,0,0,LDW>(W1, P.H, NN, W0, LDW, nullptr, 0);            // HP
  mm<0,0,1,LDW>(CH, W1, LDW, P.HT, NN, P.R, NN);              // S
  chol68<true>(CH, part, invd);
  if (tid == 0) { float s=0.f; for (int j=0;j<64;++j) s += part[j]; P.metaF[0] = s; }
  tri_solve2(CH, invd, W1, W1);                               // X
  l2g_T(P.Kss, W1);                                           // K_ss = X^T
  if (tid < 64) {
    float s = P.b[tid];
    for (int k = 0; k < 64; ++k) s -= W1[k*LDW + tid]*P.Hb[k];
    P.uss[tid] = s;                                           // u_ss = (I-KH) b
  }
  __syncthreads();
  set_id(W0); tri_solve2(CH, invd, W0, W0);                   // Sinv
  l2g(P.Sinvss, W0);
  mm<1,0,2,LDW>(W0, W1, LDW, P.HA, NN, P.A, NN);              // F_ss = A - X^T*HA
  l2g(P.Fss, W0);
  // C_ss = (pP_ss^{-1} A fP_ss)^T
  g2l(W0, fPssG);
  mm<0,0,0,LDW>(W1, P.A, NN, W0, LDW, nullptr, 0);            // AF
  g2l(CH, P.pPss);
  chol68<false>(CH, part, invd);
  tri_solve2(CH, invd, W1, W1);                               // X2 = C^T
  l2g(P.CsTss, W1);
  l2g_T(P.Css, W1);
  // C powers: C^2..C^32, C^31, C^64, C^128
  g2l(W0, P.Css);
  mm<0,0,0,LDW>(W1, W0, LDW, W0, LDW, nullptr, 0); l2g(P.Pw2,  W1);
  mm<0,0,0,LDW>(W0, W1, LDW, W1, LDW, nullptr, 0); l2g(P.Pw4,  W0);
  mm<0,0,0,LDW>(W1, W0, LDW, W0, LDW, nullptr, 0); l2g(P.Pw8,  W1);
  mm<0,0,0,LDW>(W0, W1, LDW, W1, LDW, nullptr, 0); l2g(P.Pw16, W0);  // C^16
  mm<0,0,0,LDW>(W1, W0, LDW, W0, LDW, nullptr, 0); l2g(P.Cpow32, W1);
  mm<0,0,0,LDW>(W2, W1, LDW, W1, LDW, nullptr, 0); l2g(P.Pw64, W2);
  mm<0,0,0,LDW>(CH, W2, LDW, W2, LDW, nullptr, 0); l2g(P.Pw128, CH);
  mm<0,0,0,LDW>(W1, W0, LDW, P.Pw8, NN, nullptr, 0);          // C^24
  mm<0,0,0,LDW>(W0, W1, LDW, P.Pw4, NN, nullptr, 0);          // C^28
  mm<0,0,0,LDW>(W1, W0, LDW, P.Pw2, NN, nullptr, 0);          // C^30
  mm<0,0,0,LDW>(W0, W1, LDW, P.Css, NN, nullptr, 0);          // C^31
  l2g(P.Cpow31, W0);
  // F^32
  g2l(W0, P.Fss);
  mm<0,0,0,LDW>(W1, W0, LDW, W0, LDW, nullptr, 0);
  mm<0,0,0,LDW>(W0, W1, LDW, W1, LDW, nullptr, 0);
  mm<0,0,0,LDW>(W1, W0, LDW, W0, LDW, nullptr, 0);
  mm<0,0,0,LDW>(W0, W1, LDW, W1, LDW, nullptr, 0);
  mm<0,0,0,LDW>(W1, W0, LDW, W0, LDW, nullptr, 0);
  l2g(P.Fpow, W1);
  // ---- Stein solve: sPss - C sPss C' = fPss - C pPss C' (7 doublings) ----
  g2l(W1, P.Css);                                             // M
  g2l(W2, P.CsTss);                                           // M'
  g2l(W0, P.pPss);
  mm<0,0,0,LDW>(CH, W1, LDW, W0, LDW, nullptr, 0);            // C*pPss
  mm<0,0,2,LDW>(W0, CH, LDW, W2, LDW, fPssG, NN);             // X = fPss - (C pPss) C'
  for (int it = 0; it < 7; ++it) {
    mm<0,0,0,LDW>(CH, W1, LDW, W0, LDW, nullptr, 0);          // M*X
    mm<0,0,1,LDW>(W0, CH, LDW, W2, LDW, W0, LDW);             // X += (M X) M'
    mm<0,0,0,LDW>(CH, W1, LDW, W1, LDW, nullptr, 0);          // M^2
    copyW(W1, CH);
    mm<0,0,0,LDW>(CH, W2, LDW, W2, LDW, nullptr, 0);          // (M')^2
    copyW(W2, CH);
  }
  l2g(P.sPss, W0);
  rsub_store(P.E0g, fPssG, W0);                               // E0 = fPss - sPss
}

// parallel closed-form tail: sP_{T-1-k} = sPss + C^k E0 C'^k  (C^k by binary powering)
__global__ __launch_bounds__(256) void k1d(KP P) {
  __shared__ __align__(16) float W0[LDW*NN], W1[LDW*NN], W2[LDW*NN];
  const int k = blockIdx.x;
  float* dst = P.out_cov + (size_t)(P.T-1-k)*4096;
  if (k == 0) {
    const float* src = P.fP + (size_t)(P.meta[0]-1)*4096;
    for (int e = threadIdx.x*4; e < 4096; e += 1024)
      *(float4*)(dst+e) = *(const float4*)(src+e);
    return;
  }
  const float* pw[8] = {P.Css, P.Pw2, P.Pw4, P.Pw8, P.Pw16, P.Cpow32, P.Pw64, P.Pw128};
  int b = __ffs(k) - 1;
  g2l(W1, pw[b]);
  float* cur = W1; float* oth = W0;
  for (int j = b+1; j < 8; ++j) {
    if ((k >> j) & 1) {
      mm<0,0,0,LDW>(oth, pw[j], NN, cur, LDW, nullptr, 0);
      float* tmp = cur; cur = oth; oth = tmp;
    }
  }
  mm<0,0,0,LDW>(W2, cur, LDW, P.E0g, NN, nullptr, 0);         // M*E0
  mm<0,1,1,LDW>(oth, W2, LDW, cur, LDW, P.sPss, NN);          // + (M E0) M^T + sPss
  l2g(dst, oth);
}

// parallel per-prefix-t derived quantities (+ per-t logdet)
__global__ __launch_bounds__(256) void k1b(KP P) {
  __shared__ __align__(16) float W0[LDW*NN], W1[LDW*NN], CH[LDW*NN];
  __shared__ float part[64], invd[64];
  const int t = blockIdx.x;
  if (t >= P.meta[0]) return;
  g2l(W0, P.pP + (size_t)t*4096);
  mm<0,0,0,LDW>(W1, P.H, NN, W0, LDW, nullptr, 0);            // HP
  mm<0,0,1,LDW>(CH, W1, LDW, P.HT, NN, P.R, NN);              // S
  chol68<true>(CH, part, invd);
  if (threadIdx.x == 0) { float s=0.f; for (int j=0;j<64;++j) s += part[j]; P.ld_pref[t] = s; }
  tri_solve2(CH, invd, W1, W1);                               // X
  l2g_T(P.Kp + (size_t)t*4096, W1);
  if (threadIdx.x < 64) {
    float s = P.b[threadIdx.x];
    for (int k = 0; k < 64; ++k) s -= W1[k*LDW + threadIdx.x]*P.Hb[k];
    P.u_pref[t*64 + threadIdx.x] = s;
  }
  __syncthreads();
  set_id(W0); tri_solve2(CH, invd, W0, W0);                   // Sinv
  l2g(P.Sinvp + (size_t)t*4096, W0);
  mm<1,0,2,LDW>(W0, W1, LDW, P.HA, NN, P.A, NN);              // F_t
  l2g(P.Fp + (size_t)t*4096, W0);
  // C_t
  g2l(W0, P.fP + (size_t)t*4096);
  mm<0,0,0,LDW>(W1, P.A, NN, W0, LDW, nullptr, 0);            // AF
  g2l(CH, P.pP + (size_t)(t+1)*4096);
  chol68<false>(CH, part, invd);
  tri_solve2(CH, invd, W1, W1);                               // X2
  l2g(P.CsTp + (size_t)t*4096, W1);
  l2g_T(P.Cp + (size_t)t*4096, W1);
}

// ---------------------------------------------------------------------------
// Smoothed-cov prefix as a PARALLEL suffix scan.
//   sP_t = C_t sP_{t+1} C_t^T + G_t,  G_t = fP_t - C_t pP_{t+1} C_t^T,
//   X_{N0} = sPss.  Elements (M,G); combine (Ml,Gl)∘(Mr,Gr) =
//   (Ml Mr, Ml Gr Ml^T + Gl).  8 Hillis-Steele levels over <=144 elements.
// ---------------------------------------------------------------------------

__global__ __launch_bounds__(256) void k1cI(KP P) {
  __shared__ __align__(16) float W0[LDW*NN], W1[LDW*NN];
  const int t = blockIdx.x;
  if (t >= P.meta[0]) return;
  const float* Cg = P.Cp + (size_t)t*4096;
  for (int e = threadIdx.x*4; e < 4096; e += 1024)
    *(float4*)(P.scM0 + (size_t)t*4096 + e) = *(const float4*)(Cg + e);
  g2l(W0, P.pP + (size_t)(t+1)*4096);
  mm<0,0,0,LDW>(W1, Cg, NN, W0, LDW, nullptr, 0);             // C*pP
  mm<0,0,2,LDW>(W0, W1, LDW, P.CsTp + (size_t)t*4096, NN,
                P.fP + (size_t)t*4096, NN);                   // G = fP - (C pP) C^T
  l2g(P.scG0 + (size_t)t*4096, W0);
}

__global__ __launch_bounds__(256) void k1cL(KP P, int step, int sidx) {
  __shared__ __align__(16) float Wm[LDW*NN], W0[LDW*NN], W1[LDW*NN];
  const int t = blockIdx.x;
  const int N0 = P.meta[0];
  if (t >= N0) return;
  const float* Msrc = sidx ? P.scM1 : P.scM0;
  const float* Gsrc = sidx ? P.scG1 : P.scG0;
  float* Mdst = sidx ? P.scM0 : P.scM1;
  float* Gdst = sidx ? P.scG0 : P.scG1;
  const int s = t + step;
  if (s >= N0) {   // identity on the right: pass through
    for (int e = threadIdx.x*4; e < 4096; e += 1024) {
      *(float4*)(Mdst + (size_t)t*4096 + e) = *(const float4*)(Msrc + (size_t)t*4096 + e);
      *(float4*)(Gdst + (size_t)t*4096 + e) = *(const float4*)(Gsrc + (size_t)t*4096 + e);
    }
    return;
  }
  g2l(Wm, Msrc + (size_t)t*4096);                             // Mt
  g2l(W0, Gsrc + (size_t)s*4096);                             // Gs
  mm<0,0,0,LDW>(W1, Wm, LDW, W0, LDW, nullptr, 0);            // Mt*Gs
  mm<0,1,1,LDW>(W0, W1, LDW, Wm, LDW,
                Gsrc + (size_t)t*4096, NN);                   // + Mt^T ... = Mt Gs Mt^T + Gt
  l2g(Gdst + (size_t)t*4096, W0);
  g2l(W0, Msrc + (size_t)s*4096);                             // Ms
  mm<0,0,0,LDW>(W1, Wm, LDW, W0, LDW, nullptr, 0);            // Mt*Ms
  l2g(Mdst + (size_t)t*4096, W1);
}

__global__ __launch_bounds__(256) void k1cF(KP P) {
  __shared__ __align__(16) float Wm[LDW*NN], W0[LDW*NN], W1[LDW*NN];
  const int t = blockIdx.x;
  if (t >= P.meta[0]) return;
  g2l(Wm, P.scM0 + (size_t)t*4096);
  g2l(W0, P.sPss);
  mm<0,0,0,LDW>(W1, Wm, LDW, W0, LDW, nullptr, 0);            // M*sPss
  mm<0,1,1,LDW>(W0, W1, LDW, Wm, LDW,
                P.scG0 + (size_t)t*4096, NN);                 // + M^T, + G
  l2g(P.out_cov + (size_t)t*4096, W0);
}

// fill steady middle region of smoothed covs
__global__ __launch_bounds__(256) void k4(KP P) {
  const int t = blockIdx.x;
  if (t < P.meta[0] || t >= P.T - N1CAP) return;
  float* dst = P.out_cov + (size_t)t*4096;
  for (int e = threadIdx.x*4; e < 4096; e += 1024)
    *(float4*)(dst+e) = *(const float4*)(P.sPss + e);
}

// forward mean scan: local pass (steady chunks, zero init)
__global__ __launch_bounds__(256) void k2a(KP P) {
  __shared__ float xv[64], gv[64], ty[64], red[256];
  const int c = blockIdx.x;
  const int N0 = P.meta[0];
  const int PB = (N0 + LCH - 1)/LCH;
  if (c < PB) return;
  const int tid = threadIdx.x;
  if (tid < 64) xv[tid] = 0.f;
  __syncthreads();
  for (int s = 0; s < LCH; ++s) {
    int t = c*LCH + s;
    if (tid < 64) ty[tid] = P.Y[(size_t)t*64+tid] - P.c[tid];
    __syncthreads();
    matvec256(gv, P.Kss, ty, P.uss, red);
    matvec256(xv, P.Fss, xv, gv, red);
  }
  if (tid < 64) P.u_chunk[c*64+tid] = xv[tid];
}

// forward mean scan: sequential prefix + chunk carries
__global__ __launch_bounds__(256) void k2b(KP P) {
  __shared__ float xv[64], gv[64], ty[64], hp[64], red[256];
  const int tid = threadIdx.x;
  const int N0 = P.meta[0];
  const int PB = (N0 + LCH - 1)/LCH;
  const int PE = PB*LCH;
  if (tid < 64) xv[tid] = P.pm0[tid];
  __syncthreads();
  matvec256(hp, P.H, xv, nullptr, red);
  if (tid < 64) ty[tid] = P.Y[tid] - hp[tid] - P.c[tid];
  __syncthreads();
  matvec256(xv, P.Kp, ty, xv, red);            // fm0 = pm0 + K0*r0
  if (tid < 64) P.fm[tid] = xv[tid];
  __syncthreads();
  for (int t = 1; t < PE; ++t) {
    const float* Kt = (t < N0) ? P.Kp + (size_t)t*4096 : P.Kss;
    const float* Ft = (t < N0) ? P.Fp + (size_t)t*4096 : P.Fss;
    const float* ut = (t < N0) ? P.u_pref + t*64 : P.uss;
    if (tid < 64) ty[tid] = P.Y[(size_t)t*64+tid] - P.c[tid];
    __syncthreads();
    matvec256(gv, Kt, ty, ut, red);
    matvec256(xv, Ft, xv, gv, red);
    if (tid < 64) P.fm[(size_t)t*64+tid] = xv[tid];
    __syncthreads();
  }
  for (int c = PB; c < P.NC; ++c) {
    if (tid < 64) P.startstate[c*64+tid] = xv[tid];
    __syncthreads();
    matvec256(xv, P.Fpow, xv, P.u_chunk + c*64, red);
  }
}

// forward mean scan: replay steady chunks with true start states
__global__ __launch_bounds__(256) void k2c(KP P) {
  __shared__ float xv[64], gv[64], ty[64], red[256];
  const int c = blockIdx.x;
  const int N0 = P.meta[0];
  const int PB = (N0 + LCH - 1)/LCH;
  if (c < PB) return;
  const int tid = threadIdx.x;
  if (tid < 64) xv[tid] = P.startstate[c*64+tid];
  __syncthreads();
  for (int s = 0; s < LCH; ++s) {
    int t = c*LCH + s;
    if (tid < 64) ty[tid] = P.Y[(size_t)t*64+tid] - P.c[tid];
    __syncthreads();
    matvec256(gv, P.Kss, ty, P.uss, red);
    matvec256(xv, P.Fss, xv, gv, red);
    if (tid < 64) P.fm[(size_t)t*64+tid] = xv[tid];
    __syncthreads();
  }
}

// log-likelihood terms (one wave per t) -> llbuf
__global__ __launch_bounds__(64) void k5(KP P) {
  __shared__ float pmv[64], rv[64];
  const int t = blockIdx.x;
  const int N0 = P.meta[0];
  const int r = threadIdx.x;
  float pm;
  if (t == 0) {
    pm = P.pm0[r];
  } else {
    pmv[r] = P.fm[(size_t)(t-1)*64 + r];
    __syncthreads();
    float s = P.b[r];
    const float* Ar = P.A + r*64;
    for (int k = 0; k < 64; k += 4)
      s += Ar[k]*pmv[k] + Ar[k+1]*pmv[k+1] + Ar[k+2]*pmv[k+2] + Ar[k+3]*pmv[k+3];
    pm = s;
    __syncthreads();
  }
  pmv[r] = pm; __syncthreads();
  float rr = P.Y[(size_t)t*64 + r] - P.c[r];
  const float* Hr = P.H + r*64;
  for (int k = 0; k < 64; ++k) rr -= Hr[k]*pmv[k];
  rv[r] = rr; __syncthreads();
  const float* Sv = ((t < N0) ? P.Sinvp + (size_t)t*4096 : P.Sinvss) + r*64;
  float wv = 0.f;
  for (int k = 0; k < 64; ++k) wv += Sv[k]*rv[k];
  float qq = rr*wv;
  #pragma unroll
  for (int off = 32; off > 0; off >>= 1) qq += __shfl_xor(qq, off, 64);
  if (r == 0) {
    float ldt = (t < N0) ? P.ld_pref[t] : P.metaF[0];
    P.llbuf[t] = -58.8120661250990555 - (double)ldt - 0.5*(double)qq;
  }
}

// backward mean scan: local pass
__global__ __launch_bounds__(256) void k3a(KP P) {
  __shared__ float sv[64], wv[64], vv[64], fmv[64], red[256];
  const int c = blockIdx.x;
  const int N0 = P.meta[0];
  const int PB = (N0 + LCH - 1)/LCH;
  if (c < PB) return;
  const int tid = threadIdx.x;
  if (tid < 64) sv[tid] = 0.f;
  __syncthreads();
  int hi = (c == P.NC-1) ? P.T-2 : c*LCH + LCH - 1;
  for (int t = hi; t >= c*LCH; --t) {
    if (tid < 64) fmv[tid] = P.fm[(size_t)t*64+tid];
    __syncthreads();
    matvec256(wv, P.A, fmv, P.b, red);
    if (tid < 64) vv[tid] = sv[tid] - wv[tid];
    __syncthreads();
    matvec256(sv, P.Css, vv, fmv, red);
  }
  if (tid < 64) P.ub_chunk[c*64+tid] = sv[tid];
}

// backward mean scan: carries + sequential prefix
__global__ __launch_bounds__(256) void k3b(KP P) {
  __shared__ float sv[64], wv[64], vv[64], fmv[64], red[256];
  const int tid = threadIdx.x;
  const int N0 = P.meta[0];
  const int PB = (N0 + LCH - 1)/LCH;
  const int PE = PB*LCH;
  if (tid < 64) {
    float v = P.fm[(size_t)(P.T-1)*64+tid];
    sv[tid] = v;
    P.out_mean[(size_t)(P.T-1)*64+tid] = v;
  }
  __syncthreads();
  for (int c = P.NC-1; c >= PB; --c) {
    if (tid < 64) P.endstate[c*64+tid] = sv[tid];
    __syncthreads();
    matvec256(sv, (c == P.NC-1) ? P.Cpow31 : P.Cpow32, sv, P.ub_chunk + c*64, red);
  }
  for (int t = PE-1; t >= 0; --t) {
    const float* Ct = (t < N0) ? P.Cp + (size_t)t*4096 : P.Css;
    if (tid < 64) fmv[tid] = P.fm[(size_t)t*64+tid];
    __syncthreads();
    matvec256(wv, P.A, fmv, P.b, red);
    if (tid < 64) vv[tid] = sv[tid] - wv[tid];
    __syncthreads();
    matvec256(sv, Ct, vv, fmv, red);
    if (tid < 64) P.out_mean[(size_t)t*64+tid] = sv[tid];
    __syncthreads();
  }
}

// backward mean scan: replay steady chunks
__global__ __launch_bounds__(256) void k3c(KP P) {
  __shared__ float sv[64], wv[64], vv[64], fmv[64], red[256];
  const int c = blockIdx.x;
  const int N0 = P.meta[0];
  const int PB = (N0 + LCH - 1)/LCH;
  if (c < PB) return;
  const int tid = threadIdx.x;
  if (tid < 64) sv[tid] = P.endstate[c*64+tid];
  __syncthreads();
  int hi = (c == P.NC-1) ? P.T-2 : c*LCH + LCH - 1;
  for (int t = hi; t >= c*LCH; --t) {
    if (tid < 64) fmv[tid] = P.fm[(size_t)t*64+tid];
    __syncthreads();
    matvec256(wv, P.A, fmv, P.b, red);
    if (tid < 64) vv[tid] = sv[tid] - wv[tid];
    __syncthreads();
    matvec256(sv, P.Css, vv, fmv, red);
    if (tid < 64) P.out_mean[(size_t)t*64+tid] = sv[tid];
    __syncthreads();
  }
}

// reduce per-t ll terms
__global__ __launch_bounds__(256) void k6(KP P) {
  __shared__ double rd[256];
  double s = 0.0;
  for (int t = threadIdx.x; t < P.T; t += 256) s += P.llbuf[t];
  rd[threadIdx.x] = s; __syncthreads();
  #pragma unroll
  for (int off = 128; off > 0; off >>= 1) {
    if ((int)threadIdx.x < off) rd[threadIdx.x] += rd[threadIdx.x + off];
    __syncthreads();
  }
  if (threadIdx.x == 0) P.out_ll[0] = (float)rd[0];
}

// ---------- host ----------

extern "C" void kernel_launch(void* const* d_in, const int* in_sizes, int n_in,
                              void* d_out, int out_size, void* d_ws, size_t ws_size,
                              hipStream_t stream) {
  (void)n_in; (void)out_size;
  KP P;
  P.Y   = (const float*)d_in[0];
  P.A   = (const float*)d_in[1];
  P.b   = (const float*)d_in[2];
  P.Q   = (const float*)d_in[3];
  P.H   = (const float*)d_in[4];
  P.c   = (const float*)d_in[5];
  P.R   = (const float*)d_in[6];
  P.pm0 = (const float*)d_in[7];
  P.P0  = (const float*)d_in[8];
  const int T = in_sizes[0] / 64;
  const int NC = T / LCH;
  P.T = T; P.NC = NC;

  float* out = (float*)d_out;
  P.out_mean = out;
  P.out_cov  = out + (size_t)T*64;
  P.out_ll   = out + (size_t)T*64 + (size_t)T*4096;

  float* w = (float*)d_ws;
  size_t off = 0;
  auto alloc = [&](size_t n) { float* p = w + off; off += n; return p; };
  P.meta   = (int*)alloc(8);
  P.metaF  = alloc(8);
  P.llbuf  = (double*)alloc((size_t)2*T);
  P.fm     = alloc((size_t)T*64);
  P.AT = alloc(4096); P.HT = alloc(4096); P.HA = alloc(4096); P.Hb = alloc(64);
  P.Fss = alloc(4096); P.Kss = alloc(4096); P.Sinvss = alloc(4096);
  P.Css = alloc(4096); P.CsTss = alloc(4096); P.pPss = alloc(4096); P.sPss = alloc(4096);
  P.Fpow = alloc(4096); P.Cpow32 = alloc(4096); P.Cpow31 = alloc(4096); P.uss = alloc(64);
  P.Pw2 = alloc(4096); P.Pw4 = alloc(4096); P.Pw8 = alloc(4096); P.Pw16 = alloc(4096);
  P.Pw64 = alloc(4096); P.Pw128 = alloc(4096);
  P.u_chunk = alloc((size_t)NC*64); P.startstate = alloc((size_t)NC*64);
  P.ub_chunk = alloc((size_t)NC*64); P.endstate = alloc((size_t)NC*64);
  P.E0g = alloc(4096);
  P.EA = alloc((size_t)8*4096); P.EC = alloc((size_t)8*4096);
  P.EJ = alloc((size_t)8*4096); P.EL = alloc((size_t)8*4096);
  P.astat = alloc(256); P.dstat = alloc(256);
  // prefix arrays sized by remaining workspace
  size_t fixed = off;
  size_t per_t = 11*4096 + 64 + 1;   // incl. 4 scan ping-pong buffers
  size_t total_f = ws_size / 4;
  long long avail = (long long)total_f - (long long)fixed - 4096 - 64;
  int cap = (avail > 0) ? (int)(avail / (long long)per_t) : 8;
  if (cap > N0MAX) cap = N0MAX;
  if (cap < 8) cap = 8;
  P.N0cap = cap;
  P.ld_pref = alloc(cap);
  P.u_pref  = alloc((size_t)cap*64);
  P.fP    = alloc((size_t)cap*4096);
  P.pP    = alloc((size_t)(cap+1)*4096);
  P.Kp    = alloc((size_t)cap*4096);
  P.Sinvp = alloc((size_t)cap*4096);
  P.Fp    = alloc((size_t)cap*4096);
  P.Cp    = alloc((size_t)cap*4096);
  P.CsTp  = alloc((size_t)cap*4096);
  P.scM0  = alloc((size_t)cap*4096);
  P.scM1  = alloc((size_t)cap*4096);
  P.scG0  = alloc((size_t)cap*4096);
  P.scG1  = alloc((size_t)cap*4096);

  k0<<<1, 256, 0, stream>>>(P);
  kA<<<1, 256, 0, stream>>>(P);          // leaf + fP0 + E^(2^j) doublings (serial, 1 block)
  kB<<<cap, 256, 0, stream>>>(P);        // all prefix fP_t in parallel
  kC<<<cap, 256, 0, stream>>>(P);        // per-t maxabs/maxdiff
  kN<<<1, 256, 0, stream>>>(P);          // N0 selection
  kP<<<cap+1, 256, 0, stream>>>(P);      // pP_t in parallel
  k1ss<<<1, 256, 0, stream>>>(P);        // steady-state derived + Stein
  k1b<<<cap, 256, 0, stream>>>(P);
  k1d<<<N1CAP, 256, 0, stream>>>(P);
  k4<<<T, 256, 0, stream>>>(P);
  // smoothed-cov prefix: parallel suffix scan (replaces sequential k1c)
  k1cI<<<cap, 256, 0, stream>>>(P);
  {
    int sidx = 0;
    for (int d = 0; d < 8; ++d) { k1cL<<<cap, 256, 0, stream>>>(P, 1 << d, sidx); sidx ^= 1; }
  }
  k1cF<<<cap, 256, 0, stream>>>(P);
  k2a<<<NC, 256, 0, stream>>>(P);
  k2b<<<1, 256, 0, stream>>>(P);
  k2c<<<NC, 256, 0, stream>>>(P);
  k5<<<T, 64, 0, stream>>>(P);
  k3a<<<NC, 256, 0, stream>>>(P);
  k3b<<<1, 256, 0, stream>>>(P);
  k3c<<<NC, 256, 0, stream>>>(P);
  k6<<<1, 256, 0, stream>>>(P);
}

// Round 4
// 2248.003 us; speedup vs baseline: 1.7510x; 1.0806x over previous
//
#include <hip/hip_runtime.h>
#include <math.h>

#define NN 64
#define LDW 68      // padded LDS stride (float4-aligned)
#define LCH 32      // mean-scan chunk length
#define N1CAP 144   // smoother-cov tail length (closed-form, parallel)
#define N0MAX 144   // forward Riccati cap
#define EPS_HARD 1e-5f
#define EPS_GATE 5e-2f
#define STALL_WIN 5
#define STALL_IMP 0.75f

struct KP {
  const float *Y, *A, *b, *Q, *H, *c, *R, *pm0, *P0;
  float *out_mean, *out_cov, *out_ll;
  int *meta; float *metaF;
  float *fm;
  float *AT, *HT, *HA, *Hb;
  float *Fss, *Kss, *Sinvss, *Css, *CsTss, *pPss, *sPss, *Fpow, *Cpow32, *Cpow31, *uss;
  float *Pw2, *Pw4, *Pw8, *Pw16, *Pw64, *Pw128;
  float *u_chunk, *startstate, *ub_chunk, *endstate;
  float *ld_pref, *u_pref;
  double *llbuf;
  float *E0g;
  // scan-element powers E^(2^j), j=0..7: A, C, J(unused globally), L=chol(J)
  float *EA, *EC, *EJ, *EL;
  float *astat, *dstat;
  // smoothed-cov suffix-scan ping-pong buffers
  float *scM0, *scM1, *scG0, *scG1;
  float *fP, *pP, *Kp, *Sinvp, *Fp, *Cp, *CsTp;
  int N0cap, T, NC;
};

union F4 { float4 v; float f[4]; };

// ---------- helpers (blockDim.x == 256 unless noted) ----------

__device__ __forceinline__ void g2l(float* W, const float* G) {
  for (int e = threadIdx.x*4; e < 4096; e += 1024) {
    float4 v = *(const float4*)(G + e);
    *(float4*)(W + (e>>6)*LDW + (e&63)) = v;
  }
  __syncthreads();
}
__device__ __forceinline__ void l2g(float* G, const float* W) {
  for (int e = threadIdx.x*4; e < 4096; e += 1024)
    *(float4*)(G + e) = *(const float4*)(W + (e>>6)*LDW + (e&63));
  __syncthreads();
}
// batched triple store (one pass, one barrier)
__device__ __forceinline__ void l2g3(float* G1, const float* Wa,
                                     float* G2, const float* Wb,
                                     float* G3, const float* Wc) {
  for (int e = threadIdx.x*4; e < 4096; e += 1024) {
    int base = (e>>6)*LDW + (e&63);
    *(float4*)(G1 + e) = *(const float4*)(Wa + base);
    *(float4*)(G2 + e) = *(const float4*)(Wb + base);
    *(float4*)(G3 + e) = *(const float4*)(Wc + base);
  }
  __syncthreads();
}
__device__ __forceinline__ void l2g_T(float* G, const float* W) {
  for (int e = threadIdx.x; e < 4096; e += 256)
    G[e] = W[(e&63)*LDW + (e>>6)];
  __syncthreads();
}
__device__ __forceinline__ void copyW(float* D, const float* S) {
  for (int e = threadIdx.x*4; e < 4096; e += 1024) {
    int base = (e>>6)*LDW + (e&63);
    *(float4*)(D + base) = *(const float4*)(S + base);
  }
  __syncthreads();
}
__device__ __forceinline__ void set_id(float* W) {
  for (int e = threadIdx.x; e < 4096; e += 256)
    W[(e>>6)*LDW + (e&63)] = ((e>>6) == (e&63)) ? 1.f : 0.f;
  __syncthreads();
}
// G_dst = G_src - W
__device__ __forceinline__ void rsub_store(float* Gd, const float* Gs, const float* W) {
  for (int e = threadIdx.x*4; e < 4096; e += 1024) {
    int base = (e>>6)*LDW + (e&63);
    F4 a, g; a.v = *(const float4*)(W + base); g.v = *(const float4*)(Gs + e);
    F4 o; o.f[0]=g.f[0]-a.f[0]; o.f[1]=g.f[1]-a.f[1]; o.f[2]=g.f[2]-a.f[2]; o.f[3]=g.f[3]-a.f[3];
    *(float4*)(Gd + e) = o.v;
  }
  __syncthreads();
}

// 2-value max reduction
__device__ __forceinline__ void redpair(float& ma, float& md, float* red) {
  #pragma unroll
  for (int off = 32; off; off >>= 1) {
    ma = fmaxf(ma, __shfl_xor(ma, off, 64));
    md = fmaxf(md, __shfl_xor(md, off, 64));
  }
  const int w = threadIdx.x >> 6;
  if ((threadIdx.x & 63) == 0) { red[w] = ma; red[4 + w] = md; }
  __syncthreads();
  ma = fmaxf(fmaxf(red[0], red[1]), fmaxf(red[2], red[3]));
  md = fmaxf(fmaxf(red[4], red[5]), fmaxf(red[6], red[7]));
  __syncthreads();
}

// D(stride LDD) = [ADD +/-] op(A)*op(B)
template<int TRANSA, int TRANSB, int MODE, int LDD>
__device__ __forceinline__ void mm(float* __restrict__ D,
    const float* __restrict__ A, int lda,
    const float* __restrict__ B, int ldb,
    const float* __restrict__ ADD, int ldadd)
{
  const int tid = threadIdx.x;
  const int i0 = (tid >> 4) << 2, j0 = (tid & 15) << 2;
  float acc[4][4] = {};
  for (int k0 = 0; k0 < NN; k0 += 4) {
    F4 av[4], bv[4];
    #pragma unroll
    for (int u = 0; u < 4; ++u) {
      bv[u].v = TRANSB ? *(const float4*)(B + (j0+u)*ldb + k0)
                       : *(const float4*)(B + (k0+u)*ldb + j0);
      av[u].v = TRANSA ? *(const float4*)(A + (k0+u)*lda + i0)
                       : *(const float4*)(A + (i0+u)*lda + k0);
    }
    #pragma unroll
    for (int kk = 0; kk < 4; ++kk) {
      #pragma unroll
      for (int di = 0; di < 4; ++di) {
        float a = TRANSA ? av[kk].f[di] : av[di].f[kk];
        #pragma unroll
        for (int dj = 0; dj < 4; ++dj) {
          float bb = TRANSB ? bv[dj].f[kk] : bv[kk].f[dj];
          acc[di][dj] += a * bb;
        }
      }
    }
  }
  #pragma unroll
  for (int di = 0; di < 4; ++di) {
    if (MODE == 0 && (LDD & 3) == 0) {
      F4 o;
      #pragma unroll
      for (int dj = 0; dj < 4; ++dj) o.f[dj] = acc[di][dj];
      *(float4*)(D + (i0+di)*LDD + j0) = o.v;
    } else {
      #pragma unroll
      for (int dj = 0; dj < 4; ++dj) {
        float v = acc[di][dj];
        if (MODE == 1) v = ADD[(i0+di)*ldadd + j0+dj] + v;
        if (MODE == 2) v = ADD[(i0+di)*ldadd + j0+dj] - v;
        D[(i0+di)*LDD + j0+dj] = v;
      }
    }
  }
  __syncthreads();
}

// two INDEPENDENT matmuls in one barrier region (per-output FP order == mm)
template<int TA1,int TB1,int MO1,int LD1, int TA2,int TB2,int MO2,int LD2>
__device__ __forceinline__ void mm2(
    float* __restrict__ D1, const float* __restrict__ A1, int lda1,
    const float* __restrict__ B1, int ldb1, const float* __restrict__ AD1, int ldad1,
    float* __restrict__ D2, const float* __restrict__ A2, int lda2,
    const float* __restrict__ B2, int ldb2, const float* __restrict__ AD2, int ldad2)
{
  const int tid = threadIdx.x;
  const int i0 = (tid >> 4) << 2, j0 = (tid & 15) << 2;
  float acc1[4][4] = {}, acc2[4][4] = {};
  for (int k0 = 0; k0 < NN; k0 += 4) {
    F4 av1[4], bv1[4], av2[4], bv2[4];
    #pragma unroll
    for (int u = 0; u < 4; ++u) {
      bv1[u].v = TB1 ? *(const float4*)(B1 + (j0+u)*ldb1 + k0)
                     : *(const float4*)(B1 + (k0+u)*ldb1 + j0);
      av1[u].v = TA1 ? *(const float4*)(A1 + (k0+u)*lda1 + i0)
                     : *(const float4*)(A1 + (i0+u)*lda1 + k0);
      bv2[u].v = TB2 ? *(const float4*)(B2 + (j0+u)*ldb2 + k0)
                     : *(const float4*)(B2 + (k0+u)*ldb2 + j0);
      av2[u].v = TA2 ? *(const float4*)(A2 + (k0+u)*lda2 + i0)
                     : *(const float4*)(A2 + (i0+u)*lda2 + k0);
    }
    #pragma unroll
    for (int kk = 0; kk < 4; ++kk) {
      #pragma unroll
      for (int di = 0; di < 4; ++di) {
        float a1 = TA1 ? av1[kk].f[di] : av1[di].f[kk];
        float a2 = TA2 ? av2[kk].f[di] : av2[di].f[kk];
        #pragma unroll
        for (int dj = 0; dj < 4; ++dj) {
          acc1[di][dj] += a1 * (TB1 ? bv1[dj].f[kk] : bv1[kk].f[dj]);
          acc2[di][dj] += a2 * (TB2 ? bv2[dj].f[kk] : bv2[kk].f[dj]);
        }
      }
    }
  }
  #pragma unroll
  for (int di = 0; di < 4; ++di) {
    if (MO1 == 0 && (LD1 & 3) == 0) {
      F4 o;
      #pragma unroll
      for (int dj = 0; dj < 4; ++dj) o.f[dj] = acc1[di][dj];
      *(float4*)(D1 + (i0+di)*LD1 + j0) = o.v;
    } else {
      #pragma unroll
      for (int dj = 0; dj < 4; ++dj) {
        float v = acc1[di][dj];
        if (MO1 == 1) v = AD1[(i0+di)*ldad1 + j0+dj] + v;
        if (MO1 == 2) v = AD1[(i0+di)*ldad1 + j0+dj] - v;
        D1[(i0+di)*LD1 + j0+dj] = v;
      }
    }
  }
  #pragma unroll
  for (int di = 0; di < 4; ++di) {
    if (MO2 == 0 && (LD2 & 3) == 0) {
      F4 o;
      #pragma unroll
      for (int dj = 0; dj < 4; ++dj) o.f[dj] = acc2[di][dj];
      *(float4*)(D2 + (i0+di)*LD2 + j0) = o.v;
    } else {
      #pragma unroll
      for (int dj = 0; dj < 4; ++dj) {
        float v = acc2[di][dj];
        if (MO2 == 1) v = AD2[(i0+di)*ldad2 + j0+dj] + v;
        if (MO2 == 2) v = AD2[(i0+di)*ldad2 + j0+dj] - v;
        D2[(i0+di)*LD2 + j0+dj] = v;
      }
    }
  }
  __syncthreads();
}

// panel-16 Cholesky in stride-LDW buffer (256 threads). upper zeroed.
template<bool WANTLOG>
__device__ __forceinline__ void chol68(float* __restrict__ Sm, float* part, float* invd) {
  const int tid = threadIdx.x;
  const int lane = tid & 63;
  #pragma unroll
  for (int p = 0; p < 4; ++p) {
    const int j0 = p * 16;
    if (p > 0) {
      const int i = tid & 63;
      const int jq = (tid >> 6) * 4;
      float acc[4] = {0.f, 0.f, 0.f, 0.f};
      for (int kb = 0; kb < j0; kb += 4) {
        F4 av; av.v = *(const float4*)(Sm + i*LDW + kb);
        #pragma unroll
        for (int q = 0; q < 4; ++q) {
          F4 bv; bv.v = *(const float4*)(Sm + (j0 + jq + q)*LDW + kb);
          acc[q] += av.f[0]*bv.f[0] + av.f[1]*bv.f[1] + av.f[2]*bv.f[2] + av.f[3]*bv.f[3];
        }
      }
      #pragma unroll
      for (int q = 0; q < 4; ++q)
        Sm[i*LDW + j0 + jq + q] -= acc[q];
      __syncthreads();
    }
    if (tid < 64) {
      float t[16];
      F4 tv;
      #pragma unroll
      for (int q4 = 0; q4 < 4; ++q4) {
        tv.v = *(const float4*)(Sm + lane*LDW + j0 + 4*q4);
        t[4*q4] = tv.f[0]; t[4*q4+1] = tv.f[1]; t[4*q4+2] = tv.f[2]; t[4*q4+3] = tv.f[3];
      }
      #pragma unroll
      for (int jj = 0; jj < 16; ++jj) {
        float acc = t[jj];
        #pragma unroll
        for (int kk = 0; kk < jj; ++kk)
          acc -= __shfl(t[kk], j0 + jj, 64) * t[kk];
        float piv = __shfl(acc, j0 + jj, 64);
        float sq = sqrtf(fmaxf(piv, 1e-30f));
        float inv = 1.0f / sq;
        if (lane == j0 + jj) {
          t[jj] = sq;
          invd[j0 + jj] = inv;
          if (WANTLOG) part[j0 + jj] = logf(sq);
        } else {
          t[jj] = (lane > j0 + jj) ? acc * inv : 0.f;
        }
      }
      #pragma unroll
      for (int q4 = 0; q4 < 4; ++q4) {
        tv.f[0] = t[4*q4]; tv.f[1] = t[4*q4+1]; tv.f[2] = t[4*q4+2]; tv.f[3] = t[4*q4+3];
        *(float4*)(Sm + lane*LDW + j0 + 4*q4) = tv.v;
      }
    }
    __syncthreads();
  }
}

// forward triangular solve DST <- L^-1 op(SRC); TR=1 reads SRC transposed.
template<int TR>
__device__ __forceinline__ void tri_fwd_ld(const float* __restrict__ L,
                                           const float* __restrict__ invd,
                                           const float* __restrict__ SRC, int lds,
                                           float* __restrict__ DST, int ldd) {
  const int col = threadIdx.x >> 2, p = threadIdx.x & 3;
  const int gbase = (threadIdx.x & 63) & ~3;
  float xr[16];
  #pragma unroll
  for (int u = 0; u < 16; ++u)
    xr[u] = TR ? SRC[col*lds + (4*u+p)] : SRC[(4*u+p)*lds + col];
  #pragma unroll
  for (int i = 0; i < NN; ++i) {
    const int idx = i >> 2, ow = i & 3;
    float yi = xr[idx] * invd[i];
    yi = __shfl(yi, gbase + ow, 64);
    if (p == ow) xr[idx] = yi;
    else if (p > ow) xr[idx] -= L[(4*idx+p)*LDW + i] * yi;
    #pragma unroll
    for (int u = idx+1; u < 16; ++u)
      xr[u] -= L[(4*u+p)*LDW + i] * yi;
  }
  #pragma unroll
  for (int u = 0; u < 16; ++u) DST[(4*u+p)*ldd + col] = xr[u];
  __syncthreads();
}

// TWO independent forward solves (possibly different L) in one barrier region
template<int TR1,int TR2>
__device__ __forceinline__ void tri_fwd2(
    const float* __restrict__ L1, const float* __restrict__ ivd1,
    const float* __restrict__ S1, int lds1, float* __restrict__ D1, int ldd1,
    const float* __restrict__ L2, const float* __restrict__ ivd2,
    const float* __restrict__ S2, int lds2, float* __restrict__ D2, int ldd2)
{
  const int col = threadIdx.x >> 2, p = threadIdx.x & 3;
  const int gbase = (threadIdx.x & 63) & ~3;
  float xr[16], xs[16];
  #pragma unroll
  for (int u = 0; u < 16; ++u) {
    xr[u] = TR1 ? S1[col*lds1 + (4*u+p)] : S1[(4*u+p)*lds1 + col];
    xs[u] = TR2 ? S2[col*lds2 + (4*u+p)] : S2[(4*u+p)*lds2 + col];
  }
  #pragma unroll
  for (int i = 0; i < NN; ++i) {
    const int idx = i >> 2, ow = i & 3;
    float yi = xr[idx] * ivd1[i];
    yi = __shfl(yi, gbase + ow, 64);
    float zi = xs[idx] * ivd2[i];
    zi = __shfl(zi, gbase + ow, 64);
    if (p == ow) xr[idx] = yi;
    else if (p > ow) xr[idx] -= L1[(4*idx+p)*LDW + i] * yi;
    if (p == ow) xs[idx] = zi;
    else if (p > ow) xs[idx] -= L2[(4*idx+p)*LDW + i] * zi;
    #pragma unroll
    for (int u = idx+1; u < 16; ++u) {
      xr[u] -= L1[(4*u+p)*LDW + i] * yi;
      xs[u] -= L2[(4*u+p)*LDW + i] * zi;
    }
  }
  #pragma unroll
  for (int u = 0; u < 16; ++u) {
    D1[(4*u+p)*ldd1 + col] = xr[u];
    D2[(4*u+p)*ldd2 + col] = xs[u];
  }
  __syncthreads();
}

// backward triangular solve DST <- L^-T SRC
__device__ __forceinline__ void tri_bwd_ld(const float* __restrict__ L,
                                           const float* __restrict__ invd,
                                           const float* __restrict__ SRC, int lds,
                                           float* __restrict__ DST, int ldd) {
  const int col = threadIdx.x >> 2, p = threadIdx.x & 3;
  const int gbase = (threadIdx.x & 63) & ~3;
  float xr[16];
  #pragma unroll
  for (int u = 0; u < 16; ++u) xr[u] = SRC[(4*u+p)*lds + col];
  #pragma unroll
  for (int i = NN-1; i >= 0; --i) {
    const int idx = i >> 2, ow = i & 3;
    float zi = xr[idx] * invd[i];
    zi = __shfl(zi, gbase + ow, 64);
    if (p == ow) xr[idx] = zi;
    else if (p < ow) xr[idx] -= L[i*LDW + 4*idx+p] * zi;
    #pragma unroll
    for (int u = 0; u < idx; ++u)
      xr[u] -= L[i*LDW + 4*u+p] * zi;
  }
  #pragma unroll
  for (int u = 0; u < 16; ++u) DST[(4*u+p)*ldd + col] = xr[u];
  __syncthreads();
}

// one forward + one backward solve (same L), interleaved
__device__ __forceinline__ void tri_fb2(
    const float* __restrict__ L, const float* __restrict__ ivd,
    const float* __restrict__ Sf, int ldsf, float* __restrict__ Df, int lddf,
    const float* __restrict__ Sb, int ldsb, float* __restrict__ Db, int lddb)
{
  const int col = threadIdx.x >> 2, p = threadIdx.x & 3;
  const int gbase = (threadIdx.x & 63) & ~3;
  float xf[16], xb[16];
  #pragma unroll
  for (int u = 0; u < 16; ++u) {
    xf[u] = Sf[(4*u+p)*ldsf + col];
    xb[u] = Sb[(4*u+p)*ldsb + col];
  }
  #pragma unroll
  for (int k = 0; k < NN; ++k) {
    { // forward step i=k
      const int i = k, idx = i >> 2, ow = i & 3;
      float yi = xf[idx] * ivd[i];
      yi = __shfl(yi, gbase + ow, 64);
      if (p == ow) xf[idx] = yi;
      else if (p > ow) xf[idx] -= L[(4*idx+p)*LDW + i] * yi;
      #pragma unroll
      for (int u = idx+1; u < 16; ++u)
        xf[u] -= L[(4*u+p)*LDW + i] * yi;
    }
    { // backward step i=NN-1-k
      const int i = NN-1-k, idx = i >> 2, ow = i & 3;
      float zi = xb[idx] * ivd[i];
      zi = __shfl(zi, gbase + ow, 64);
      if (p == ow) xb[idx] = zi;
      else if (p < ow) xb[idx] -= L[i*LDW + 4*idx+p] * zi;
      #pragma unroll
      for (int u = 0; u < idx; ++u)
        xb[u] -= L[i*LDW + 4*u+p] * zi;
    }
  }
  #pragma unroll
  for (int u = 0; u < 16; ++u) {
    Df[(4*u+p)*lddf + col] = xf[u];
    Db[(4*u+p)*lddb + col] = xb[u];
  }
  __syncthreads();
}

// two-sided triangular solve: DST <- L^-T L^-1 SRC
__device__ __forceinline__ void tri_solve2(const float* __restrict__ L,
                                           const float* __restrict__ invd,
                                           const float* __restrict__ SRC,
                                           float* __restrict__ DST) {
  const int col = threadIdx.x >> 2, p = threadIdx.x & 3;
  const int gbase = (threadIdx.x & 63) & ~3;
  float xr[16];
  #pragma unroll
  for (int u = 0; u < 16; ++u) xr[u] = SRC[(4*u+p)*LDW + col];
  #pragma unroll
  for (int i = 0; i < NN; ++i) {
    const int idx = i >> 2, ow = i & 3;
    float yi = xr[idx] * invd[i];
    yi = __shfl(yi, gbase + ow, 64);
    if (p == ow) xr[idx] = yi;
    else if (p > ow) xr[idx] -= L[(4*idx+p)*LDW + i] * yi;
    #pragma unroll
    for (int u = idx+1; u < 16; ++u)
      xr[u] -= L[(4*u+p)*LDW + i] * yi;
  }
  #pragma unroll
  for (int i = NN-1; i >= 0; --i) {
    const int idx = i >> 2, ow = i & 3;
    float zi = xr[idx] * invd[i];
    zi = __shfl(zi, gbase + ow, 64);
    if (p == ow) xr[idx] = zi;
    else if (p < ow) xr[idx] -= L[i*LDW + 4*idx+p] * zi;
    #pragma unroll
    for (int u = 0; u < idx; ++u)
      xr[u] -= L[i*LDW + 4*u+p] * zi;
  }
  #pragma unroll
  for (int u = 0; u < 16; ++u) DST[(4*u+p)*LDW + col] = xr[u];
  __syncthreads();
}

// TWO independent two-sided solves (same L), in-place, stride LDW
__device__ __forceinline__ void tri_s2x2(const float* __restrict__ L,
                                         const float* __restrict__ invd,
                                         float* __restrict__ X1,
                                         float* __restrict__ X2) {
  const int col = threadIdx.x >> 2, p = threadIdx.x & 3;
  const int gbase = (threadIdx.x & 63) & ~3;
  float xr[16], xs[16];
  #pragma unroll
  for (int u = 0; u < 16; ++u) {
    xr[u] = X1[(4*u+p)*LDW + col];
    xs[u] = X2[(4*u+p)*LDW + col];
  }
  #pragma unroll
  for (int i = 0; i < NN; ++i) {
    const int idx = i >> 2, ow = i & 3;
    float yi = xr[idx] * invd[i];
    yi = __shfl(yi, gbase + ow, 64);
    float zi = xs[idx] * invd[i];
    zi = __shfl(zi, gbase + ow, 64);
    if (p == ow) xr[idx] = yi;
    else if (p > ow) xr[idx] -= L[(4*idx+p)*LDW + i] * yi;
    if (p == ow) xs[idx] = zi;
    else if (p > ow) xs[idx] -= L[(4*idx+p)*LDW + i] * zi;
    #pragma unroll
    for (int u = idx+1; u < 16; ++u) {
      xr[u] -= L[(4*u+p)*LDW + i] * yi;
      xs[u] -= L[(4*u+p)*LDW + i] * zi;
    }
  }
  #pragma unroll
  for (int i = NN-1; i >= 0; --i) {
    const int idx = i >> 2, ow = i & 3;
    float yi = xr[idx] * invd[i];
    yi = __shfl(yi, gbase + ow, 64);
    float zi = xs[idx] * invd[i];
    zi = __shfl(zi, gbase + ow, 64);
    if (p == ow) xr[idx] = yi;
    else if (p < ow) xr[idx] -= L[i*LDW + 4*idx+p] * yi;
    if (p == ow) xs[idx] = zi;
    else if (p < ow) xs[idx] -= L[i*LDW + 4*idx+p] * zi;
    #pragma unroll
    for (int u = 0; u < idx; ++u) {
      xr[u] -= L[i*LDW + 4*u+p] * yi;
      xs[u] -= L[i*LDW + 4*u+p] * zi;
    }
  }
  #pragma unroll
  for (int u = 0; u < 16; ++u) {
    X1[(4*u+p)*LDW + col] = xr[u];
    X2[(4*u+p)*LDW + col] = xs[u];
  }
  __syncthreads();
}

// y(LDS 64-vec) = Mg(64x64 row-major)*x + addv (nullable). y may alias x.
__device__ __forceinline__ void matvec256(float* __restrict__ y, const float* __restrict__ Mg,
    const float* __restrict__ x, const float* __restrict__ addv, float* __restrict__ red) {
  const int r = threadIdx.x & 63, p = threadIdx.x >> 6;
  const int kb = p*16;
  float s = 0.f;
  #pragma unroll
  for (int q = 0; q < 4; ++q) {
    F4 mv; mv.v = *(const float4*)(Mg + r*NN + kb + q*4);
    s += mv.f[0]*x[kb+q*4] + mv.f[1]*x[kb+q*4+1] + mv.f[2]*x[kb+q*4+2] + mv.f[3]*x[kb+q*4+3];
  }
  red[p*64 + r] = s;
  __syncthreads();
  if (threadIdx.x < 64) {
    float t = red[r] + red[64+r] + red[128+r] + red[192+r];
    y[r] = t + (addv ? addv[r] : 0.f);
  }
  __syncthreads();
}

// ---------- kernels ----------

__global__ __launch_bounds__(256) void k0(KP P) {
  __shared__ __align__(16) float W0[LDW*NN];
  const int tid = threadIdx.x;
  for (int e = tid; e < 4096; e += 256) {
    int r = e>>6, cc = e&63;
    P.AT[e] = P.A[cc*64+r];
    P.HT[e] = P.H[cc*64+r];
  }
  if (tid < 64) {
    float s = 0.f;
    for (int k = 0; k < 64; ++k) s += P.H[tid*64+k]*P.b[k];
    P.Hb[tid] = s;
  }
  __syncthreads();
  mm<0,0,0,LDW>(W0, P.H, NN, P.A, NN, nullptr, 0);   // HA = H*A
  l2g(P.HA, W0);
}

// ---------------------------------------------------------------------------
// Parallel Riccati prefix via associative filtering elements (Sarkka-style).
// kA v2: batched ops (mm2/tri2), state A,C,J,L LDS-resident (9 buffers, 157KB).
// ---------------------------------------------------------------------------

__global__ __launch_bounds__(256) void kA(KP P) {
  __shared__ __align__(16) float LA[LDW*NN], LC[LDW*NN], LJ[LDW*NN], LL[LDW*NN];
  __shared__ __align__(16) float W0[LDW*NN], W1[LDW*NN], W2[LDW*NN], W3[LDW*NN], W4[LDW*NN];
  __shared__ float part[64], iv1[64], iv2[64];
  const int tid = threadIdx.x;
  // ---- leaf E^1 and a1 (fP0), batched ----
  mm2<0,0,0,LDW, 0,0,0,LDW>(W0, P.H,NN, P.Q,NN, nullptr,0,
                            W2, P.H,NN, P.P0,NN, nullptr,0);      // T = H Q ; HP0 = H P0
  mm2<0,1,1,LDW, 0,1,1,LDW>(W1, W0,LDW, P.H,NN, P.R,NN,
                            W3, W2,LDW, P.H,NN, P.R,NN);          // St ; S0
  chol68<false>(W1, part, iv1);                                    // Ls
  chol68<false>(W3, part, iv2);                                    // L0
  tri_fwd2<0,0>(W1, iv1, P.HA,NN, W4,LDW,
                W3, iv2, W2,LDW,  W2,LDW);                         // U = Ls^-1 HA ; U0
  mm2<1,0,0,LDW, 1,0,2,LDW>(LJ, W4,LDW, W4,LDW, nullptr,0,
                            W3, W2,LDW, W2,LDW, P.P0,NN);          // Jt = U^T U ; fP0
  l2g(P.fP, W3);
  copyW(LL, LJ);
  chol68<false>(LL, part, iv2);                                    // Lt = chol(Jt)
  tri_fb2(W1, iv1, W0,LDW, W3,LDW,  W4,LDW, W4,LDW);               // V = Ls^-1 T ; X = Ls^-T U
  mm2<1,0,2,LDW, 1,0,2,LDW>(LA, W0,LDW, W4,LDW, P.A,NN,
                            LC, W3,LDW, W3,LDW, P.Q,NN);           // At = A - T^T X ; Ct = Q - V^T V
  l2g3(P.EA, LA, P.EC, LC, P.EL, LL);
  // ---- doublings: E^(2^(j+1)) = E^(2^j) ∘ E^(2^j), state in LA/LC/LJ/LL ----
  for (int j = 0; j < 7 && (2 << j) <= P.N0cap - 1; ++j) {
    mm2<0,0,0,LDW, 1,0,0,LDW>(W0, LC,LDW, LL,LDW, nullptr,0,
                              W2, LL,LDW, LA,LDW, nullptr,0);      // Pm = C L ; T1 = L^T A
    mm<1,0,0,LDW>(W1, LL,LDW, W0,LDW, nullptr,0);                  // W = L^T Pm
    if (tid < 64) W1[tid*LDW + tid] += 1.f;
    __syncthreads();
    chol68<false>(W1, part, iv1);                                   // Lw = chol(I+W)
    tri_fwd2<0,1>(W1, iv1, W2,LDW, W2,LDW,
                  W1, iv1, W0,LDW, W3,LDW);                         // T2f = Lw^-1 T1 ; T5 = Lw^-1 Pm^T
    mm2<1,0,1,LDW, 1,0,2,LDW>(LJ, W2,LDW, W2,LDW, LJ,LDW,
                              W4, W3,LDW, W3,LDW, LC,LDW);          // Jn = T2f^T T2f + J ; ZC = C - T5^T T5
    copyW(LL, LJ);
    chol68<false>(LL, part, iv2);                                   // Ln = chol(Jn)
    tri_bwd_ld(W1, iv1, W2,LDW, W2,LDW);                            // T2 = Lw^-T T2f
    mm<0,0,2,LDW>(W3, W0,LDW, W2,LDW, LA,LDW);                      // ZA = A - Pm T2
    mm2<0,0,0,LDW, 0,0,0,LDW>(W2, LA,LDW, W3,LDW, nullptr,0,
                              W0, LA,LDW, W4,LDW, nullptr,0);       // An = A ZA ; T7 = A ZC
    mm<0,1,1,LDW>(LC, W0,LDW, LA,LDW, LC,LDW);                      // Cn = T7 A^T + C
    copyW(LA, W2);
    l2g3(P.EA+(size_t)(j+1)*4096, LA, P.EC+(size_t)(j+1)*4096, LC,
         P.EL+(size_t)(j+1)*4096, LL);
  }
}

// block t: fP_t = C of a1 ∘ E^t, by combining set bits of t (ascending).
__global__ __launch_bounds__(256) void kB(KP P) {
  __shared__ __align__(16) float Wc[LDW*NN], W0[LDW*NN], W1[LDW*NN], W2[LDW*NN];
  __shared__ float part[64], ivw[64];
  const int t = blockIdx.x;
  if (t == 0) return;                       // fP0 written by kA
  g2l(Wc, P.fP);                            // acc.C = fP0
  int rem = t;
  for (int j = 0; rem; ++j, rem >>= 1) {
    if (!(rem & 1)) continue;
    const float* Ag = P.EA + j*4096;
    const float* Cg = P.EC + j*4096;
    const float* Lg = P.EL + j*4096;
    mm<0,0,0,LDW>(W0, Wc, LDW, Lg, NN, nullptr, 0);     // Pm = C L
    mm<1,0,0,LDW>(W1, Lg, NN, W0, LDW, nullptr, 0);     // W = L^T Pm
    if (threadIdx.x < 64) W1[threadIdx.x*LDW + threadIdx.x] += 1.f;
    __syncthreads();
    chol68<false>(W1, part, ivw);                        // Lw
    tri_fwd_ld<1>(W1, ivw, W0, LDW, W2, LDW);           // T5 = Lw^-1 Pm^T
    mm<1,0,2,LDW>(W1, W2, LDW, W2, LDW, Wc, LDW);       // ZC = C - T5^T T5
    mm<0,0,0,LDW>(W0, Ag, NN, W1, LDW, nullptr, 0);     // T7 = A ZC
    mm<0,1,1,LDW>(Wc, W0, LDW, Ag, NN, Cg, NN);         // C' = T7 A^T + C
  }
  l2g(P.fP + (size_t)t*4096, Wc);
}

// per-t maxabs + maxdiff of fP (parallel)
__global__ __launch_bounds__(256) void kC(KP P) {
  __shared__ float red[16];
  const int t = blockIdx.x;
  const float* cur = P.fP + (size_t)t*4096;
  const float* prv = P.fP + (size_t)(t > 0 ? t-1 : 0)*4096;
  float a = 0.f, d = 0.f;
  for (int e = threadIdx.x*4; e < 4096; e += 1024) {
    F4 v, pv; v.v = *(const float4*)(cur + e); pv.v = *(const float4*)(prv + e);
    #pragma unroll
    for (int q = 0; q < 4; ++q) {
      a = fmaxf(a, fabsf(v.f[q]));
      d = fmaxf(d, fabsf(v.f[q] - pv.f[q]));
    }
  }
  redpair(a, d, red);
  if (threadIdx.x == 0) { P.astat[t] = a; P.dstat[t] = (t > 0) ? d : 0.f; }
}

// replicate the original stall/convergence selection of N0 (scalar, tiny)
__global__ __launch_bounds__(256) void kN(KP P) {
  __shared__ float as_[N0MAX], ds_[N0MAX];
  const int cap = P.N0cap;
  for (int i = threadIdx.x; i < cap; i += 256) { as_[i] = P.astat[i]; ds_[i] = P.dstat[i]; }
  __syncthreads();
  if (threadIdx.x == 0) {
    float mabs = 1e-20f, dref = 1e30f;
    int tref = 0, N0 = cap;
    bool conv = false;
    for (int t = 0; t < cap; ++t) {
      mabs = fmaxf(mabs, as_[t]);
      if (t > 0) {
        float d = ds_[t];
        if (d <= EPS_HARD*mabs) { N0 = t+1; conv = true; }
        if (d < STALL_IMP*dref) { dref = d; tref = t; }
        else if (t - tref >= STALL_WIN && t >= 12 && d < EPS_GATE*mabs) { N0 = t+1; conv = true; }
      }
      if (conv) break;
    }
    P.meta[0] = N0; P.metaF[1] = mabs;
  }
}

// pP_t for t in [0, cap]: pP_0 = P0; pP_t = A fP_{t-1} A^T + Q  (parallel)
__global__ __launch_bounds__(256) void kP(KP P) {
  __shared__ __align__(16) float W0[LDW*NN], W1[LDW*NN];
  const int t = blockIdx.x;
  if (t == 0) {
    for (int e = threadIdx.x*4; e < 4096; e += 1024)
      *(float4*)(P.pP + e) = *(const float4*)(P.P0 + e);
    return;
  }
  mm<0,0,0,LDW>(W1, P.A, NN, P.fP + (size_t)(t-1)*4096, NN, nullptr, 0);
  mm<0,0,1,LDW>(W0, W1, LDW, P.AT, NN, P.Q, NN);
  l2g(P.pP + (size_t)t*4096, W0);
}

// steady-state derived quantities + Stein solve
__global__ __launch_bounds__(256) void k1ss(KP P) {
  __shared__ __align__(16) float W0[LDW*NN], W1[LDW*NN], W2[LDW*NN], W3[LDW*NN], W4[LDW*NN], CH[LDW*NN];
  __shared__ float part[64], invd[64];
  const int tid = threadIdx.x;
  const int N0 = P.meta[0];
  const float* fPssG = P.fP + (size_t)(N0-1)*4096;
  g2l(CH, fPssG);                                             // fP_ss
  mm<0,0,0,LDW>(W1, P.A, NN, CH, LDW, nullptr, 0);            // A*fP_ss
  mm<0,0,1,LDW>(W0, W1, LDW, P.AT, NN, P.Q, NN);              // pP_ss
  l2g(P.pPss, W0);
  mm<0,0,0,LDW>(W1, P.H, NN, W0, LDW, nullptr, 0);            // HP
  mm<0,0,1,LDW>(CH, W1, LDW, P.HT, NN, P.R, NN);              // S
  chol68<true>(CH, part, invd);
  if (tid == 0) { float s=0.f; for (int j=0;j<64;++j) s += part[j]; P.metaF[0] = s; }
  set_id(W0);
  tri_s2x2(CH, invd, W1, W0);                                 // X ; Sinv (batched)
  l2g_T(P.Kss, W1);                                           // K_ss = X^T
  if (tid < 64) {
    float s = P.b[tid];
    for (int k = 0; k < 64; ++k) s -= W1[k*LDW + tid]*P.Hb[k];
    P.uss[tid] = s;                                           // u_ss = (I-KH) b
  }
  __syncthreads();
  l2g(P.Sinvss, W0);
  mm<1,0,2,LDW>(W0, W1, LDW, P.HA, NN, P.A, NN);              // F_ss = A - X^T*HA
  l2g(P.Fss, W0);
  // C_ss = (pP_ss^{-1} A fP_ss)^T
  mm<0,0,0,LDW>(W1, P.A, NN, fPssG, NN, nullptr, 0);          // AF (B global)
  g2l(CH, P.pPss);
  chol68<false>(CH, part, invd);
  tri_solve2(CH, invd, W1, W1);                               // X2 = C^T
  l2g(P.CsTss, W1);
  l2g_T(P.Css, W1);
  // ---- C powers ∥ F powers (batched) ----
  g2l(W0, P.Css);
  g2l(W3, P.Fss);
  mm2<0,0,0,LDW, 0,0,0,LDW>(W1, W0,LDW, W0,LDW, nullptr,0,
                            W4, W3,LDW, W3,LDW, nullptr,0);   // C2 ; F2
  l2g(P.Pw2, W1);
  mm2<0,0,0,LDW, 0,0,0,LDW>(W2, W1,LDW, W1,LDW, nullptr,0,
                            W3, W4,LDW, W4,LDW, nullptr,0);   // C4 ; F4
  l2g(P.Pw4, W2);
  mm2<0,0,0,LDW, 0,0,0,LDW>(W0, W2,LDW, W2,LDW, nullptr,0,
                            W4, W3,LDW, W3,LDW, nullptr,0);   // C8 ; F8
  l2g(P.Pw8, W0);
  mm2<0,0,0,LDW, 0,0,0,LDW>(W1, W0,LDW, W0,LDW, nullptr,0,
                            W3, W4,LDW, W4,LDW, nullptr,0);   // C16 ; F16
  l2g(P.Pw16, W1);
  mm2<0,0,0,LDW, 0,0,0,LDW>(W4, W1,LDW, W1,LDW, nullptr,0,
                            CH, W3,LDW, W3,LDW, nullptr,0);   // C32 ; F32
  l2g(P.Cpow32, W4);
  l2g(P.Fpow, CH);
  mm2<0,0,0,LDW, 0,0,0,LDW>(CH, W4,LDW, W4,LDW, nullptr,0,
                            W3, W1,LDW, W0,LDW, nullptr,0);   // C64 ; C24 = C16*C8
  l2g(P.Pw64, CH);
  mm2<0,0,0,LDW, 0,0,0,LDW>(W1, CH,LDW, CH,LDW, nullptr,0,
                            W0, W3,LDW, W2,LDW, nullptr,0);   // C128 ; C28 = C24*C4
  l2g(P.Pw128, W1);
  mm<0,0,0,LDW>(W2, W0, LDW, P.Pw2, NN, nullptr, 0);          // C30 = C28*C2
  mm<0,0,0,LDW>(W0, W2, LDW, P.Css, NN, nullptr, 0);          // C31
  l2g(P.Cpow31, W0);
  // ---- Stein solve: 7 doublings with mm2 + pointer swap ----
  g2l(W1, P.Css);                                             // M
  g2l(W2, P.CsTss);                                           // M'
  g2l(W0, P.pPss);
  mm<0,0,0,LDW>(CH, W1, LDW, W0, LDW, nullptr, 0);            // C*pPss
  mm<0,0,2,LDW>(W0, CH, LDW, W2, LDW, fPssG, NN);             // X = fPss - (C pPss) C'
  {
    float *m1 = W1, *m2 = W2, *t1 = W3, *t2 = W4;
    for (int it = 0; it < 7; ++it) {
      mm2<0,0,0,LDW, 0,0,0,LDW>(CH, m1,LDW, W0,LDW, nullptr,0,
                                t1, m1,LDW, m1,LDW, nullptr,0);   // M*X ; M^2
      mm2<0,0,1,LDW, 0,0,0,LDW>(W0, CH,LDW, m2,LDW, W0,LDW,
                                t2, m2,LDW, m2,LDW, nullptr,0);   // X += (MX)M' ; M'^2
      float* tmp = m1; m1 = t1; t1 = tmp;
      tmp = m2; m2 = t2; t2 = tmp;
    }
  }
  l2g(P.sPss, W0);
  rsub_store(P.E0g, fPssG, W0);                               // E0 = fPss - sPss
}

// parallel closed-form tail: sP_{T-1-k} = sPss + C^k E0 C'^k
__global__ __launch_bounds__(256) void k1d(KP P) {
  __shared__ __align__(16) float W0[LDW*NN], W1[LDW*NN], W2[LDW*NN];
  const int k = blockIdx.x;
  float* dst = P.out_cov + (size_t)(P.T-1-k)*4096;
  if (k == 0) {
    const float* src = P.fP + (size_t)(P.meta[0]-1)*4096;
    for (int e = threadIdx.x*4; e < 4096; e += 1024)
      *(float4*)(dst+e) = *(const float4*)(src+e);
    return;
  }
  const float* pw[8] = {P.Css, P.Pw2, P.Pw4, P.Pw8, P.Pw16, P.Cpow32, P.Pw64, P.Pw128};
  int b = __ffs(k) - 1;
  g2l(W1, pw[b]);
  float* cur = W1; float* oth = W0;
  for (int j = b+1; j < 8; ++j) {
    if ((k >> j) & 1) {
      mm<0,0,0,LDW>(oth, pw[j], NN, cur, LDW, nullptr, 0);
      float* tmp = cur; cur = oth; oth = tmp;
    }
  }
  mm<0,0,0,LDW>(W2, cur, LDW, P.E0g, NN, nullptr, 0);         // M*E0
  mm<0,1,1,LDW>(oth, W2, LDW, cur, LDW, P.sPss, NN);          // + (M E0) M^T + sPss
  l2g(dst, oth);
}

// parallel per-prefix-t derived quantities (+ per-t logdet)
__global__ __launch_bounds__(256) void k1b(KP P) {
  __shared__ __align__(16) float W0[LDW*NN], W1[LDW*NN], CH[LDW*NN];
  __shared__ float part[64], invd[64];
  const int t = blockIdx.x;
  if (t >= P.meta[0]) return;
  mm<0,0,0,LDW>(W1, P.H, NN, P.pP + (size_t)t*4096, NN, nullptr, 0);  // HP (B global)
  mm<0,0,1,LDW>(CH, W1, LDW, P.HT, NN, P.R, NN);              // S
  chol68<true>(CH, part, invd);
  if (threadIdx.x == 0) { float s=0.f; for (int j=0;j<64;++j) s += part[j]; P.ld_pref[t] = s; }
  set_id(W0);
  tri_s2x2(CH, invd, W1, W0);                                 // X ; Sinv (batched)
  l2g_T(P.Kp + (size_t)t*4096, W1);
  if (threadIdx.x < 64) {
    float s = P.b[threadIdx.x];
    for (int k = 0; k < 64; ++k) s -= W1[k*LDW + threadIdx.x]*P.Hb[k];
    P.u_pref[t*64 + threadIdx.x] = s;
  }
  __syncthreads();
  l2g(P.Sinvp + (size_t)t*4096, W0);
  mm<1,0,2,LDW>(W0, W1, LDW, P.HA, NN, P.A, NN);              // F_t
  l2g(P.Fp + (size_t)t*4096, W0);
  // C_t
  mm<0,0,0,LDW>(W1, P.A, NN, P.fP + (size_t)t*4096, NN, nullptr, 0);  // AF (B global)
  g2l(CH, P.pP + (size_t)(t+1)*4096);
  chol68<false>(CH, part, invd);
  tri_solve2(CH, invd, W1, W1);                               // X2
  l2g(P.CsTp + (size_t)t*4096, W1);
  l2g_T(P.Cp + (size_t)t*4096, W1);
}

// ---------------------------------------------------------------------------
// Smoothed-cov prefix as a PARALLEL suffix scan (global operands, 2 ops/level)
// ---------------------------------------------------------------------------

__global__ __launch_bounds__(256) void k1cI(KP P) {
  __shared__ __align__(16) float W1[LDW*NN];
  const int t = blockIdx.x;
  if (t >= P.meta[0]) return;
  const float* Cg = P.Cp + (size_t)t*4096;
  for (int e = threadIdx.x*4; e < 4096; e += 1024)
    *(float4*)(P.scM0 + (size_t)t*4096 + e) = *(const float4*)(Cg + e);
  mm<0,0,0,LDW>(W1, Cg, NN, P.pP + (size_t)(t+1)*4096, NN, nullptr, 0);   // C*pP
  mm<0,0,2,NN>(P.scG0 + (size_t)t*4096, W1, LDW,
               P.CsTp + (size_t)t*4096, NN, P.fP + (size_t)t*4096, NN);   // G = fP - (C pP) C^T
}

__global__ __launch_bounds__(256) void k1cL(KP P, int step, int sidx) {
  __shared__ __align__(16) float W1[LDW*NN];
  const int t = blockIdx.x;
  const int N0 = P.meta[0];
  if (t >= N0) return;
  const float* Msrc = sidx ? P.scM1 : P.scM0;
  const float* Gsrc = sidx ? P.scG1 : P.scG0;
  float* Mdst = sidx ? P.scM0 : P.scM1;
  float* Gdst = sidx ? P.scG0 : P.scG1;
  const int s = t + step;
  if (s >= N0) {   // identity on the right: pass through
    for (int e = threadIdx.x*4; e < 4096; e += 1024) {
      *(float4*)(Mdst + (size_t)t*4096 + e) = *(const float4*)(Msrc + (size_t)t*4096 + e);
      *(float4*)(Gdst + (size_t)t*4096 + e) = *(const float4*)(Gsrc + (size_t)t*4096 + e);
    }
    return;
  }
  const float* Mt = Msrc + (size_t)t*4096;
  // W1 = Mt*Gs ; Mdst[t] = Mt*Ms  (batched; operands global)
  mm2<0,0,0,LDW, 0,0,0,NN>(W1, Mt,NN, Gsrc + (size_t)s*4096,NN, nullptr,0,
                           Mdst + (size_t)t*4096, Mt,NN, Msrc + (size_t)s*4096,NN, nullptr,0);
  // Gdst[t] = (Mt Gs) Mt^T + Gt
  mm<0,1,1,NN>(Gdst + (size_t)t*4096, W1, LDW, Mt, NN, Gsrc + (size_t)t*4096, NN);
}

__global__ __launch_bounds__(256) void k1cF(KP P) {
  __shared__ __align__(16) float W1[LDW*NN];
  const int t = blockIdx.x;
  if (t >= P.meta[0]) return;
  const float* Mt = P.scM0 + (size_t)t*4096;
  mm<0,0,0,LDW>(W1, Mt, NN, P.sPss, NN, nullptr, 0);                      // M*sPss
  mm<0,1,1,NN>(P.out_cov + (size_t)t*4096, W1, LDW, Mt, NN,
               P.scG0 + (size_t)t*4096, NN);                              // + M^T, + G
}

// fill steady middle region of smoothed covs
__global__ __launch_bounds__(256) void k4(KP P) {
  const int t = blockIdx.x;
  if (t < P.meta[0] || t >= P.T - N1CAP) return;
  float* dst = P.out_cov + (size_t)t*4096;
  for (int e = threadIdx.x*4; e < 4096; e += 1024)
    *(float4*)(dst+e) = *(const float4*)(P.sPss + e);
}

// forward mean scan: local pass (steady chunks, zero init)
__global__ __launch_bounds__(256) void k2a(KP P) {
  __shared__ float xv[64], gv[64], ty[64], red[256];
  const int c = blockIdx.x;
  const int N0 = P.meta[0];
  const int PB = (N0 + LCH - 1)/LCH;
  if (c < PB) return;
  const int tid = threadIdx.x;
  if (tid < 64) xv[tid] = 0.f;
  __syncthreads();
  for (int s = 0; s < LCH; ++s) {
    int t = c*LCH + s;
    if (tid < 64) ty[tid] = P.Y[(size_t)t*64+tid] - P.c[tid];
    __syncthreads();
    matvec256(gv, P.Kss, ty, P.uss, red);
    matvec256(xv, P.Fss, xv, gv, red);
  }
  if (tid < 64) P.u_chunk[c*64+tid] = xv[tid];
}

// forward mean scan: sequential prefix + chunk carries
__global__ __launch_bounds__(256) void k2b(KP P) {
  __shared__ float xv[64], gv[64], ty[64], hp[64], red[256];
  const int tid = threadIdx.x;
  const int N0 = P.meta[0];
  const int PB = (N0 + LCH - 1)/LCH;
  const int PE = PB*LCH;
  if (tid < 64) xv[tid] = P.pm0[tid];
  __syncthreads();
  matvec256(hp, P.H, xv, nullptr, red);
  if (tid < 64) ty[tid] = P.Y[tid] - hp[tid] - P.c[tid];
  __syncthreads();
  matvec256(xv, P.Kp, ty, xv, red);            // fm0 = pm0 + K0*r0
  if (tid < 64) P.fm[tid] = xv[tid];
  __syncthreads();
  for (int t = 1; t < PE; ++t) {
    const float* Kt = (t < N0) ? P.Kp + (size_t)t*4096 : P.Kss;
    const float* Ft = (t < N0) ? P.Fp + (size_t)t*4096 : P.Fss;
    const float* ut = (t < N0) ? P.u_pref + t*64 : P.uss;
    if (tid < 64) ty[tid] = P.Y[(size_t)t*64+tid] - P.c[tid];
    __syncthreads();
    matvec256(gv, Kt, ty, ut, red);
    matvec256(xv, Ft, xv, gv, red);
    if (tid < 64) P.fm[(size_t)t*64+tid] = xv[tid];
    __syncthreads();
  }
  for (int c = PB; c < P.NC; ++c) {
    if (tid < 64) P.startstate[c*64+tid] = xv[tid];
    __syncthreads();
    matvec256(xv, P.Fpow, xv, P.u_chunk + c*64, red);
  }
}

// forward mean scan: replay steady chunks with true start states
__global__ __launch_bounds__(256) void k2c(KP P) {
  __shared__ float xv[64], gv[64], ty[64], red[256];
  const int c = blockIdx.x;
  const int N0 = P.meta[0];
  const int PB = (N0 + LCH - 1)/LCH;
  if (c < PB) return;
  const int tid = threadIdx.x;
  if (tid < 64) xv[tid] = P.startstate[c*64+tid];
  __syncthreads();
  for (int s = 0; s < LCH; ++s) {
    int t = c*LCH + s;
    if (tid < 64) ty[tid] = P.Y[(size_t)t*64+tid] - P.c[tid];
    __syncthreads();
    matvec256(gv, P.Kss, ty, P.uss, red);
    matvec256(xv, P.Fss, xv, gv, red);
    if (tid < 64) P.fm[(size_t)t*64+tid] = xv[tid];
    __syncthreads();
  }
}

// log-likelihood terms (one wave per t) -> llbuf
__global__ __launch_bounds__(64) void k5(KP P) {
  __shared__ float pmv[64], rv[64];
  const int t = blockIdx.x;
  const int N0 = P.meta[0];
  const int r = threadIdx.x;
  float pm;
  if (t == 0) {
    pm = P.pm0[r];
  } else {
    pmv[r] = P.fm[(size_t)(t-1)*64 + r];
    __syncthreads();
    float s = P.b[r];
    const float* Ar = P.A + r*64;
    for (int k = 0; k < 64; k += 4)
      s += Ar[k]*pmv[k] + Ar[k+1]*pmv[k+1] + Ar[k+2]*pmv[k+2] + Ar[k+3]*pmv[k+3];
    pm = s;
    __syncthreads();
  }
  pmv[r] = pm; __syncthreads();
  float rr = P.Y[(size_t)t*64 + r] - P.c[r];
  const float* Hr = P.H + r*64;
  for (int k = 0; k < 64; ++k) rr -= Hr[k]*pmv[k];
  rv[r] = rr; __syncthreads();
  const float* Sv = ((t < N0) ? P.Sinvp + (size_t)t*4096 : P.Sinvss) + r*64;
  float wv = 0.f;
  for (int k = 0; k < 64; ++k) wv += Sv[k]*rv[k];
  float qq = rr*wv;
  #pragma unroll
  for (int off = 32; off > 0; off >>= 1) qq += __shfl_xor(qq, off, 64);
  if (r == 0) {
    float ldt = (t < N0) ? P.ld_pref[t] : P.metaF[0];
    P.llbuf[t] = -58.8120661250990555 - (double)ldt - 0.5*(double)qq;
  }
}

// backward mean scan: local pass
__global__ __launch_bounds__(256) void k3a(KP P) {
  __shared__ float sv[64], wv[64], vv[64], fmv[64], red[256];
  const int c = blockIdx.x;
  const int N0 = P.meta[0];
  const int PB = (N0 + LCH - 1)/LCH;
  if (c < PB) return;
  const int tid = threadIdx.x;
  if (tid < 64) sv[tid] = 0.f;
  __syncthreads();
  int hi = (c == P.NC-1) ? P.T-2 : c*LCH + LCH - 1;
  for (int t = hi; t >= c*LCH; --t) {
    if (tid < 64) fmv[tid] = P.fm[(size_t)t*64+tid];
    __syncthreads();
    matvec256(wv, P.A, fmv, P.b, red);
    if (tid < 64) vv[tid] = sv[tid] - wv[tid];
    __syncthreads();
    matvec256(sv, P.Css, vv, fmv, red);
  }
  if (tid < 64) P.ub_chunk[c*64+tid] = sv[tid];
}

// backward mean scan: carries + sequential prefix
__global__ __launch_bounds__(256) void k3b(KP P) {
  __shared__ float sv[64], wv[64], vv[64], fmv[64], red[256];
  const int tid = threadIdx.x;
  const int N0 = P.meta[0];
  const int PB = (N0 + LCH - 1)/LCH;
  const int PE = PB*LCH;
  if (tid < 64) {
    float v = P.fm[(size_t)(P.T-1)*64+tid];
    sv[tid] = v;
    P.out_mean[(size_t)(P.T-1)*64+tid] = v;
  }
  __syncthreads();
  for (int c = P.NC-1; c >= PB; --c) {
    if (tid < 64) P.endstate[c*64+tid] = sv[tid];
    __syncthreads();
    matvec256(sv, (c == P.NC-1) ? P.Cpow31 : P.Cpow32, sv, P.ub_chunk + c*64, red);
  }
  for (int t = PE-1; t >= 0; --t) {
    const float* Ct = (t < N0) ? P.Cp + (size_t)t*4096 : P.Css;
    if (tid < 64) fmv[tid] = P.fm[(size_t)t*64+tid];
    __syncthreads();
    matvec256(wv, P.A, fmv, P.b, red);
    if (tid < 64) vv[tid] = sv[tid] - wv[tid];
    __syncthreads();
    matvec256(sv, Ct, vv, fmv, red);
    if (tid < 64) P.out_mean[(size_t)t*64+tid] = sv[tid];
    __syncthreads();
  }
}

// backward mean scan: replay steady chunks
__global__ __launch_bounds__(256) void k3c(KP P) {
  __shared__ float sv[64], wv[64], vv[64], fmv[64], red[256];
  const int c = blockIdx.x;
  const int N0 = P.meta[0];
  const int PB = (N0 + LCH - 1)/LCH;
  if (c < PB) return;
  const int tid = threadIdx.x;
  if (tid < 64) sv[tid] = P.endstate[c*64+tid];
  __syncthreads();
  int hi = (c == P.NC-1) ? P.T-2 : c*LCH + LCH - 1;
  for (int t = hi; t >= c*LCH; --t) {
    if (tid < 64) fmv[tid] = P.fm[(size_t)t*64+tid];
    __syncthreads();
    matvec256(wv, P.A, fmv, P.b, red);
    if (tid < 64) vv[tid] = sv[tid] - wv[tid];
    __syncthreads();
    matvec256(sv, P.Css, vv, fmv, red);
    if (tid < 64) P.out_mean[(size_t)t*64+tid] = sv[tid];
    __syncthreads();
  }
}

// reduce per-t ll terms
__global__ __launch_bounds__(256) void k6(KP P) {
  __shared__ double rd[256];
  double s = 0.0;
  for (int t = threadIdx.x; t < P.T; t += 256) s += P.llbuf[t];
  rd[threadIdx.x] = s; __syncthreads();
  #pragma unroll
  for (int off = 128; off > 0; off >>= 1) {
    if ((int)threadIdx.x < off) rd[threadIdx.x] += rd[threadIdx.x + off];
    __syncthreads();
  }
  if (threadIdx.x == 0) P.out_ll[0] = (float)rd[0];
}

// ---------- host ----------

extern "C" void kernel_launch(void* const* d_in, const int* in_sizes, int n_in,
                              void* d_out, int out_size, void* d_ws, size_t ws_size,
                              hipStream_t stream) {
  (void)n_in; (void)out_size;
  KP P;
  P.Y   = (const float*)d_in[0];
  P.A   = (const float*)d_in[1];
  P.b   = (const float*)d_in[2];
  P.Q   = (const float*)d_in[3];
  P.H   = (const float*)d_in[4];
  P.c   = (const float*)d_in[5];
  P.R   = (const float*)d_in[6];
  P.pm0 = (const float*)d_in[7];
  P.P0  = (const float*)d_in[8];
  const int T = in_sizes[0] / 64;
  const int NC = T / LCH;
  P.T = T; P.NC = NC;

  float* out = (float*)d_out;
  P.out_mean = out;
  P.out_cov  = out + (size_t)T*64;
  P.out_ll   = out + (size_t)T*64 + (size_t)T*4096;

  float* w = (float*)d_ws;
  size_t off = 0;
  auto alloc = [&](size_t n) { float* p = w + off; off += n; return p; };
  P.meta   = (int*)alloc(8);
  P.metaF  = alloc(8);
  P.llbuf  = (double*)alloc((size_t)2*T);
  P.fm     = alloc((size_t)T*64);
  P.AT = alloc(4096); P.HT = alloc(4096); P.HA = alloc(4096); P.Hb = alloc(64);
  P.Fss = alloc(4096); P.Kss = alloc(4096); P.Sinvss = alloc(4096);
  P.Css = alloc(4096); P.CsTss = alloc(4096); P.pPss = alloc(4096); P.sPss = alloc(4096);
  P.Fpow = alloc(4096); P.Cpow32 = alloc(4096); P.Cpow31 = alloc(4096); P.uss = alloc(64);
  P.Pw2 = alloc(4096); P.Pw4 = alloc(4096); P.Pw8 = alloc(4096); P.Pw16 = alloc(4096);
  P.Pw64 = alloc(4096); P.Pw128 = alloc(4096);
  P.u_chunk = alloc((size_t)NC*64); P.startstate = alloc((size_t)NC*64);
  P.ub_chunk = alloc((size_t)NC*64); P.endstate = alloc((size_t)NC*64);
  P.E0g = alloc(4096);
  P.EA = alloc((size_t)8*4096); P.EC = alloc((size_t)8*4096);
  P.EJ = alloc((size_t)8*4096); P.EL = alloc((size_t)8*4096);
  P.astat = alloc(256); P.dstat = alloc(256);
  // prefix arrays sized by remaining workspace
  size_t fixed = off;
  size_t per_t = 11*4096 + 64 + 1;   // incl. 4 scan ping-pong buffers
  size_t total_f = ws_size / 4;
  long long avail = (long long)total_f - (long long)fixed - 4096 - 64;
  int cap = (avail > 0) ? (int)(avail / (long long)per_t) : 8;
  if (cap > N0MAX) cap = N0MAX;
  if (cap < 8) cap = 8;
  P.N0cap = cap;
  P.ld_pref = alloc(cap);
  P.u_pref  = alloc((size_t)cap*64);
  P.fP    = alloc((size_t)cap*4096);
  P.pP    = alloc((size_t)(cap+1)*4096);
  P.Kp    = alloc((size_t)cap*4096);
  P.Sinvp = alloc((size_t)cap*4096);
  P.Fp    = alloc((size_t)cap*4096);
  P.Cp    = alloc((size_t)cap*4096);
  P.CsTp  = alloc((size_t)cap*4096);
  P.scM0  = alloc((size_t)cap*4096);
  P.scM1  = alloc((size_t)cap*4096);
  P.scG0  = alloc((size_t)cap*4096);
  P.scG1  = alloc((size_t)cap*4096);

  k0<<<1, 256, 0, stream>>>(P);
  kA<<<1, 256, 0, stream>>>(P);          // leaf + fP0 + E^(2^j) doublings (batched, LDS-resident)
  kB<<<cap, 256, 0, stream>>>(P);        // all prefix fP_t in parallel
  kC<<<cap, 256, 0, stream>>>(P);        // per-t maxabs/maxdiff
  kN<<<1, 256, 0, stream>>>(P);          // N0 selection
  kP<<<cap+1, 256, 0, stream>>>(P);      // pP_t in parallel
  k1ss<<<1, 256, 0, stream>>>(P);        // steady-state derived + Stein (batched)
  k1b<<<cap, 256, 0, stream>>>(P);
  k1d<<<N1CAP, 256, 0, stream>>>(P);
  k4<<<T, 256, 0, stream>>>(P);
  // smoothed-cov prefix: parallel suffix scan
  k1cI<<<cap, 256, 0, stream>>>(P);
  {
    int sidx = 0;
    for (int d = 0; d < 8; ++d) { k1cL<<<cap, 256, 0, stream>>>(P, 1 << d, sidx); sidx ^= 1; }
  }
  k1cF<<<cap, 256, 0, stream>>>(P);
  k2a<<<NC, 256, 0, stream>>>(P);
  k2b<<<1, 256, 0, stream>>>(P);
  k2c<<<NC, 256, 0, stream>>>(P);
  k5<<<T, 64, 0, stream>>>(P);
  k3a<<<NC, 256, 0, stream>>>(P);
  k3b<<<1, 256, 0, stream>>>(P);
  k3c<<<NC, 256, 0, stream>>>(P);
  k6<<<1, 256, 0, stream>>>(P);
}

// Round 5
// 2107.216 us; speedup vs baseline: 1.8680x; 1.0668x over previous
//
#include <hip/hip_runtime.h>
#include <math.h>

#define NN 64
#define LDW 68      // padded LDS stride (float4-aligned)
#define LCH 32      // mean-scan chunk length
#define N1CAP 144   // smoother-cov tail length (closed-form, parallel)
#define N0MAX 144   // forward Riccati cap
#define EPS_HARD 1e-5f
#define EPS_GATE 5e-2f
#define STALL_WIN 5
#define STALL_IMP 0.75f

struct KP {
  const float *Y, *A, *b, *Q, *H, *c, *R, *pm0, *P0;
  float *out_mean, *out_cov, *out_ll;
  int *meta; float *metaF;
  float *fm;
  float *AT, *HT, *HA, *Hb;
  float *Fss, *Kss, *Sinvss, *Css, *CsTss, *pPss, *sPss, *Fpow, *Cpow32, *Cpow31, *uss;
  float *Pw2, *Pw4, *Pw8, *Pw16, *Pw64, *Pw128;
  float *Dmss, *dvnss;                    // I - Css*A ; -Css*b (fused backward scan)
  float *u_chunk, *startstate, *ub_chunk, *endstate;
  float *ld_pref, *u_pref;
  double *llbuf;
  float *E0g;
  // scan-element powers E^(2^j), j=0..5: A, C, J, L=chol(J)
  float *EA, *EC, *EJ, *EL;
  float *astat, *dstat;
  // smoothed-cov suffix-scan ping-pong buffers
  float *scM0, *scM1, *scG0, *scG1;
  float *fP, *pP, *Kp, *Sinvp, *Fp, *Cp, *CsTp, *Dmp, *dvnp;
  int N0cap, T, NC;
};

union F4 { float4 v; float f[4]; };

// ---------- helpers (blockDim.x == 256 unless noted) ----------

__device__ __forceinline__ void g2l(float* W, const float* G) {
  for (int e = threadIdx.x*4; e < 4096; e += 1024) {
    float4 v = *(const float4*)(G + e);
    *(float4*)(W + (e>>6)*LDW + (e&63)) = v;
  }
  __syncthreads();
}
__device__ __forceinline__ void l2g(float* G, const float* W) {
  for (int e = threadIdx.x*4; e < 4096; e += 1024)
    *(float4*)(G + e) = *(const float4*)(W + (e>>6)*LDW + (e&63));
  __syncthreads();
}
__device__ __forceinline__ void l2g3(float* G1, const float* Wa,
                                     float* G2, const float* Wb,
                                     float* G3, const float* Wc) {
  for (int e = threadIdx.x*4; e < 4096; e += 1024) {
    int base = (e>>6)*LDW + (e&63);
    *(float4*)(G1 + e) = *(const float4*)(Wa + base);
    *(float4*)(G2 + e) = *(const float4*)(Wb + base);
    *(float4*)(G3 + e) = *(const float4*)(Wc + base);
  }
  __syncthreads();
}
__device__ __forceinline__ void l2g_T(float* G, const float* W) {
  for (int e = threadIdx.x; e < 4096; e += 256)
    G[e] = W[(e&63)*LDW + (e>>6)];
  __syncthreads();
}
__device__ __forceinline__ void copyW(float* D, const float* S) {
  for (int e = threadIdx.x*4; e < 4096; e += 1024) {
    int base = (e>>6)*LDW + (e&63);
    *(float4*)(D + base) = *(const float4*)(S + base);
  }
  __syncthreads();
}
__device__ __forceinline__ void set_id(float* W) {
  for (int e = threadIdx.x; e < 4096; e += 256)
    W[(e>>6)*LDW + (e&63)] = ((e>>6) == (e&63)) ? 1.f : 0.f;
  __syncthreads();
}
// G = I - W (LDS -> global)
__device__ __forceinline__ void store_id_sub(float* G, const float* W) {
  for (int e = threadIdx.x; e < 4096; e += 256)
    G[e] = (((e>>6) == (e&63)) ? 1.f : 0.f) - W[(e>>6)*LDW + (e&63)];
  __syncthreads();
}
// G_dst = G_src - W
__device__ __forceinline__ void rsub_store(float* Gd, const float* Gs, const float* W) {
  for (int e = threadIdx.x*4; e < 4096; e += 1024) {
    int base = (e>>6)*LDW + (e&63);
    F4 a, g; a.v = *(const float4*)(W + base); g.v = *(const float4*)(Gs + e);
    F4 o; o.f[0]=g.f[0]-a.f[0]; o.f[1]=g.f[1]-a.f[1]; o.f[2]=g.f[2]-a.f[2]; o.f[3]=g.f[3]-a.f[3];
    *(float4*)(Gd + e) = o.v;
  }
  __syncthreads();
}

__device__ __forceinline__ void redpair(float& ma, float& md, float* red) {
  #pragma unroll
  for (int off = 32; off; off >>= 1) {
    ma = fmaxf(ma, __shfl_xor(ma, off, 64));
    md = fmaxf(md, __shfl_xor(md, off, 64));
  }
  const int w = threadIdx.x >> 6;
  if ((threadIdx.x & 63) == 0) { red[w] = ma; red[4 + w] = md; }
  __syncthreads();
  ma = fmaxf(fmaxf(red[0], red[1]), fmaxf(red[2], red[3]));
  md = fmaxf(fmaxf(red[4], red[5]), fmaxf(red[6], red[7]));
  __syncthreads();
}

// D(stride LDD) = [ADD +/-] op(A)*op(B)
template<int TRANSA, int TRANSB, int MODE, int LDD>
__device__ __forceinline__ void mm(float* __restrict__ D,
    const float* __restrict__ A, int lda,
    const float* __restrict__ B, int ldb,
    const float* __restrict__ ADD, int ldadd)
{
  const int tid = threadIdx.x;
  const int i0 = (tid >> 4) << 2, j0 = (tid & 15) << 2;
  float acc[4][4] = {};
  for (int k0 = 0; k0 < NN; k0 += 4) {
    F4 av[4], bv[4];
    #pragma unroll
    for (int u = 0; u < 4; ++u) {
      bv[u].v = TRANSB ? *(const float4*)(B + (j0+u)*ldb + k0)
                       : *(const float4*)(B + (k0+u)*ldb + j0);
      av[u].v = TRANSA ? *(const float4*)(A + (k0+u)*lda + i0)
                       : *(const float4*)(A + (i0+u)*lda + k0);
    }
    #pragma unroll
    for (int kk = 0; kk < 4; ++kk) {
      #pragma unroll
      for (int di = 0; di < 4; ++di) {
        float a = TRANSA ? av[kk].f[di] : av[di].f[kk];
        #pragma unroll
        for (int dj = 0; dj < 4; ++dj) {
          float bb = TRANSB ? bv[dj].f[kk] : bv[kk].f[dj];
          acc[di][dj] += a * bb;
        }
      }
    }
  }
  #pragma unroll
  for (int di = 0; di < 4; ++di) {
    if (MODE == 0 && (LDD & 3) == 0) {
      F4 o;
      #pragma unroll
      for (int dj = 0; dj < 4; ++dj) o.f[dj] = acc[di][dj];
      *(float4*)(D + (i0+di)*LDD + j0) = o.v;
    } else {
      #pragma unroll
      for (int dj = 0; dj < 4; ++dj) {
        float v = acc[di][dj];
        if (MODE == 1) v = ADD[(i0+di)*ldadd + j0+dj] + v;
        if (MODE == 2) v = ADD[(i0+di)*ldadd + j0+dj] - v;
        D[(i0+di)*LDD + j0+dj] = v;
      }
    }
  }
  __syncthreads();
}

// two INDEPENDENT matmuls in one barrier region
template<int TA1,int TB1,int MO1,int LD1, int TA2,int TB2,int MO2,int LD2>
__device__ __forceinline__ void mm2(
    float* __restrict__ D1, const float* __restrict__ A1, int lda1,
    const float* __restrict__ B1, int ldb1, const float* __restrict__ AD1, int ldad1,
    float* __restrict__ D2, const float* __restrict__ A2, int lda2,
    const float* __restrict__ B2, int ldb2, const float* __restrict__ AD2, int ldad2)
{
  const int tid = threadIdx.x;
  const int i0 = (tid >> 4) << 2, j0 = (tid & 15) << 2;
  float acc1[4][4] = {}, acc2[4][4] = {};
  for (int k0 = 0; k0 < NN; k0 += 4) {
    F4 av1[4], bv1[4], av2[4], bv2[4];
    #pragma unroll
    for (int u = 0; u < 4; ++u) {
      bv1[u].v = TB1 ? *(const float4*)(B1 + (j0+u)*ldb1 + k0)
                     : *(const float4*)(B1 + (k0+u)*ldb1 + j0);
      av1[u].v = TA1 ? *(const float4*)(A1 + (k0+u)*lda1 + i0)
                     : *(const float4*)(A1 + (i0+u)*lda1 + k0);
      bv2[u].v = TB2 ? *(const float4*)(B2 + (j0+u)*ldb2 + k0)
                     : *(const float4*)(B2 + (k0+u)*ldb2 + j0);
      av2[u].v = TA2 ? *(const float4*)(A2 + (k0+u)*lda2 + i0)
                     : *(const float4*)(A2 + (i0+u)*lda2 + k0);
    }
    #pragma unroll
    for (int kk = 0; kk < 4; ++kk) {
      #pragma unroll
      for (int di = 0; di < 4; ++di) {
        float a1 = TA1 ? av1[kk].f[di] : av1[di].f[kk];
        float a2 = TA2 ? av2[kk].f[di] : av2[di].f[kk];
        #pragma unroll
        for (int dj = 0; dj < 4; ++dj) {
          acc1[di][dj] += a1 * (TB1 ? bv1[dj].f[kk] : bv1[kk].f[dj]);
          acc2[di][dj] += a2 * (TB2 ? bv2[dj].f[kk] : bv2[kk].f[dj]);
        }
      }
    }
  }
  #pragma unroll
  for (int di = 0; di < 4; ++di) {
    if (MO1 == 0 && (LD1 & 3) == 0) {
      F4 o;
      #pragma unroll
      for (int dj = 0; dj < 4; ++dj) o.f[dj] = acc1[di][dj];
      *(float4*)(D1 + (i0+di)*LD1 + j0) = o.v;
    } else {
      #pragma unroll
      for (int dj = 0; dj < 4; ++dj) {
        float v = acc1[di][dj];
        if (MO1 == 1) v = AD1[(i0+di)*ldad1 + j0+dj] + v;
        if (MO1 == 2) v = AD1[(i0+di)*ldad1 + j0+dj] - v;
        D1[(i0+di)*LD1 + j0+dj] = v;
      }
    }
  }
  #pragma unroll
  for (int di = 0; di < 4; ++di) {
    if (MO2 == 0 && (LD2 & 3) == 0) {
      F4 o;
      #pragma unroll
      for (int dj = 0; dj < 4; ++dj) o.f[dj] = acc2[di][dj];
      *(float4*)(D2 + (i0+di)*LD2 + j0) = o.v;
    } else {
      #pragma unroll
      for (int dj = 0; dj < 4; ++dj) {
        float v = acc2[di][dj];
        if (MO2 == 1) v = AD2[(i0+di)*ldad2 + j0+dj] + v;
        if (MO2 == 2) v = AD2[(i0+di)*ldad2 + j0+dj] - v;
        D2[(i0+di)*LD2 + j0+dj] = v;
      }
    }
  }
  __syncthreads();
}

// panel-16 Cholesky in stride-LDW buffer (256 threads). upper zeroed.
template<bool WANTLOG>
__device__ __forceinline__ void chol68(float* __restrict__ Sm, float* part, float* invd) {
  const int tid = threadIdx.x;
  const int lane = tid & 63;
  #pragma unroll
  for (int p = 0; p < 4; ++p) {
    const int j0 = p * 16;
    if (p > 0) {
      const int i = tid & 63;
      const int jq = (tid >> 6) * 4;
      float acc[4] = {0.f, 0.f, 0.f, 0.f};
      for (int kb = 0; kb < j0; kb += 4) {
        F4 av; av.v = *(const float4*)(Sm + i*LDW + kb);
        #pragma unroll
        for (int q = 0; q < 4; ++q) {
          F4 bv; bv.v = *(const float4*)(Sm + (j0 + jq + q)*LDW + kb);
          acc[q] += av.f[0]*bv.f[0] + av.f[1]*bv.f[1] + av.f[2]*bv.f[2] + av.f[3]*bv.f[3];
        }
      }
      #pragma unroll
      for (int q = 0; q < 4; ++q)
        Sm[i*LDW + j0 + jq + q] -= acc[q];
      __syncthreads();
    }
    if (tid < 64) {
      float t[16];
      F4 tv;
      #pragma unroll
      for (int q4 = 0; q4 < 4; ++q4) {
        tv.v = *(const float4*)(Sm + lane*LDW + j0 + 4*q4);
        t[4*q4] = tv.f[0]; t[4*q4+1] = tv.f[1]; t[4*q4+2] = tv.f[2]; t[4*q4+3] = tv.f[3];
      }
      #pragma unroll
      for (int jj = 0; jj < 16; ++jj) {
        float acc = t[jj];
        #pragma unroll
        for (int kk = 0; kk < jj; ++kk)
          acc -= __shfl(t[kk], j0 + jj, 64) * t[kk];
        float piv = __shfl(acc, j0 + jj, 64);
        float sq = sqrtf(fmaxf(piv, 1e-30f));
        float inv = 1.0f / sq;
        if (lane == j0 + jj) {
          t[jj] = sq;
          invd[j0 + jj] = inv;
          if (WANTLOG) part[j0 + jj] = logf(sq);
        } else {
          t[jj] = (lane > j0 + jj) ? acc * inv : 0.f;
        }
      }
      #pragma unroll
      for (int q4 = 0; q4 < 4; ++q4) {
        tv.f[0] = t[4*q4]; tv.f[1] = t[4*q4+1]; tv.f[2] = t[4*q4+2]; tv.f[3] = t[4*q4+3];
        *(float4*)(Sm + lane*LDW + j0 + 4*q4) = tv.v;
      }
    }
    __syncthreads();
  }
}

// forward triangular solve DST <- L^-1 op(SRC); TR=1 reads SRC transposed.
template<int TR>
__device__ __forceinline__ void tri_fwd_ld(const float* __restrict__ L,
                                           const float* __restrict__ invd,
                                           const float* __restrict__ SRC, int lds,
                                           float* __restrict__ DST, int ldd) {
  const int col = threadIdx.x >> 2, p = threadIdx.x & 3;
  const int gbase = (threadIdx.x & 63) & ~3;
  float xr[16];
  #pragma unroll
  for (int u = 0; u < 16; ++u)
    xr[u] = TR ? SRC[col*lds + (4*u+p)] : SRC[(4*u+p)*lds + col];
  #pragma unroll
  for (int i = 0; i < NN; ++i) {
    const int idx = i >> 2, ow = i & 3;
    float yi = xr[idx] * invd[i];
    yi = __shfl(yi, gbase + ow, 64);
    if (p == ow) xr[idx] = yi;
    else if (p > ow) xr[idx] -= L[(4*idx+p)*LDW + i] * yi;
    #pragma unroll
    for (int u = idx+1; u < 16; ++u)
      xr[u] -= L[(4*u+p)*LDW + i] * yi;
  }
  #pragma unroll
  for (int u = 0; u < 16; ++u) DST[(4*u+p)*ldd + col] = xr[u];
  __syncthreads();
}

// TWO independent forward solves (possibly different L) in one barrier region
template<int TR1,int TR2>
__device__ __forceinline__ void tri_fwd2(
    const float* __restrict__ L1, const float* __restrict__ ivd1,
    const float* __restrict__ S1, int lds1, float* __restrict__ D1, int ldd1,
    const float* __restrict__ L2, const float* __restrict__ ivd2,
    const float* __restrict__ S2, int lds2, float* __restrict__ D2, int ldd2)
{
  const int col = threadIdx.x >> 2, p = threadIdx.x & 3;
  const int gbase = (threadIdx.x & 63) & ~3;
  float xr[16], xs[16];
  #pragma unroll
  for (int u = 0; u < 16; ++u) {
    xr[u] = TR1 ? S1[col*lds1 + (4*u+p)] : S1[(4*u+p)*lds1 + col];
    xs[u] = TR2 ? S2[col*lds2 + (4*u+p)] : S2[(4*u+p)*lds2 + col];
  }
  #pragma unroll
  for (int i = 0; i < NN; ++i) {
    const int idx = i >> 2, ow = i & 3;
    float yi = xr[idx] * ivd1[i];
    yi = __shfl(yi, gbase + ow, 64);
    float zi = xs[idx] * ivd2[i];
    zi = __shfl(zi, gbase + ow, 64);
    if (p == ow) xr[idx] = yi;
    else if (p > ow) xr[idx] -= L1[(4*idx+p)*LDW + i] * yi;
    if (p == ow) xs[idx] = zi;
    else if (p > ow) xs[idx] -= L2[(4*idx+p)*LDW + i] * zi;
    #pragma unroll
    for (int u = idx+1; u < 16; ++u) {
      xr[u] -= L1[(4*u+p)*LDW + i] * yi;
      xs[u] -= L2[(4*u+p)*LDW + i] * zi;
    }
  }
  #pragma unroll
  for (int u = 0; u < 16; ++u) {
    D1[(4*u+p)*ldd1 + col] = xr[u];
    D2[(4*u+p)*ldd2 + col] = xs[u];
  }
  __syncthreads();
}

// backward triangular solve DST <- L^-T SRC
__device__ __forceinline__ void tri_bwd_ld(const float* __restrict__ L,
                                           const float* __restrict__ invd,
                                           const float* __restrict__ SRC, int lds,
                                           float* __restrict__ DST, int ldd) {
  const int col = threadIdx.x >> 2, p = threadIdx.x & 3;
  const int gbase = (threadIdx.x & 63) & ~3;
  float xr[16];
  #pragma unroll
  for (int u = 0; u < 16; ++u) xr[u] = SRC[(4*u+p)*lds + col];
  #pragma unroll
  for (int i = NN-1; i >= 0; --i) {
    const int idx = i >> 2, ow = i & 3;
    float zi = xr[idx] * invd[i];
    zi = __shfl(zi, gbase + ow, 64);
    if (p == ow) xr[idx] = zi;
    else if (p < ow) xr[idx] -= L[i*LDW + 4*idx+p] * zi;
    #pragma unroll
    for (int u = 0; u < idx; ++u)
      xr[u] -= L[i*LDW + 4*u+p] * zi;
  }
  #pragma unroll
  for (int u = 0; u < 16; ++u) DST[(4*u+p)*ldd + col] = xr[u];
  __syncthreads();
}

// one forward + one backward solve (same L), interleaved
__device__ __forceinline__ void tri_fb2(
    const float* __restrict__ L, const float* __restrict__ ivd,
    const float* __restrict__ Sf, int ldsf, float* __restrict__ Df, int lddf,
    const float* __restrict__ Sb, int ldsb, float* __restrict__ Db, int lddb)
{
  const int col = threadIdx.x >> 2, p = threadIdx.x & 3;
  const int gbase = (threadIdx.x & 63) & ~3;
  float xf[16], xb[16];
  #pragma unroll
  for (int u = 0; u < 16; ++u) {
    xf[u] = Sf[(4*u+p)*ldsf + col];
    xb[u] = Sb[(4*u+p)*ldsb + col];
  }
  #pragma unroll
  for (int k = 0; k < NN; ++k) {
    {
      const int i = k, idx = i >> 2, ow = i & 3;
      float yi = xf[idx] * ivd[i];
      yi = __shfl(yi, gbase + ow, 64);
      if (p == ow) xf[idx] = yi;
      else if (p > ow) xf[idx] -= L[(4*idx+p)*LDW + i] * yi;
      #pragma unroll
      for (int u = idx+1; u < 16; ++u)
        xf[u] -= L[(4*u+p)*LDW + i] * yi;
    }
    {
      const int i = NN-1-k, idx = i >> 2, ow = i & 3;
      float zi = xb[idx] * ivd[i];
      zi = __shfl(zi, gbase + ow, 64);
      if (p == ow) xb[idx] = zi;
      else if (p < ow) xb[idx] -= L[i*LDW + 4*idx+p] * zi;
      #pragma unroll
      for (int u = 0; u < idx; ++u)
        xb[u] -= L[i*LDW + 4*u+p] * zi;
    }
  }
  #pragma unroll
  for (int u = 0; u < 16; ++u) {
    Df[(4*u+p)*lddf + col] = xf[u];
    Db[(4*u+p)*lddb + col] = xb[u];
  }
  __syncthreads();
}

// two-sided triangular solve: DST <- L^-T L^-1 SRC
__device__ __forceinline__ void tri_solve2(const float* __restrict__ L,
                                           const float* __restrict__ invd,
                                           const float* __restrict__ SRC,
                                           float* __restrict__ DST) {
  const int col = threadIdx.x >> 2, p = threadIdx.x & 3;
  const int gbase = (threadIdx.x & 63) & ~3;
  float xr[16];
  #pragma unroll
  for (int u = 0; u < 16; ++u) xr[u] = SRC[(4*u+p)*LDW + col];
  #pragma unroll
  for (int i = 0; i < NN; ++i) {
    const int idx = i >> 2, ow = i & 3;
    float yi = xr[idx] * invd[i];
    yi = __shfl(yi, gbase + ow, 64);
    if (p == ow) xr[idx] = yi;
    else if (p > ow) xr[idx] -= L[(4*idx+p)*LDW + i] * yi;
    #pragma unroll
    for (int u = idx+1; u < 16; ++u)
      xr[u] -= L[(4*u+p)*LDW + i] * yi;
  }
  #pragma unroll
  for (int i = NN-1; i >= 0; --i) {
    const int idx = i >> 2, ow = i & 3;
    float zi = xr[idx] * invd[i];
    zi = __shfl(zi, gbase + ow, 64);
    if (p == ow) xr[idx] = zi;
    else if (p < ow) xr[idx] -= L[i*LDW + 4*idx+p] * zi;
    #pragma unroll
    for (int u = 0; u < idx; ++u)
      xr[u] -= L[i*LDW + 4*u+p] * zi;
  }
  #pragma unroll
  for (int u = 0; u < 16; ++u) DST[(4*u+p)*LDW + col] = xr[u];
  __syncthreads();
}

// TWO independent two-sided solves (same L), in-place, stride LDW
__device__ __forceinline__ void tri_s2x2(const float* __restrict__ L,
                                         const float* __restrict__ invd,
                                         float* __restrict__ X1,
                                         float* __restrict__ X2) {
  const int col = threadIdx.x >> 2, p = threadIdx.x & 3;
  const int gbase = (threadIdx.x & 63) & ~3;
  float xr[16], xs[16];
  #pragma unroll
  for (int u = 0; u < 16; ++u) {
    xr[u] = X1[(4*u+p)*LDW + col];
    xs[u] = X2[(4*u+p)*LDW + col];
  }
  #pragma unroll
  for (int i = 0; i < NN; ++i) {
    const int idx = i >> 2, ow = i & 3;
    float yi = xr[idx] * invd[i];
    yi = __shfl(yi, gbase + ow, 64);
    float zi = xs[idx] * invd[i];
    zi = __shfl(zi, gbase + ow, 64);
    if (p == ow) xr[idx] = yi;
    else if (p > ow) xr[idx] -= L[(4*idx+p)*LDW + i] * yi;
    if (p == ow) xs[idx] = zi;
    else if (p > ow) xs[idx] -= L[(4*idx+p)*LDW + i] * zi;
    #pragma unroll
    for (int u = idx+1; u < 16; ++u) {
      xr[u] -= L[(4*u+p)*LDW + i] * yi;
      xs[u] -= L[(4*u+p)*LDW + i] * zi;
    }
  }
  #pragma unroll
  for (int i = NN-1; i >= 0; --i) {
    const int idx = i >> 2, ow = i & 3;
    float yi = xr[idx] * invd[i];
    yi = __shfl(yi, gbase + ow, 64);
    float zi = xs[idx] * invd[i];
    zi = __shfl(zi, gbase + ow, 64);
    if (p == ow) xr[idx] = yi;
    else if (p < ow) xr[idx] -= L[i*LDW + 4*idx+p] * yi;
    if (p == ow) xs[idx] = zi;
    else if (p < ow) xs[idx] -= L[i*LDW + 4*idx+p] * zi;
    #pragma unroll
    for (int u = 0; u < idx; ++u) {
      xr[u] -= L[i*LDW + 4*u+p] * yi;
      xs[u] -= L[i*LDW + 4*u+p] * zi;
    }
  }
  #pragma unroll
  for (int u = 0; u < 16; ++u) {
    X1[(4*u+p)*LDW + col] = xr[u];
    X2[(4*u+p)*LDW + col] = xs[u];
  }
  __syncthreads();
}

// y(64) = M1*x1 + M2*x2 + addv. Both 64x64 row-major (global). y may alias x1/x2.
__device__ __forceinline__ void matvec2(float* __restrict__ y,
    const float* __restrict__ M1, const float* __restrict__ x1,
    const float* __restrict__ M2, const float* __restrict__ x2,
    const float* __restrict__ addv, float* __restrict__ red) {
  const int r = threadIdx.x & 63, p = threadIdx.x >> 6;
  const int kb = p*16;
  float s = 0.f;
  #pragma unroll
  for (int q = 0; q < 4; ++q) {
    F4 mv; mv.v = *(const float4*)(M1 + r*NN + kb + q*4);
    s += mv.f[0]*x1[kb+q*4] + mv.f[1]*x1[kb+q*4+1] + mv.f[2]*x1[kb+q*4+2] + mv.f[3]*x1[kb+q*4+3];
    F4 nv; nv.v = *(const float4*)(M2 + r*NN + kb + q*4);
    s += nv.f[0]*x2[kb+q*4] + nv.f[1]*x2[kb+q*4+1] + nv.f[2]*x2[kb+q*4+2] + nv.f[3]*x2[kb+q*4+3];
  }
  red[p*64 + r] = s;
  __syncthreads();
  if (threadIdx.x < 64) {
    float t = red[r] + red[64+r] + red[128+r] + red[192+r];
    y[r] = t + addv[r];
  }
  __syncthreads();
}

// y(LDS 64-vec) = Mg(64x64 row-major)*x + addv (nullable). y may alias x.
__device__ __forceinline__ void matvec256(float* __restrict__ y, const float* __restrict__ Mg,
    const float* __restrict__ x, const float* __restrict__ addv, float* __restrict__ red) {
  const int r = threadIdx.x & 63, p = threadIdx.x >> 6;
  const int kb = p*16;
  float s = 0.f;
  #pragma unroll
  for (int q = 0; q < 4; ++q) {
    F4 mv; mv.v = *(const float4*)(Mg + r*NN + kb + q*4);
    s += mv.f[0]*x[kb+q*4] + mv.f[1]*x[kb+q*4+1] + mv.f[2]*x[kb+q*4+2] + mv.f[3]*x[kb+q*4+3];
  }
  red[p*64 + r] = s;
  __syncthreads();
  if (threadIdx.x < 64) {
    float t = red[r] + red[64+r] + red[128+r] + red[192+r];
    y[r] = t + (addv ? addv[r] : 0.f);
  }
  __syncthreads();
}

// ---------- kernels ----------

__global__ __launch_bounds__(256) void k0(KP P) {
  __shared__ __align__(16) float W0[LDW*NN];
  const int tid = threadIdx.x;
  for (int e = tid; e < 4096; e += 256) {
    int r = e>>6, cc = e&63;
    P.AT[e] = P.A[cc*64+r];
    P.HT[e] = P.H[cc*64+r];
  }
  if (tid < 64) {
    float s = 0.f;
    for (int k = 0; k < 64; ++k) s += P.H[tid*64+k]*P.b[k];
    P.Hb[tid] = s;
  }
  __syncthreads();
  mm<0,0,0,LDW>(W0, P.H, NN, P.A, NN, nullptr, 0);   // HA = H*A
  l2g(P.HA, W0);
}

// kA: leaf + fP0 + 5 doublings (E^2..E^32; kB decomposes t = 32q + bits)
__global__ __launch_bounds__(256) void kA(KP P) {
  __shared__ __align__(16) float LA[LDW*NN], LC[LDW*NN], LJ[LDW*NN], LL[LDW*NN];
  __shared__ __align__(16) float W0[LDW*NN], W1[LDW*NN], W2[LDW*NN], W3[LDW*NN], W4[LDW*NN];
  __shared__ float part[64], iv1[64], iv2[64];
  const int tid = threadIdx.x;
  mm2<0,0,0,LDW, 0,0,0,LDW>(W0, P.H,NN, P.Q,NN, nullptr,0,
                            W2, P.H,NN, P.P0,NN, nullptr,0);      // T = H Q ; HP0
  mm2<0,1,1,LDW, 0,1,1,LDW>(W1, W0,LDW, P.H,NN, P.R,NN,
                            W3, W2,LDW, P.H,NN, P.R,NN);          // St ; S0
  chol68<false>(W1, part, iv1);
  chol68<false>(W3, part, iv2);
  tri_fwd2<0,0>(W1, iv1, P.HA,NN, W4,LDW,
                W3, iv2, W2,LDW,  W2,LDW);                         // U ; U0
  mm2<1,0,0,LDW, 1,0,2,LDW>(LJ, W4,LDW, W4,LDW, nullptr,0,
                            W3, W2,LDW, W2,LDW, P.P0,NN);          // Jt ; fP0
  l2g(P.fP, W3);
  copyW(LL, LJ);
  chol68<false>(LL, part, iv2);                                    // Lt
  tri_fb2(W1, iv1, W0,LDW, W3,LDW,  W4,LDW, W4,LDW);               // V ; X
  mm2<1,0,2,LDW, 1,0,2,LDW>(LA, W0,LDW, W4,LDW, P.A,NN,
                            LC, W3,LDW, W3,LDW, P.Q,NN);           // At ; Ct
  l2g3(P.EA, LA, P.EC, LC, P.EL, LL);
  for (int j = 0; j < 5 && (2 << j) <= P.N0cap - 1; ++j) {
    mm2<0,0,0,LDW, 1,0,0,LDW>(W0, LC,LDW, LL,LDW, nullptr,0,
                              W2, LL,LDW, LA,LDW, nullptr,0);      // Pm ; T1
    mm<1,0,0,LDW>(W1, LL,LDW, W0,LDW, nullptr,0);                  // W
    if (tid < 64) W1[tid*LDW + tid] += 1.f;
    __syncthreads();
    chol68<false>(W1, part, iv1);                                   // Lw
    tri_fwd2<0,1>(W1, iv1, W2,LDW, W2,LDW,
                  W1, iv1, W0,LDW, W3,LDW);                         // T2f ; T5
    mm2<1,0,1,LDW, 1,0,2,LDW>(LJ, W2,LDW, W2,LDW, LJ,LDW,
                              W4, W3,LDW, W3,LDW, LC,LDW);          // Jn ; ZC
    copyW(LL, LJ);
    chol68<false>(LL, part, iv2);                                   // Ln
    tri_bwd_ld(W1, iv1, W2,LDW, W2,LDW);                            // T2
    mm<0,0,2,LDW>(W3, W0,LDW, W2,LDW, LA,LDW);                      // ZA
    mm2<0,0,0,LDW, 0,0,0,LDW>(W2, LA,LDW, W3,LDW, nullptr,0,
                              W0, LA,LDW, W4,LDW, nullptr,0);       // An ; T7
    mm<0,1,1,LDW>(LC, W0,LDW, LA,LDW, LC,LDW);                      // Cn
    copyW(LA, W2);
    l2g3(P.EA+(size_t)(j+1)*4096, LA, P.EC+(size_t)(j+1)*4096, LC,
         P.EL+(size_t)(j+1)*4096, LL);
  }
}

// block t: fP_t via greedy decomposition; also pP_{t+1} (folds old kP)
__global__ __launch_bounds__(256) void kB(KP P) {
  __shared__ __align__(16) float Wc[LDW*NN], W0[LDW*NN], W1[LDW*NN], W2[LDW*NN];
  __shared__ float part[64], ivw[64];
  const int t = blockIdx.x;
  if (t == 0) {
    for (int e = threadIdx.x*4; e < 4096; e += 1024)
      *(float4*)(P.pP + e) = *(const float4*)(P.P0 + e);
    __syncthreads();
    mm<0,0,0,LDW>(W1, P.A, NN, P.fP, NN, nullptr, 0);
    mm<0,0,1,LDW>(W0, W1, LDW, P.AT, NN, P.Q, NN);
    l2g(P.pP + 4096, W0);
    return;
  }
  g2l(Wc, P.fP);
  int rem = t;
  for (int j = 5; j >= 0; --j) {
    const int pw = 1 << j;
    if (j > 0 && pw > P.N0cap - 1) continue;
    while (rem >= pw) {
      const float* Ag = P.EA + j*4096;
      const float* Cg = P.EC + j*4096;
      const float* Lg = P.EL + j*4096;
      mm<0,0,0,LDW>(W0, Wc, LDW, Lg, NN, nullptr, 0);     // Pm = C L
      mm<1,0,0,LDW>(W1, Lg, NN, W0, LDW, nullptr, 0);     // W = L^T Pm
      if (threadIdx.x < 64) W1[threadIdx.x*LDW + threadIdx.x] += 1.f;
      __syncthreads();
      chol68<false>(W1, part, ivw);
      tri_fwd_ld<1>(W1, ivw, W0, LDW, W2, LDW);           // T5
      mm<1,0,2,LDW>(W1, W2, LDW, W2, LDW, Wc, LDW);       // ZC
      mm<0,0,0,LDW>(W0, Ag, NN, W1, LDW, nullptr, 0);     // T7
      mm<0,1,1,LDW>(Wc, W0, LDW, Ag, NN, Cg, NN);         // C'
      rem -= pw;
    }
  }
  l2g(P.fP + (size_t)t*4096, Wc);
  mm<0,0,0,LDW>(W0, P.A, NN, Wc, LDW, nullptr, 0);
  mm<0,0,1,LDW>(W1, W0, LDW, P.AT, NN, P.Q, NN);
  l2g(P.pP + (size_t)(t+1)*4096, W1);
}

__global__ __launch_bounds__(256) void kC(KP P) {
  __shared__ float red[16];
  const int t = blockIdx.x;
  const float* cur = P.fP + (size_t)t*4096;
  const float* prv = P.fP + (size_t)(t > 0 ? t-1 : 0)*4096;
  float a = 0.f, d = 0.f;
  for (int e = threadIdx.x*4; e < 4096; e += 1024) {
    F4 v, pv; v.v = *(const float4*)(cur + e); pv.v = *(const float4*)(prv + e);
    #pragma unroll
    for (int q = 0; q < 4; ++q) {
      a = fmaxf(a, fabsf(v.f[q]));
      d = fmaxf(d, fabsf(v.f[q] - pv.f[q]));
    }
  }
  redpair(a, d, red);
  if (threadIdx.x == 0) { P.astat[t] = a; P.dstat[t] = (t > 0) ? d : 0.f; }
}

__global__ __launch_bounds__(256) void kN(KP P) {
  __shared__ float as_[N0MAX], ds_[N0MAX];
  const int cap = P.N0cap;
  for (int i = threadIdx.x; i < cap; i += 256) { as_[i] = P.astat[i]; ds_[i] = P.dstat[i]; }
  __syncthreads();
  if (threadIdx.x == 0) {
    float mabs = 1e-20f, dref = 1e30f;
    int tref = 0, N0 = cap;
    bool conv = false;
    for (int t = 0; t < cap; ++t) {
      mabs = fmaxf(mabs, as_[t]);
      if (t > 0) {
        float d = ds_[t];
        if (d <= EPS_HARD*mabs) { N0 = t+1; conv = true; }
        if (d < STALL_IMP*dref) { dref = d; tref = t; }
        else if (t - tref >= STALL_WIN && t >= 12 && d < EPS_GATE*mabs) { N0 = t+1; conv = true; }
      }
      if (conv) break;
    }
    P.meta[0] = N0; P.metaF[1] = mabs;
  }
}

__global__ __launch_bounds__(256) void k1ss(KP P) {
  __shared__ __align__(16) float W0[LDW*NN], W1[LDW*NN], W2[LDW*NN], W3[LDW*NN], W4[LDW*NN], CH[LDW*NN];
  __shared__ float part[64], invd[64];
  const int tid = threadIdx.x;
  const int N0 = P.meta[0];
  const float* fPssG = P.fP + (size_t)(N0-1)*4096;
  g2l(CH, fPssG);
  mm<0,0,0,LDW>(W1, P.A, NN, CH, LDW, nullptr, 0);
  mm<0,0,1,LDW>(W0, W1, LDW, P.AT, NN, P.Q, NN);              // pP_ss
  l2g(P.pPss, W0);
  mm<0,0,0,LDW>(W1, P.H, NN, W0, LDW, nullptr, 0);            // HP
  mm<0,0,1,LDW>(CH, W1, LDW, P.HT, NN, P.R, NN);              // S
  chol68<true>(CH, part, invd);
  if (tid == 0) { float s=0.f; for (int j=0;j<64;++j) s += part[j]; P.metaF[0] = s; }
  set_id(W0);
  tri_s2x2(CH, invd, W1, W0);                                 // X ; Sinv
  l2g_T(P.Kss, W1);
  if (tid < 64) {
    float s = P.b[tid];
    for (int k = 0; k < 64; ++k) s -= W1[k*LDW + tid]*P.Hb[k];
    P.uss[tid] = s;
  }
  __syncthreads();
  l2g(P.Sinvss, W0);
  mm<1,0,2,LDW>(W0, W1, LDW, P.HA, NN, P.A, NN);              // F_ss
  l2g(P.Fss, W0);
  mm<0,0,0,LDW>(W1, P.A, NN, fPssG, NN, nullptr, 0);          // AF
  g2l(CH, P.pPss);
  chol68<false>(CH, part, invd);
  tri_solve2(CH, invd, W1, W1);                               // X2 = Css^T
  l2g(P.CsTss, W1);
  l2g_T(P.Css, W1);
  // Dmss = I - Css A ; dvnss = -Css b
  mm<1,0,0,LDW>(W2, W1, LDW, P.A, NN, nullptr, 0);
  store_id_sub(P.Dmss, W2);
  if (tid < 64) {
    float s = 0.f;
    for (int k = 0; k < 64; ++k) s += W1[k*LDW + tid]*P.b[k];
    P.dvnss[tid] = -s;
  }
  __syncthreads();
  // C powers ∥ F powers
  g2l(W0, P.Css);
  g2l(W3, P.Fss);
  mm2<0,0,0,LDW, 0,0,0,LDW>(W1, W0,LDW, W0,LDW, nullptr,0,
                            W4, W3,LDW, W3,LDW, nullptr,0);   // C2 ; F2
  l2g(P.Pw2, W1);
  mm2<0,0,0,LDW, 0,0,0,LDW>(W2, W1,LDW, W1,LDW, nullptr,0,
                            W3, W4,LDW, W4,LDW, nullptr,0);   // C4 ; F4
  l2g(P.Pw4, W2);
  mm2<0,0,0,LDW, 0,0,0,LDW>(W0, W2,LDW, W2,LDW, nullptr,0,
                            W4, W3,LDW, W3,LDW, nullptr,0);   // C8 ; F8
  l2g(P.Pw8, W0);
  mm2<0,0,0,LDW, 0,0,0,LDW>(W1, W0,LDW, W0,LDW, nullptr,0,
                            W3, W4,LDW, W4,LDW, nullptr,0);   // C16 ; F16
  l2g(P.Pw16, W1);
  mm2<0,0,0,LDW, 0,0,0,LDW>(W4, W1,LDW, W1,LDW, nullptr,0,
                            CH, W3,LDW, W3,LDW, nullptr,0);   // C32 ; F32
  l2g(P.Cpow32, W4);
  l2g(P.Fpow, CH);
  mm2<0,0,0,LDW, 0,0,0,LDW>(CH, W4,LDW, W4,LDW, nullptr,0,
                            W3, W1,LDW, W0,LDW, nullptr,0);   // C64 ; C24
  l2g(P.Pw64, CH);
  mm2<0,0,0,LDW, 0,0,0,LDW>(W1, CH,LDW, CH,LDW, nullptr,0,
                            W0, W3,LDW, W2,LDW, nullptr,0);   // C128 ; C28
  l2g(P.Pw128, W1);
  mm<0,0,0,LDW>(W2, W0, LDW, P.Pw2, NN, nullptr, 0);          // C30
  mm<0,0,0,LDW>(W0, W2, LDW, P.Css, NN, nullptr, 0);          // C31
  l2g(P.Cpow31, W0);
  // Stein
  g2l(W1, P.Css);
  g2l(W2, P.CsTss);
  g2l(W0, P.pPss);
  mm<0,0,0,LDW>(CH, W1, LDW, W0, LDW, nullptr, 0);
  mm<0,0,2,LDW>(W0, CH, LDW, W2, LDW, fPssG, NN);
  {
    float *m1 = W1, *m2 = W2, *t1 = W3, *t2 = W4;
    for (int it = 0; it < 7; ++it) {
      mm2<0,0,0,LDW, 0,0,0,LDW>(CH, m1,LDW, W0,LDW, nullptr,0,
                                t1, m1,LDW, m1,LDW, nullptr,0);
      mm2<0,0,1,LDW, 0,0,0,LDW>(W0, CH,LDW, m2,LDW, W0,LDW,
                                t2, m2,LDW, m2,LDW, nullptr,0);
      float* tmp = m1; m1 = t1; t1 = tmp;
      tmp = m2; m2 = t2; t2 = tmp;
    }
  }
  l2g(P.sPss, W0);
  rsub_store(P.E0g, fPssG, W0);
}

__global__ __launch_bounds__(256) void k1d(KP P) {
  __shared__ __align__(16) float W0[LDW*NN], W1[LDW*NN], W2[LDW*NN];
  const int k = blockIdx.x;
  float* dst = P.out_cov + (size_t)(P.T-1-k)*4096;
  if (k == 0) {
    const float* src = P.fP + (size_t)(P.meta[0]-1)*4096;
    for (int e = threadIdx.x*4; e < 4096; e += 1024)
      *(float4*)(dst+e) = *(const float4*)(src+e);
    return;
  }
  const float* pw[8] = {P.Css, P.Pw2, P.Pw4, P.Pw8, P.Pw16, P.Cpow32, P.Pw64, P.Pw128};
  int b = __ffs(k) - 1;
  g2l(W1, pw[b]);
  float* cur = W1; float* oth = W0;
  for (int j = b+1; j < 8; ++j) {
    if ((k >> j) & 1) {
      mm<0,0,0,LDW>(oth, pw[j], NN, cur, LDW, nullptr, 0);
      float* tmp = cur; cur = oth; oth = tmp;
    }
  }
  mm<0,0,0,LDW>(W2, cur, LDW, P.E0g, NN, nullptr, 0);
  mm<0,1,1,LDW>(oth, W2, LDW, cur, LDW, P.sPss, NN);
  l2g(dst, oth);
}

__global__ __launch_bounds__(256) void k1b(KP P) {
  __shared__ __align__(16) float W0[LDW*NN], W1[LDW*NN], CH[LDW*NN];
  __shared__ float part[64], invd[64];
  const int t = blockIdx.x;
  if (t >= P.meta[0]) return;
  mm<0,0,0,LDW>(W1, P.H, NN, P.pP + (size_t)t*4096, NN, nullptr, 0);
  mm<0,0,1,LDW>(CH, W1, LDW, P.HT, NN, P.R, NN);
  chol68<true>(CH, part, invd);
  if (threadIdx.x == 0) { float s=0.f; for (int j=0;j<64;++j) s += part[j]; P.ld_pref[t] = s; }
  set_id(W0);
  tri_s2x2(CH, invd, W1, W0);
  l2g_T(P.Kp + (size_t)t*4096, W1);
  if (threadIdx.x < 64) {
    float s = P.b[threadIdx.x];
    for (int k = 0; k < 64; ++k) s -= W1[k*LDW + threadIdx.x]*P.Hb[k];
    P.u_pref[t*64 + threadIdx.x] = s;
  }
  __syncthreads();
  l2g(P.Sinvp + (size_t)t*4096, W0);
  mm<1,0,2,LDW>(W0, W1, LDW, P.HA, NN, P.A, NN);
  l2g(P.Fp + (size_t)t*4096, W0);
  mm<0,0,0,LDW>(W1, P.A, NN, P.fP + (size_t)t*4096, NN, nullptr, 0);
  g2l(CH, P.pP + (size_t)(t+1)*4096);
  chol68<false>(CH, part, invd);
  tri_solve2(CH, invd, W1, W1);                               // X2 = C_t^T
  l2g(P.CsTp + (size_t)t*4096, W1);
  l2g_T(P.Cp + (size_t)t*4096, W1);
  mm<1,0,0,LDW>(W0, W1, LDW, P.A, NN, nullptr, 0);            // C_t*A
  store_id_sub(P.Dmp + (size_t)t*4096, W0);
  if (threadIdx.x < 64) {
    float s = 0.f;
    for (int k = 0; k < 64; ++k) s += W1[k*LDW + threadIdx.x]*P.b[k];
    P.dvnp[t*64 + threadIdx.x] = -s;
  }
}

__global__ __launch_bounds__(256) void k1cI(KP P) {
  __shared__ __align__(16) float W1[LDW*NN];
  const int t = blockIdx.x;
  if (t >= P.meta[0]) return;
  const float* Cg = P.Cp + (size_t)t*4096;
  for (int e = threadIdx.x*4; e < 4096; e += 1024)
    *(float4*)(P.scM0 + (size_t)t*4096 + e) = *(const float4*)(Cg + e);
  mm<0,0,0,LDW>(W1, Cg, NN, P.pP + (size_t)(t+1)*4096, NN, nullptr, 0);
  mm<0,0,2,NN>(P.scG0 + (size_t)t*4096, W1, LDW,
               P.CsTp + (size_t)t*4096, NN, P.fP + (size_t)t*4096, NN);
}

__global__ __launch_bounds__(256) void k1cL(KP P, int step, int sidx) {
  __shared__ __align__(16) float W1[LDW*NN];
  const int t = blockIdx.x;
  const int N0 = P.meta[0];
  if (t >= N0) return;
  const float* Msrc = sidx ? P.scM1 : P.scM0;
  const float* Gsrc = sidx ? P.scG1 : P.scG0;
  float* Mdst = sidx ? P.scM0 : P.scM1;
  float* Gdst = sidx ? P.scG0 : P.scG1;
  const int s = t + step;
  if (s >= N0) {
    for (int e = threadIdx.x*4; e < 4096; e += 1024) {
      *(float4*)(Mdst + (size_t)t*4096 + e) = *(const float4*)(Msrc + (size_t)t*4096 + e);
      *(float4*)(Gdst + (size_t)t*4096 + e) = *(const float4*)(Gsrc + (size_t)t*4096 + e);
    }
    return;
  }
  const float* Mt = Msrc + (size_t)t*4096;
  mm2<0,0,0,LDW, 0,0,0,NN>(W1, Mt,NN, Gsrc + (size_t)s*4096,NN, nullptr,0,
                           Mdst + (size_t)t*4096, Mt,NN, Msrc + (size_t)s*4096,NN, nullptr,0);
  mm<0,1,1,NN>(Gdst + (size_t)t*4096, W1, LDW, Mt, NN, Gsrc + (size_t)t*4096, NN);
}

__global__ __launch_bounds__(256) void k1cF(KP P) {
  __shared__ __align__(16) float W1[LDW*NN];
  const int t = blockIdx.x;
  if (t >= P.meta[0]) return;
  const float* Mt = P.scM0 + (size_t)t*4096;
  mm<0,0,0,LDW>(W1, Mt, NN, P.sPss, NN, nullptr, 0);
  mm<0,1,1,NN>(P.out_cov + (size_t)t*4096, W1, LDW, Mt, NN,
               P.scG0 + (size_t)t*4096, NN);
}

__global__ __launch_bounds__(256) void k4(KP P) {
  const int t = blockIdx.x;
  if (t < P.meta[0] || t >= P.T - N1CAP) return;
  float* dst = P.out_cov + (size_t)t*4096;
  for (int e = threadIdx.x*4; e < 4096; e += 1024)
    *(float4*)(dst+e) = *(const float4*)(P.sPss + e);
}

__global__ __launch_bounds__(256) void k2a(KP P) {
  __shared__ float xv[64], ty[64], red[256];
  const int c = blockIdx.x;
  const int N0 = P.meta[0];
  const int PB = (N0 + LCH - 1)/LCH;
  if (c < PB) return;
  const int tid = threadIdx.x;
  if (tid < 64) xv[tid] = 0.f;
  __syncthreads();
  for (int s = 0; s < LCH; ++s) {
    int t = c*LCH + s;
    if (tid < 64) ty[tid] = P.Y[(size_t)t*64+tid] - P.c[tid];
    __syncthreads();
    matvec2(xv, P.Fss, xv, P.Kss, ty, P.uss, red);
  }
  if (tid < 64) P.u_chunk[c*64+tid] = xv[tid];
}

__global__ __launch_bounds__(256) void k2b(KP P) {
  __shared__ float xv[64], ty[64], hp[64], red[256];
  const int tid = threadIdx.x;
  const int N0 = P.meta[0];
  const int PB = (N0 + LCH - 1)/LCH;
  const int PE = PB*LCH;
  if (tid < 64) xv[tid] = P.pm0[tid];
  __syncthreads();
  matvec256(hp, P.H, xv, nullptr, red);
  if (tid < 64) ty[tid] = P.Y[tid] - hp[tid] - P.c[tid];
  __syncthreads();
  matvec256(xv, P.Kp, ty, xv, red);
  if (tid < 64) P.fm[tid] = xv[tid];
  __syncthreads();
  for (int t = 1; t < PE; ++t) {
    const float* Kt = (t < N0) ? P.Kp + (size_t)t*4096 : P.Kss;
    const float* Ft = (t < N0) ? P.Fp + (size_t)t*4096 : P.Fss;
    const float* ut = (t < N0) ? P.u_pref + t*64 : P.uss;
    if (tid < 64) ty[tid] = P.Y[(size_t)t*64+tid] - P.c[tid];
    __syncthreads();
    matvec2(xv, Ft, xv, Kt, ty, ut, red);
    if (tid < 64) P.fm[(size_t)t*64+tid] = xv[tid];
    __syncthreads();
  }
  for (int c = PB; c < P.NC; ++c) {
    if (tid < 64) P.startstate[c*64+tid] = xv[tid];
    __syncthreads();
    matvec256(xv, P.Fpow, xv, P.u_chunk + c*64, red);
  }
}

__global__ __launch_bounds__(256) void k2c(KP P) {
  __shared__ float xv[64], ty[64], red[256];
  const int c = blockIdx.x;
  const int N0 = P.meta[0];
  const int PB = (N0 + LCH - 1)/LCH;
  if (c < PB) return;
  const int tid = threadIdx.x;
  if (tid < 64) xv[tid] = P.startstate[c*64+tid];
  __syncthreads();
  for (int s = 0; s < LCH; ++s) {
    int t = c*LCH + s;
    if (tid < 64) ty[tid] = P.Y[(size_t)t*64+tid] - P.c[tid];
    __syncthreads();
    matvec2(xv, P.Fss, xv, P.Kss, ty, P.uss, red);
    if (tid < 64) P.fm[(size_t)t*64+tid] = xv[tid];
    __syncthreads();
  }
}

__global__ __launch_bounds__(64) void k5(KP P) {
  __shared__ float pmv[64], rv[64];
  const int t = blockIdx.x;
  const int N0 = P.meta[0];
  const int r = threadIdx.x;
  float pm;
  if (t == 0) {
    pm = P.pm0[r];
  } else {
    pmv[r] = P.fm[(size_t)(t-1)*64 + r];
    __syncthreads();
    float s = P.b[r];
    const float* Ar = P.A + r*64;
    for (int k = 0; k < 64; k += 4)
      s += Ar[k]*pmv[k] + Ar[k+1]*pmv[k+1] + Ar[k+2]*pmv[k+2] + Ar[k+3]*pmv[k+3];
    pm = s;
    __syncthreads();
  }
  pmv[r] = pm; __syncthreads();
  float rr = P.Y[(size_t)t*64 + r] - P.c[r];
  const float* Hr = P.H + r*64;
  for (int k = 0; k < 64; ++k) rr -= Hr[k]*pmv[k];
  rv[r] = rr; __syncthreads();
  const float* Sv = ((t < N0) ? P.Sinvp + (size_t)t*4096 : P.Sinvss) + r*64;
  float wv = 0.f;
  for (int k = 0; k < 64; ++k) wv += Sv[k]*rv[k];
  float qq = rr*wv;
  #pragma unroll
  for (int off = 32; off > 0; off >>= 1) qq += __shfl_xor(qq, off, 64);
  if (r == 0) {
    float ldt = (t < N0) ? P.ld_pref[t] : P.metaF[0];
    P.llbuf[t] = -58.8120661250990555 - (double)ldt - 0.5*(double)qq;
  }
}

__global__ __launch_bounds__(256) void k3a(KP P) {
  __shared__ float sv[64], fmv[64], red[256];
  const int c = blockIdx.x;
  const int N0 = P.meta[0];
  const int PB = (N0 + LCH - 1)/LCH;
  if (c < PB) return;
  const int tid = threadIdx.x;
  if (tid < 64) sv[tid] = 0.f;
  __syncthreads();
  int hi = (c == P.NC-1) ? P.T-2 : c*LCH + LCH - 1;
  for (int t = hi; t >= c*LCH; --t) {
    if (tid < 64) fmv[tid] = P.fm[(size_t)t*64+tid];
    __syncthreads();
    matvec2(sv, P.Css, sv, P.Dmss, fmv, P.dvnss, red);
  }
  if (tid < 64) P.ub_chunk[c*64+tid] = sv[tid];
}

__global__ __launch_bounds__(256) void k3b(KP P) {
  __shared__ float sv[64], fmv[64], red[256];
  const int tid = threadIdx.x;
  const int N0 = P.meta[0];
  const int PB = (N0 + LCH - 1)/LCH;
  const int PE = PB*LCH;
  if (tid < 64) {
    float v = P.fm[(size_t)(P.T-1)*64+tid];
    sv[tid] = v;
    P.out_mean[(size_t)(P.T-1)*64+tid] = v;
  }
  __syncthreads();
  for (int c = P.NC-1; c >= PB; --c) {
    if (tid < 64) P.endstate[c*64+tid] = sv[tid];
    __syncthreads();
    matvec256(sv, (c == P.NC-1) ? P.Cpow31 : P.Cpow32, sv, P.ub_chunk + c*64, red);
  }
  for (int t = PE-1; t >= 0; --t) {
    const float* Ct  = (t < N0) ? P.Cp  + (size_t)t*4096 : P.Css;
    const float* Dmt = (t < N0) ? P.Dmp + (size_t)t*4096 : P.Dmss;
    const float* dvt = (t < N0) ? P.dvnp + t*64 : P.dvnss;
    if (tid < 64) fmv[tid] = P.fm[(size_t)t*64+tid];
    __syncthreads();
    matvec2(sv, Ct, sv, Dmt, fmv, dvt, red);
    if (tid < 64) P.out_mean[(size_t)t*64+tid] = sv[tid];
    __syncthreads();
  }
}

__global__ __launch_bounds__(256) void k3c(KP P) {
  __shared__ float sv[64], fmv[64], red[256];
  const int c = blockIdx.x;
  const int N0 = P.meta[0];
  const int PB = (N0 + LCH - 1)/LCH;
  if (c < PB) return;
  const int tid = threadIdx.x;
  if (tid < 64) sv[tid] = P.endstate[c*64+tid];
  __syncthreads();
  int hi = (c == P.NC-1) ? P.T-2 : c*LCH + LCH - 1;
  for (int t = hi; t >= c*LCH; --t) {
    if (tid < 64) fmv[tid] = P.fm[(size_t)t*64+tid];
    __syncthreads();
    matvec2(sv, P.Css, sv, P.Dmss, fmv, P.dvnss, red);
    if (tid < 64) P.out_mean[(size_t)t*64+tid] = sv[tid];
    __syncthreads();
  }
}

__global__ __launch_bounds__(256) void k6(KP P) {
  __shared__ double rd[256];
  double s = 0.0;
  for (int t = threadIdx.x; t < P.T; t += 256) s += P.llbuf[t];
  rd[threadIdx.x] = s; __syncthreads();
  #pragma unroll
  for (int off = 128; off > 0; off >>= 1) {
    if ((int)threadIdx.x < off) rd[threadIdx.x] += rd[threadIdx.x + off];
    __syncthreads();
  }
  if (threadIdx.x == 0) P.out_ll[0] = (float)rd[0];
}

// ---------- host ----------

extern "C" void kernel_launch(void* const* d_in, const int* in_sizes, int n_in,
                              void* d_out, int out_size, void* d_ws, size_t ws_size,
                              hipStream_t stream) {
  (void)n_in; (void)out_size;
  KP P;
  P.Y   = (const float*)d_in[0];
  P.A   = (const float*)d_in[1];
  P.b   = (const float*)d_in[2];
  P.Q   = (const float*)d_in[3];
  P.H   = (const float*)d_in[4];
  P.c   = (const float*)d_in[5];
  P.R   = (const float*)d_in[6];
  P.pm0 = (const float*)d_in[7];
  P.P0  = (const float*)d_in[8];
  const int T = in_sizes[0] / 64;
  const int NC = T / LCH;
  P.T = T; P.NC = NC;

  float* out = (float*)d_out;
  P.out_mean = out;
  P.out_cov  = out + (size_t)T*64;
  P.out_ll   = out + (size_t)T*64 + (size_t)T*4096;

  float* w = (float*)d_ws;
  size_t off = 0;
  auto alloc = [&](size_t n) { float* p = w + off; off += n; return p; };
  P.meta   = (int*)alloc(8);
  P.metaF  = alloc(8);
  P.llbuf  = (double*)alloc((size_t)2*T);
  P.fm     = alloc((size_t)T*64);
  P.AT = alloc(4096); P.HT = alloc(4096); P.HA = alloc(4096); P.Hb = alloc(64);
  P.Fss = alloc(4096); P.Kss = alloc(4096); P.Sinvss = alloc(4096);
  P.Css = alloc(4096); P.CsTss = alloc(4096); P.pPss = alloc(4096); P.sPss = alloc(4096);
  P.Fpow = alloc(4096); P.Cpow32 = alloc(4096); P.Cpow31 = alloc(4096); P.uss = alloc(64);
  P.Pw2 = alloc(4096); P.Pw4 = alloc(4096); P.Pw8 = alloc(4096); P.Pw16 = alloc(4096);
  P.Pw64 = alloc(4096); P.Pw128 = alloc(4096);
  P.Dmss = alloc(4096); P.dvnss = alloc(64);
  P.u_chunk = alloc((size_t)NC*64); P.startstate = alloc((size_t)NC*64);
  P.ub_chunk = alloc((size_t)NC*64); P.endstate = alloc((size_t)NC*64);
  P.E0g = alloc(4096);
  P.EA = alloc((size_t)8*4096); P.EC = alloc((size_t)8*4096);
  P.EJ = alloc((size_t)8*4096); P.EL = alloc((size_t)8*4096);
  P.astat = alloc(256); P.dstat = alloc(256);
  size_t fixed = off;
  size_t per_t = 12*4096 + 128 + 1;
  size_t total_f = ws_size / 4;
  long long avail = (long long)total_f - (long long)fixed - 4096 - 64;
  int cap = (avail > 0) ? (int)(avail / (long long)per_t) : 8;
  if (cap > N0MAX) cap = N0MAX;
  if (cap < 8) cap = 8;
  P.N0cap = cap;
  P.ld_pref = alloc(cap);
  P.u_pref  = alloc((size_t)cap*64);
  P.dvnp    = alloc((size_t)cap*64);
  P.fP    = alloc((size_t)cap*4096);
  P.pP    = alloc((size_t)(cap+1)*4096);
  P.Kp    = alloc((size_t)cap*4096);
  P.Sinvp = alloc((size_t)cap*4096);
  P.Fp    = alloc((size_t)cap*4096);
  P.Cp    = alloc((size_t)cap*4096);
  P.CsTp  = alloc((size_t)cap*4096);
  P.Dmp   = alloc((size_t)cap*4096);
  P.scM0  = alloc((size_t)cap*4096);
  P.scM1  = alloc((size_t)cap*4096);
  P.scG0  = alloc((size_t)cap*4096);
  P.scG1  = alloc((size_t)cap*4096);

  k0<<<1, 256, 0, stream>>>(P);
  kA<<<1, 256, 0, stream>>>(P);
  kB<<<cap, 256, 0, stream>>>(P);
  kC<<<cap, 256, 0, stream>>>(P);
  kN<<<1, 256, 0, stream>>>(P);
  k1ss<<<1, 256, 0, stream>>>(P);
  k1b<<<cap, 256, 0, stream>>>(P);
  k1d<<<N1CAP, 256, 0, stream>>>(P);
  k4<<<T, 256, 0, stream>>>(P);
  k1cI<<<cap, 256, 0, stream>>>(P);
  {
    int sidx = 0;
    for (int d = 0; d < 8; ++d) { k1cL<<<cap, 256, 0, stream>>>(P, 1 << d, sidx); sidx ^= 1; }
  }
  k1cF<<<cap, 256, 0, stream>>>(P);
  k2a<<<NC, 256, 0, stream>>>(P);
  k2b<<<1, 256, 0, stream>>>(P);
  k2c<<<NC, 256, 0, stream>>>(P);
  k5<<<T, 64, 0, stream>>>(P);
  k3a<<<NC, 256, 0, stream>>>(P);
  k3b<<<1, 256, 0, stream>>>(P);
  k3c<<<NC, 256, 0, stream>>>(P);
  k6<<<1, 256, 0, stream>>>(P);
}

// Round 6
// 1793.960 us; speedup vs baseline: 2.1942x; 1.1746x over previous
//
#include <hip/hip_runtime.h>
#include <math.h>

#define NN 64
#define LDW 68      // padded LDS stride (float4-aligned)
#define LCH 32      // mean-scan chunk length
#define N1CAP 144   // smoother-cov tail length (closed-form, parallel)
#define N0MAX 144   // forward Riccati cap
#define EPS_HARD 1e-5f
#define EPS_GATE 5e-2f
#define STALL_WIN 5
#define STALL_IMP 0.75f

struct KP {
  const float *Y, *A, *b, *Q, *H, *c, *R, *pm0, *P0;
  float *out_mean, *out_cov, *out_ll;
  int *meta; float *metaF;
  float *fm;
  float *AT, *HT, *HA, *Hb;
  float *Fss, *Kss, *Sinvss, *Css, *CsTss, *pPss, *sPss, *Fpow, *Cpow32, *Cpow31, *uss;
  float *Pw2, *Pw4, *Pw8, *Pw16, *Pw64, *Pw128;
  float *FpwHi, *CpwHi;                   // F^(64..2048) [6], C^(256..2048) [4]
  float *Dmss, *dvnss;                    // I - Css*A ; -Css*b (fused backward scan)
  float *u_chunk, *startstate, *ub_chunk, *endstate;  // legacy (unused)
  float *scanF0, *scanF1, *scanB0, *scanB1;           // chunk-carry scan buffers
  float *ld_pref, *u_pref;
  double *llbuf;
  float *E0g;
  float *EA, *EC, *EJ, *EL;
  float *astat, *dstat;
  float *scM0, *scM1, *scG0, *scG1;
  float *fP, *pP, *Kp, *Sinvp, *Fp, *Cp, *CsTp, *Dmp, *dvnp;
  int N0cap, T, NC;
};

union F4 { float4 v; float f[4]; };

// ---------- helpers (blockDim.x == 256 unless noted) ----------

__device__ __forceinline__ void g2l(float* W, const float* G) {
  for (int e = threadIdx.x*4; e < 4096; e += 1024) {
    float4 v = *(const float4*)(G + e);
    *(float4*)(W + (e>>6)*LDW + (e&63)) = v;
  }
  __syncthreads();
}
__device__ __forceinline__ void l2g(float* G, const float* W) {
  for (int e = threadIdx.x*4; e < 4096; e += 1024)
    *(float4*)(G + e) = *(const float4*)(W + (e>>6)*LDW + (e&63));
  __syncthreads();
}
__device__ __forceinline__ void l2g2(float* G1, const float* Wa,
                                     float* G2, const float* Wb) {
  for (int e = threadIdx.x*4; e < 4096; e += 1024) {
    int base = (e>>6)*LDW + (e&63);
    *(float4*)(G1 + e) = *(const float4*)(Wa + base);
    *(float4*)(G2 + e) = *(const float4*)(Wb + base);
  }
  __syncthreads();
}
__device__ __forceinline__ void l2g3(float* G1, const float* Wa,
                                     float* G2, const float* Wb,
                                     float* G3, const float* Wc) {
  for (int e = threadIdx.x*4; e < 4096; e += 1024) {
    int base = (e>>6)*LDW + (e&63);
    *(float4*)(G1 + e) = *(const float4*)(Wa + base);
    *(float4*)(G2 + e) = *(const float4*)(Wb + base);
    *(float4*)(G3 + e) = *(const float4*)(Wc + base);
  }
  __syncthreads();
}
__device__ __forceinline__ void l2g_T(float* G, const float* W) {
  for (int e = threadIdx.x; e < 4096; e += 256)
    G[e] = W[(e&63)*LDW + (e>>6)];
  __syncthreads();
}
__device__ __forceinline__ void copyW(float* D, const float* S) {
  for (int e = threadIdx.x*4; e < 4096; e += 1024) {
    int base = (e>>6)*LDW + (e&63);
    *(float4*)(D + base) = *(const float4*)(S + base);
  }
  __syncthreads();
}
__device__ __forceinline__ void set_id(float* W) {
  for (int e = threadIdx.x; e < 4096; e += 256)
    W[(e>>6)*LDW + (e&63)] = ((e>>6) == (e&63)) ? 1.f : 0.f;
  __syncthreads();
}
// G = I - W (LDS -> global)
__device__ __forceinline__ void store_id_sub(float* G, const float* W) {
  for (int e = threadIdx.x; e < 4096; e += 256)
    G[e] = (((e>>6) == (e&63)) ? 1.f : 0.f) - W[(e>>6)*LDW + (e&63)];
  __syncthreads();
}
// G_dst = G_src - W
__device__ __forceinline__ void rsub_store(float* Gd, const float* Gs, const float* W) {
  for (int e = threadIdx.x*4; e < 4096; e += 1024) {
    int base = (e>>6)*LDW + (e&63);
    F4 a, g; a.v = *(const float4*)(W + base); g.v = *(const float4*)(Gs + e);
    F4 o; o.f[0]=g.f[0]-a.f[0]; o.f[1]=g.f[1]-a.f[1]; o.f[2]=g.f[2]-a.f[2]; o.f[3]=g.f[3]-a.f[3];
    *(float4*)(Gd + e) = o.v;
  }
  __syncthreads();
}

__device__ __forceinline__ void redpair(float& ma, float& md, float* red) {
  #pragma unroll
  for (int off = 32; off; off >>= 1) {
    ma = fmaxf(ma, __shfl_xor(ma, off, 64));
    md = fmaxf(md, __shfl_xor(md, off, 64));
  }
  const int w = threadIdx.x >> 6;
  if ((threadIdx.x & 63) == 0) { red[w] = ma; red[4 + w] = md; }
  __syncthreads();
  ma = fmaxf(fmaxf(red[0], red[1]), fmaxf(red[2], red[3]));
  md = fmaxf(fmaxf(red[4], red[5]), fmaxf(red[6], red[7]));
  __syncthreads();
}

// D(stride LDD) = [ADD +/-] op(A)*op(B)
template<int TRANSA, int TRANSB, int MODE, int LDD>
__device__ __forceinline__ void mm(float* __restrict__ D,
    const float* __restrict__ A, int lda,
    const float* __restrict__ B, int ldb,
    const float* __restrict__ ADD, int ldadd)
{
  const int tid = threadIdx.x;
  const int i0 = (tid >> 4) << 2, j0 = (tid & 15) << 2;
  float acc[4][4] = {};
  for (int k0 = 0; k0 < NN; k0 += 4) {
    F4 av[4], bv[4];
    #pragma unroll
    for (int u = 0; u < 4; ++u) {
      bv[u].v = TRANSB ? *(const float4*)(B + (j0+u)*ldb + k0)
                       : *(const float4*)(B + (k0+u)*ldb + j0);
      av[u].v = TRANSA ? *(const float4*)(A + (k0+u)*lda + i0)
                       : *(const float4*)(A + (i0+u)*lda + k0);
    }
    #pragma unroll
    for (int kk = 0; kk < 4; ++kk) {
      #pragma unroll
      for (int di = 0; di < 4; ++di) {
        float a = TRANSA ? av[kk].f[di] : av[di].f[kk];
        #pragma unroll
        for (int dj = 0; dj < 4; ++dj) {
          float bb = TRANSB ? bv[dj].f[kk] : bv[kk].f[dj];
          acc[di][dj] += a * bb;
        }
      }
    }
  }
  #pragma unroll
  for (int di = 0; di < 4; ++di) {
    if (MODE == 0 && (LDD & 3) == 0) {
      F4 o;
      #pragma unroll
      for (int dj = 0; dj < 4; ++dj) o.f[dj] = acc[di][dj];
      *(float4*)(D + (i0+di)*LDD + j0) = o.v;
    } else {
      #pragma unroll
      for (int dj = 0; dj < 4; ++dj) {
        float v = acc[di][dj];
        if (MODE == 1) v = ADD[(i0+di)*ldadd + j0+dj] + v;
        if (MODE == 2) v = ADD[(i0+di)*ldadd + j0+dj] - v;
        D[(i0+di)*LDD + j0+dj] = v;
      }
    }
  }
  __syncthreads();
}

// two INDEPENDENT matmuls in one barrier region
template<int TA1,int TB1,int MO1,int LD1, int TA2,int TB2,int MO2,int LD2>
__device__ __forceinline__ void mm2(
    float* __restrict__ D1, const float* __restrict__ A1, int lda1,
    const float* __restrict__ B1, int ldb1, const float* __restrict__ AD1, int ldad1,
    float* __restrict__ D2, const float* __restrict__ A2, int lda2,
    const float* __restrict__ B2, int ldb2, const float* __restrict__ AD2, int ldad2)
{
  const int tid = threadIdx.x;
  const int i0 = (tid >> 4) << 2, j0 = (tid & 15) << 2;
  float acc1[4][4] = {}, acc2[4][4] = {};
  for (int k0 = 0; k0 < NN; k0 += 4) {
    F4 av1[4], bv1[4], av2[4], bv2[4];
    #pragma unroll
    for (int u = 0; u < 4; ++u) {
      bv1[u].v = TB1 ? *(const float4*)(B1 + (j0+u)*ldb1 + k0)
                     : *(const float4*)(B1 + (k0+u)*ldb1 + j0);
      av1[u].v = TA1 ? *(const float4*)(A1 + (k0+u)*lda1 + i0)
                     : *(const float4*)(A1 + (i0+u)*lda1 + k0);
      bv2[u].v = TB2 ? *(const float4*)(B2 + (j0+u)*ldb2 + k0)
                     : *(const float4*)(B2 + (k0+u)*ldb2 + j0);
      av2[u].v = TA2 ? *(const float4*)(A2 + (k0+u)*lda2 + i0)
                     : *(const float4*)(A2 + (i0+u)*lda2 + k0);
    }
    #pragma unroll
    for (int kk = 0; kk < 4; ++kk) {
      #pragma unroll
      for (int di = 0; di < 4; ++di) {
        float a1 = TA1 ? av1[kk].f[di] : av1[di].f[kk];
        float a2 = TA2 ? av2[kk].f[di] : av2[di].f[kk];
        #pragma unroll
        for (int dj = 0; dj < 4; ++dj) {
          acc1[di][dj] += a1 * (TB1 ? bv1[dj].f[kk] : bv1[kk].f[dj]);
          acc2[di][dj] += a2 * (TB2 ? bv2[dj].f[kk] : bv2[kk].f[dj]);
        }
      }
    }
  }
  #pragma unroll
  for (int di = 0; di < 4; ++di) {
    if (MO1 == 0 && (LD1 & 3) == 0) {
      F4 o;
      #pragma unroll
      for (int dj = 0; dj < 4; ++dj) o.f[dj] = acc1[di][dj];
      *(float4*)(D1 + (i0+di)*LD1 + j0) = o.v;
    } else {
      #pragma unroll
      for (int dj = 0; dj < 4; ++dj) {
        float v = acc1[di][dj];
        if (MO1 == 1) v = AD1[(i0+di)*ldad1 + j0+dj] + v;
        if (MO1 == 2) v = AD1[(i0+di)*ldad1 + j0+dj] - v;
        D1[(i0+di)*LD1 + j0+dj] = v;
      }
    }
  }
  #pragma unroll
  for (int di = 0; di < 4; ++di) {
    if (MO2 == 0 && (LD2 & 3) == 0) {
      F4 o;
      #pragma unroll
      for (int dj = 0; dj < 4; ++dj) o.f[dj] = acc2[di][dj];
      *(float4*)(D2 + (i0+di)*LD2 + j0) = o.v;
    } else {
      #pragma unroll
      for (int dj = 0; dj < 4; ++dj) {
        float v = acc2[di][dj];
        if (MO2 == 1) v = AD2[(i0+di)*ldad2 + j0+dj] + v;
        if (MO2 == 2) v = AD2[(i0+di)*ldad2 + j0+dj] - v;
        D2[(i0+di)*LD2 + j0+dj] = v;
      }
    }
  }
  __syncthreads();
}

// panel-16 Cholesky in stride-LDW buffer (256 threads). upper zeroed.
template<bool WANTLOG>
__device__ __forceinline__ void chol68(float* __restrict__ Sm, float* part, float* invd) {
  const int tid = threadIdx.x;
  const int lane = tid & 63;
  #pragma unroll
  for (int p = 0; p < 4; ++p) {
    const int j0 = p * 16;
    if (p > 0) {
      const int i = tid & 63;
      const int jq = (tid >> 6) * 4;
      float acc[4] = {0.f, 0.f, 0.f, 0.f};
      for (int kb = 0; kb < j0; kb += 4) {
        F4 av; av.v = *(const float4*)(Sm + i*LDW + kb);
        #pragma unroll
        for (int q = 0; q < 4; ++q) {
          F4 bv; bv.v = *(const float4*)(Sm + (j0 + jq + q)*LDW + kb);
          acc[q] += av.f[0]*bv.f[0] + av.f[1]*bv.f[1] + av.f[2]*bv.f[2] + av.f[3]*bv.f[3];
        }
      }
      #pragma unroll
      for (int q = 0; q < 4; ++q)
        Sm[i*LDW + j0 + jq + q] -= acc[q];
      __syncthreads();
    }
    if (tid < 64) {
      float t[16];
      F4 tv;
      #pragma unroll
      for (int q4 = 0; q4 < 4; ++q4) {
        tv.v = *(const float4*)(Sm + lane*LDW + j0 + 4*q4);
        t[4*q4] = tv.f[0]; t[4*q4+1] = tv.f[1]; t[4*q4+2] = tv.f[2]; t[4*q4+3] = tv.f[3];
      }
      #pragma unroll
      for (int jj = 0; jj < 16; ++jj) {
        float acc = t[jj];
        #pragma unroll
        for (int kk = 0; kk < jj; ++kk)
          acc -= __shfl(t[kk], j0 + jj, 64) * t[kk];
        float piv = __shfl(acc, j0 + jj, 64);
        float sq = sqrtf(fmaxf(piv, 1e-30f));
        float inv = 1.0f / sq;
        if (lane == j0 + jj) {
          t[jj] = sq;
          invd[j0 + jj] = inv;
          if (WANTLOG) part[j0 + jj] = logf(sq);
        } else {
          t[jj] = (lane > j0 + jj) ? acc * inv : 0.f;
        }
      }
      #pragma unroll
      for (int q4 = 0; q4 < 4; ++q4) {
        tv.f[0] = t[4*q4]; tv.f[1] = t[4*q4+1]; tv.f[2] = t[4*q4+2]; tv.f[3] = t[4*q4+3];
        *(float4*)(Sm + lane*LDW + j0 + 4*q4) = tv.v;
      }
    }
    __syncthreads();
  }
}

// forward triangular solve DST <- L^-1 op(SRC); TR=1 reads SRC transposed.
template<int TR>
__device__ __forceinline__ void tri_fwd_ld(const float* __restrict__ L,
                                           const float* __restrict__ invd,
                                           const float* __restrict__ SRC, int lds,
                                           float* __restrict__ DST, int ldd) {
  const int col = threadIdx.x >> 2, p = threadIdx.x & 3;
  const int gbase = (threadIdx.x & 63) & ~3;
  float xr[16];
  #pragma unroll
  for (int u = 0; u < 16; ++u)
    xr[u] = TR ? SRC[col*lds + (4*u+p)] : SRC[(4*u+p)*lds + col];
  #pragma unroll
  for (int i = 0; i < NN; ++i) {
    const int idx = i >> 2, ow = i & 3;
    float yi = xr[idx] * invd[i];
    yi = __shfl(yi, gbase + ow, 64);
    if (p == ow) xr[idx] = yi;
    else if (p > ow) xr[idx] -= L[(4*idx+p)*LDW + i] * yi;
    #pragma unroll
    for (int u = idx+1; u < 16; ++u)
      xr[u] -= L[(4*u+p)*LDW + i] * yi;
  }
  #pragma unroll
  for (int u = 0; u < 16; ++u) DST[(4*u+p)*ldd + col] = xr[u];
  __syncthreads();
}

// TWO independent forward solves in one barrier region
template<int TR1,int TR2>
__device__ __forceinline__ void tri_fwd2(
    const float* __restrict__ L1, const float* __restrict__ ivd1,
    const float* __restrict__ S1, int lds1, float* __restrict__ D1, int ldd1,
    const float* __restrict__ L2, const float* __restrict__ ivd2,
    const float* __restrict__ S2, int lds2, float* __restrict__ D2, int ldd2)
{
  const int col = threadIdx.x >> 2, p = threadIdx.x & 3;
  const int gbase = (threadIdx.x & 63) & ~3;
  float xr[16], xs[16];
  #pragma unroll
  for (int u = 0; u < 16; ++u) {
    xr[u] = TR1 ? S1[col*lds1 + (4*u+p)] : S1[(4*u+p)*lds1 + col];
    xs[u] = TR2 ? S2[col*lds2 + (4*u+p)] : S2[(4*u+p)*lds2 + col];
  }
  #pragma unroll
  for (int i = 0; i < NN; ++i) {
    const int idx = i >> 2, ow = i & 3;
    float yi = xr[idx] * ivd1[i];
    yi = __shfl(yi, gbase + ow, 64);
    float zi = xs[idx] * ivd2[i];
    zi = __shfl(zi, gbase + ow, 64);
    if (p == ow) xr[idx] = yi;
    else if (p > ow) xr[idx] -= L1[(4*idx+p)*LDW + i] * yi;
    if (p == ow) xs[idx] = zi;
    else if (p > ow) xs[idx] -= L2[(4*idx+p)*LDW + i] * zi;
    #pragma unroll
    for (int u = idx+1; u < 16; ++u) {
      xr[u] -= L1[(4*u+p)*LDW + i] * yi;
      xs[u] -= L2[(4*u+p)*LDW + i] * zi;
    }
  }
  #pragma unroll
  for (int u = 0; u < 16; ++u) {
    D1[(4*u+p)*ldd1 + col] = xr[u];
    D2[(4*u+p)*ldd2 + col] = xs[u];
  }
  __syncthreads();
}

// backward triangular solve DST <- L^-T SRC
__device__ __forceinline__ void tri_bwd_ld(const float* __restrict__ L,
                                           const float* __restrict__ invd,
                                           const float* __restrict__ SRC, int lds,
                                           float* __restrict__ DST, int ldd) {
  const int col = threadIdx.x >> 2, p = threadIdx.x & 3;
  const int gbase = (threadIdx.x & 63) & ~3;
  float xr[16];
  #pragma unroll
  for (int u = 0; u < 16; ++u) xr[u] = SRC[(4*u+p)*lds + col];
  #pragma unroll
  for (int i = NN-1; i >= 0; --i) {
    const int idx = i >> 2, ow = i & 3;
    float zi = xr[idx] * invd[i];
    zi = __shfl(zi, gbase + ow, 64);
    if (p == ow) xr[idx] = zi;
    else if (p < ow) xr[idx] -= L[i*LDW + 4*idx+p] * zi;
    #pragma unroll
    for (int u = 0; u < idx; ++u)
      xr[u] -= L[i*LDW + 4*u+p] * zi;
  }
  #pragma unroll
  for (int u = 0; u < 16; ++u) DST[(4*u+p)*ldd + col] = xr[u];
  __syncthreads();
}

// one forward + one backward solve (same L), interleaved
__device__ __forceinline__ void tri_fb2(
    const float* __restrict__ L, const float* __restrict__ ivd,
    const float* __restrict__ Sf, int ldsf, float* __restrict__ Df, int lddf,
    const float* __restrict__ Sb, int ldsb, float* __restrict__ Db, int lddb)
{
  const int col = threadIdx.x >> 2, p = threadIdx.x & 3;
  const int gbase = (threadIdx.x & 63) & ~3;
  float xf[16], xb[16];
  #pragma unroll
  for (int u = 0; u < 16; ++u) {
    xf[u] = Sf[(4*u+p)*ldsf + col];
    xb[u] = Sb[(4*u+p)*ldsb + col];
  }
  #pragma unroll
  for (int k = 0; k < NN; ++k) {
    {
      const int i = k, idx = i >> 2, ow = i & 3;
      float yi = xf[idx] * ivd[i];
      yi = __shfl(yi, gbase + ow, 64);
      if (p == ow) xf[idx] = yi;
      else if (p > ow) xf[idx] -= L[(4*idx+p)*LDW + i] * yi;
      #pragma unroll
      for (int u = idx+1; u < 16; ++u)
        xf[u] -= L[(4*u+p)*LDW + i] * yi;
    }
    {
      const int i = NN-1-k, idx = i >> 2, ow = i & 3;
      float zi = xb[idx] * ivd[i];
      zi = __shfl(zi, gbase + ow, 64);
      if (p == ow) xb[idx] = zi;
      else if (p < ow) xb[idx] -= L[i*LDW + 4*idx+p] * zi;
      #pragma unroll
      for (int u = 0; u < idx; ++u)
        xb[u] -= L[i*LDW + 4*u+p] * zi;
    }
  }
  #pragma unroll
  for (int u = 0; u < 16; ++u) {
    Df[(4*u+p)*lddf + col] = xf[u];
    Db[(4*u+p)*lddb + col] = xb[u];
  }
  __syncthreads();
}

// two-sided triangular solve: DST <- L^-T L^-1 SRC
__device__ __forceinline__ void tri_solve2(const float* __restrict__ L,
                                           const float* __restrict__ invd,
                                           const float* __restrict__ SRC,
                                           float* __restrict__ DST) {
  const int col = threadIdx.x >> 2, p = threadIdx.x & 3;
  const int gbase = (threadIdx.x & 63) & ~3;
  float xr[16];
  #pragma unroll
  for (int u = 0; u < 16; ++u) xr[u] = SRC[(4*u+p)*LDW + col];
  #pragma unroll
  for (int i = 0; i < NN; ++i) {
    const int idx = i >> 2, ow = i & 3;
    float yi = xr[idx] * invd[i];
    yi = __shfl(yi, gbase + ow, 64);
    if (p == ow) xr[idx] = yi;
    else if (p > ow) xr[idx] -= L[(4*idx+p)*LDW + i] * yi;
    #pragma unroll
    for (int u = idx+1; u < 16; ++u)
      xr[u] -= L[(4*u+p)*LDW + i] * yi;
  }
  #pragma unroll
  for (int i = NN-1; i >= 0; --i) {
    const int idx = i >> 2, ow = i & 3;
    float zi = xr[idx] * invd[i];
    zi = __shfl(zi, gbase + ow, 64);
    if (p == ow) xr[idx] = zi;
    else if (p < ow) xr[idx] -= L[i*LDW + 4*idx+p] * zi;
    #pragma unroll
    for (int u = 0; u < idx; ++u)
      xr[u] -= L[i*LDW + 4*u+p] * zi;
  }
  #pragma unroll
  for (int u = 0; u < 16; ++u) DST[(4*u+p)*LDW + col] = xr[u];
  __syncthreads();
}

// TWO independent two-sided solves (same L), in-place, stride LDW
__device__ __forceinline__ void tri_s2x2(const float* __restrict__ L,
                                         const float* __restrict__ invd,
                                         float* __restrict__ X1,
                                         float* __restrict__ X2) {
  const int col = threadIdx.x >> 2, p = threadIdx.x & 3;
  const int gbase = (threadIdx.x & 63) & ~3;
  float xr[16], xs[16];
  #pragma unroll
  for (int u = 0; u < 16; ++u) {
    xr[u] = X1[(4*u+p)*LDW + col];
    xs[u] = X2[(4*u+p)*LDW + col];
  }
  #pragma unroll
  for (int i = 0; i < NN; ++i) {
    const int idx = i >> 2, ow = i & 3;
    float yi = xr[idx] * invd[i];
    yi = __shfl(yi, gbase + ow, 64);
    float zi = xs[idx] * invd[i];
    zi = __shfl(zi, gbase + ow, 64);
    if (p == ow) xr[idx] = yi;
    else if (p > ow) xr[idx] -= L[(4*idx+p)*LDW + i] * yi;
    if (p == ow) xs[idx] = zi;
    else if (p > ow) xs[idx] -= L[(4*idx+p)*LDW + i] * zi;
    #pragma unroll
    for (int u = idx+1; u < 16; ++u) {
      xr[u] -= L[(4*u+p)*LDW + i] * yi;
      xs[u] -= L[(4*u+p)*LDW + i] * zi;
    }
  }
  #pragma unroll
  for (int i = NN-1; i >= 0; --i) {
    const int idx = i >> 2, ow = i & 3;
    float yi = xr[idx] * invd[i];
    yi = __shfl(yi, gbase + ow, 64);
    float zi = xs[idx] * invd[i];
    zi = __shfl(zi, gbase + ow, 64);
    if (p == ow) xr[idx] = yi;
    else if (p < ow) xr[idx] -= L[i*LDW + 4*idx+p] * yi;
    if (p == ow) xs[idx] = zi;
    else if (p < ow) xs[idx] -= L[i*LDW + 4*idx+p] * zi;
    #pragma unroll
    for (int u = 0; u < idx; ++u) {
      xr[u] -= L[i*LDW + 4*u+p] * yi;
      xs[u] -= L[i*LDW + 4*u+p] * zi;
    }
  }
  #pragma unroll
  for (int u = 0; u < 16; ++u) {
    X1[(4*u+p)*LDW + col] = xr[u];
    X2[(4*u+p)*LDW + col] = xs[u];
  }
  __syncthreads();
}

// y(64) = M1*x1 + M2*x2 + addv. 256 threads. y may alias x1/x2/addv.
__device__ __forceinline__ void matvec2(float* __restrict__ y,
    const float* __restrict__ M1, const float* __restrict__ x1,
    const float* __restrict__ M2, const float* __restrict__ x2,
    const float* __restrict__ addv, float* __restrict__ red) {
  const int r = threadIdx.x & 63, p = threadIdx.x >> 6;
  const int kb = p*16;
  float s = 0.f;
  #pragma unroll
  for (int q = 0; q < 4; ++q) {
    F4 mv; mv.v = *(const float4*)(M1 + r*NN + kb + q*4);
    s += mv.f[0]*x1[kb+q*4] + mv.f[1]*x1[kb+q*4+1] + mv.f[2]*x1[kb+q*4+2] + mv.f[3]*x1[kb+q*4+3];
    F4 nv; nv.v = *(const float4*)(M2 + r*NN + kb + q*4);
    s += nv.f[0]*x2[kb+q*4] + nv.f[1]*x2[kb+q*4+1] + nv.f[2]*x2[kb+q*4+2] + nv.f[3]*x2[kb+q*4+3];
  }
  red[p*64 + r] = s;
  __syncthreads();
  if (threadIdx.x < 64) {
    float t = red[r] + red[64+r] + red[128+r] + red[192+r];
    y[r] = t + addv[r];
  }
  __syncthreads();
}

// y = Mg*x + addv (nullable). 256 threads.
__device__ __forceinline__ void matvec256(float* __restrict__ y, const float* __restrict__ Mg,
    const float* __restrict__ x, const float* __restrict__ addv, float* __restrict__ red) {
  const int r = threadIdx.x & 63, p = threadIdx.x >> 6;
  const int kb = p*16;
  float s = 0.f;
  #pragma unroll
  for (int q = 0; q < 4; ++q) {
    F4 mv; mv.v = *(const float4*)(Mg + r*NN + kb + q*4);
    s += mv.f[0]*x[kb+q*4] + mv.f[1]*x[kb+q*4+1] + mv.f[2]*x[kb+q*4+2] + mv.f[3]*x[kb+q*4+3];
  }
  red[p*64 + r] = s;
  __syncthreads();
  if (threadIdx.x < 64) {
    float t = red[r] + red[64+r] + red[128+r] + red[192+r];
    y[r] = t + (addv ? addv[r] : 0.f);
  }
  __syncthreads();
}

// ---------- kernels ----------

__global__ __launch_bounds__(256) void k0(KP P) {
  __shared__ __align__(16) float W0[LDW*NN];
  const int tid = threadIdx.x;
  for (int e = tid; e < 4096; e += 256) {
    int r = e>>6, cc = e&63;
    P.AT[e] = P.A[cc*64+r];
    P.HT[e] = P.H[cc*64+r];
  }
  if (tid < 64) {
    float s = 0.f;
    for (int k = 0; k < 64; ++k) s += P.H[tid*64+k]*P.b[k];
    P.Hb[tid] = s;
  }
  __syncthreads();
  mm<0,0,0,LDW>(W0, P.H, NN, P.A, NN, nullptr, 0);   // HA = H*A
  l2g(P.HA, W0);
}

// kA: leaf + fP0 + 5 doublings (E^2..E^32; kB decomposes t = 32q + bits)
__global__ __launch_bounds__(256) void kA(KP P) {
  __shared__ __align__(16) float LA[LDW*NN], LC[LDW*NN], LJ[LDW*NN], LL[LDW*NN];
  __shared__ __align__(16) float W0[LDW*NN], W1[LDW*NN], W2[LDW*NN], W3[LDW*NN], W4[LDW*NN];
  __shared__ float part[64], iv1[64], iv2[64];
  const int tid = threadIdx.x;
  mm2<0,0,0,LDW, 0,0,0,LDW>(W0, P.H,NN, P.Q,NN, nullptr,0,
                            W2, P.H,NN, P.P0,NN, nullptr,0);      // T = H Q ; HP0
  mm2<0,1,1,LDW, 0,1,1,LDW>(W1, W0,LDW, P.H,NN, P.R,NN,
                            W3, W2,LDW, P.H,NN, P.R,NN);          // St ; S0
  chol68<false>(W1, part, iv1);
  chol68<false>(W3, part, iv2);
  tri_fwd2<0,0>(W1, iv1, P.HA,NN, W4,LDW,
                W3, iv2, W2,LDW,  W2,LDW);                         // U ; U0
  mm2<1,0,0,LDW, 1,0,2,LDW>(LJ, W4,LDW, W4,LDW, nullptr,0,
                            W3, W2,LDW, W2,LDW, P.P0,NN);          // Jt ; fP0
  l2g(P.fP, W3);
  copyW(LL, LJ);
  chol68<false>(LL, part, iv2);                                    // Lt
  tri_fb2(W1, iv1, W0,LDW, W3,LDW,  W4,LDW, W4,LDW);               // V ; X
  mm2<1,0,2,LDW, 1,0,2,LDW>(LA, W0,LDW, W4,LDW, P.A,NN,
                            LC, W3,LDW, W3,LDW, P.Q,NN);           // At ; Ct
  l2g3(P.EA, LA, P.EC, LC, P.EL, LL);
  for (int j = 0; j < 5 && (2 << j) <= P.N0cap - 1; ++j) {
    mm2<0,0,0,LDW, 1,0,0,LDW>(W0, LC,LDW, LL,LDW, nullptr,0,
                              W2, LL,LDW, LA,LDW, nullptr,0);      // Pm ; T1
    mm<1,0,0,LDW>(W1, LL,LDW, W0,LDW, nullptr,0);                  // W
    if (tid < 64) W1[tid*LDW + tid] += 1.f;
    __syncthreads();
    chol68<false>(W1, part, iv1);                                   // Lw
    tri_fwd2<0,1>(W1, iv1, W2,LDW, W2,LDW,
                  W1, iv1, W0,LDW, W3,LDW);                         // T2f ; T5
    mm2<1,0,1,LDW, 1,0,2,LDW>(LJ, W2,LDW, W2,LDW, LJ,LDW,
                              W4, W3,LDW, W3,LDW, LC,LDW);          // Jn ; ZC
    copyW(LL, LJ);
    chol68<false>(LL, part, iv2);                                   // Ln
    tri_bwd_ld(W1, iv1, W2,LDW, W2,LDW);                            // T2
    mm<0,0,2,LDW>(W3, W0,LDW, W2,LDW, LA,LDW);                      // ZA
    mm2<0,0,0,LDW, 0,0,0,LDW>(W2, LA,LDW, W3,LDW, nullptr,0,
                              W0, LA,LDW, W4,LDW, nullptr,0);       // An ; T7
    mm<0,1,1,LDW>(LC, W0,LDW, LA,LDW, LC,LDW);                      // Cn
    copyW(LA, W2);
    l2g3(P.EA+(size_t)(j+1)*4096, LA, P.EC+(size_t)(j+1)*4096, LC,
         P.EL+(size_t)(j+1)*4096, LL);
  }
}

// block t: fP_t via greedy decomposition; also pP_{t+1}
__global__ __launch_bounds__(256) void kB(KP P) {
  __shared__ __align__(16) float Wc[LDW*NN], W0[LDW*NN], W1[LDW*NN], W2[LDW*NN];
  __shared__ float part[64], ivw[64];
  const int t = blockIdx.x;
  if (t == 0) {
    for (int e = threadIdx.x*4; e < 4096; e += 1024)
      *(float4*)(P.pP + e) = *(const float4*)(P.P0 + e);
    __syncthreads();
    mm<0,0,0,LDW>(W1, P.A, NN, P.fP, NN, nullptr, 0);
    mm<0,0,1,LDW>(W0, W1, LDW, P.AT, NN, P.Q, NN);
    l2g(P.pP + 4096, W0);
    return;
  }
  g2l(Wc, P.fP);
  int rem = t;
  for (int j = 5; j >= 0; --j) {
    const int pw = 1 << j;
    if (j > 0 && pw > P.N0cap - 1) continue;
    while (rem >= pw) {
      const float* Ag = P.EA + j*4096;
      const float* Cg = P.EC + j*4096;
      const float* Lg = P.EL + j*4096;
      mm<0,0,0,LDW>(W0, Wc, LDW, Lg, NN, nullptr, 0);     // Pm = C L
      mm<1,0,0,LDW>(W1, Lg, NN, W0, LDW, nullptr, 0);     // W = L^T Pm
      if (threadIdx.x < 64) W1[threadIdx.x*LDW + threadIdx.x] += 1.f;
      __syncthreads();
      chol68<false>(W1, part, ivw);
      tri_fwd_ld<1>(W1, ivw, W0, LDW, W2, LDW);           // T5
      mm<1,0,2,LDW>(W1, W2, LDW, W2, LDW, Wc, LDW);       // ZC
      mm<0,0,0,LDW>(W0, Ag, NN, W1, LDW, nullptr, 0);     // T7
      mm<0,1,1,LDW>(Wc, W0, LDW, Ag, NN, Cg, NN);         // C'
      rem -= pw;
    }
  }
  l2g(P.fP + (size_t)t*4096, Wc);
  mm<0,0,0,LDW>(W0, P.A, NN, Wc, LDW, nullptr, 0);
  mm<0,0,1,LDW>(W1, W0, LDW, P.AT, NN, P.Q, NN);
  l2g(P.pP + (size_t)(t+1)*4096, W1);
}

__global__ __launch_bounds__(256) void kC(KP P) {
  __shared__ float red[16];
  const int t = blockIdx.x;
  const float* cur = P.fP + (size_t)t*4096;
  const float* prv = P.fP + (size_t)(t > 0 ? t-1 : 0)*4096;
  float a = 0.f, d = 0.f;
  for (int e = threadIdx.x*4; e < 4096; e += 1024) {
    F4 v, pv; v.v = *(const float4*)(cur + e); pv.v = *(const float4*)(prv + e);
    #pragma unroll
    for (int q = 0; q < 4; ++q) {
      a = fmaxf(a, fabsf(v.f[q]));
      d = fmaxf(d, fabsf(v.f[q] - pv.f[q]));
    }
  }
  redpair(a, d, red);
  if (threadIdx.x == 0) { P.astat[t] = a; P.dstat[t] = (t > 0) ? d : 0.f; }
}

__global__ __launch_bounds__(256) void kN(KP P) {
  __shared__ float as_[N0MAX], ds_[N0MAX];
  const int cap = P.N0cap;
  for (int i = threadIdx.x; i < cap; i += 256) { as_[i] = P.astat[i]; ds_[i] = P.dstat[i]; }
  __syncthreads();
  if (threadIdx.x == 0) {
    float mabs = 1e-20f, dref = 1e30f;
    int tref = 0, N0 = cap;
    bool conv = false;
    for (int t = 0; t < cap; ++t) {
      mabs = fmaxf(mabs, as_[t]);
      if (t > 0) {
        float d = ds_[t];
        if (d <= EPS_HARD*mabs) { N0 = t+1; conv = true; }
        if (d < STALL_IMP*dref) { dref = d; tref = t; }
        else if (t - tref >= STALL_WIN && t >= 12 && d < EPS_GATE*mabs) { N0 = t+1; conv = true; }
      }
      if (conv) break;
    }
    P.meta[0] = N0; P.metaF[1] = mabs;
  }
}

// merged: blocks 0..cap-1 = per-t derived quantities; last block = steady-state part A
__global__ __launch_bounds__(256) void k1x(KP P) {
  __shared__ __align__(16) float W0[LDW*NN], W1[LDW*NN], W2[LDW*NN], CH[LDW*NN];
  __shared__ float part[64], invd[64];
  const int tid = threadIdx.x;
  const int N0 = P.meta[0];
  if ((int)blockIdx.x == (int)gridDim.x - 1) {
    // ---- steady-state derived (part A) ----
    const float* fPssG = P.fP + (size_t)(N0-1)*4096;
    g2l(CH, fPssG);
    mm<0,0,0,LDW>(W1, P.A, NN, CH, LDW, nullptr, 0);
    mm<0,0,1,LDW>(W0, W1, LDW, P.AT, NN, P.Q, NN);            // pPss
    l2g(P.pPss, W0);
    mm<0,0,0,LDW>(W1, P.H, NN, W0, LDW, nullptr, 0);          // HP
    mm<0,0,1,LDW>(CH, W1, LDW, P.HT, NN, P.R, NN);            // S
    chol68<true>(CH, part, invd);
    if (tid == 0) { float s=0.f; for (int j=0;j<64;++j) s += part[j]; P.metaF[0] = s; }
    set_id(W0);
    tri_s2x2(CH, invd, W1, W0);                               // X ; Sinv
    l2g_T(P.Kss, W1);
    if (tid < 64) {
      float s = P.b[tid];
      for (int k = 0; k < 64; ++k) s -= W1[k*LDW + tid]*P.Hb[k];
      P.uss[tid] = s;
    }
    __syncthreads();
    l2g(P.Sinvss, W0);
    mm<1,0,2,LDW>(W0, W1, LDW, P.HA, NN, P.A, NN);            // F_ss
    l2g(P.Fss, W0);
    mm<0,0,0,LDW>(W1, P.A, NN, fPssG, NN, nullptr, 0);        // AF
    g2l(CH, P.pPss);
    chol68<false>(CH, part, invd);
    tri_solve2(CH, invd, W1, W1);                             // X2 = Css^T
    l2g(P.CsTss, W1);
    l2g_T(P.Css, W1);
    mm<1,0,0,LDW>(W2, W1, LDW, P.A, NN, nullptr, 0);          // Css*A
    store_id_sub(P.Dmss, W2);
    if (tid < 64) {
      float s = 0.f;
      for (int k = 0; k < 64; ++k) s += W1[k*LDW + tid]*P.b[k];
      P.dvnss[tid] = -s;
    }
    return;
  }
  const int t = blockIdx.x;
  if (t >= N0) return;
  mm<0,0,0,LDW>(W1, P.H, NN, P.pP + (size_t)t*4096, NN, nullptr, 0);
  mm<0,0,1,LDW>(CH, W1, LDW, P.HT, NN, P.R, NN);
  chol68<true>(CH, part, invd);
  if (tid == 0) { float s=0.f; for (int j=0;j<64;++j) s += part[j]; P.ld_pref[t] = s; }
  set_id(W0);
  tri_s2x2(CH, invd, W1, W0);
  l2g_T(P.Kp + (size_t)t*4096, W1);
  if (tid < 64) {
    float s = P.b[tid];
    for (int k = 0; k < 64; ++k) s -= W1[k*LDW + tid]*P.Hb[k];
    P.u_pref[t*64 + tid] = s;
  }
  __syncthreads();
  l2g(P.Sinvp + (size_t)t*4096, W0);
  mm<1,0,2,LDW>(W0, W1, LDW, P.HA, NN, P.A, NN);
  l2g(P.Fp + (size_t)t*4096, W0);
  mm<0,0,0,LDW>(W1, P.A, NN, P.fP + (size_t)t*4096, NN, nullptr, 0);
  g2l(CH, P.pP + (size_t)(t+1)*4096);
  chol68<false>(CH, part, invd);
  tri_solve2(CH, invd, W1, W1);                               // X2 = C_t^T
  l2g(P.CsTp + (size_t)t*4096, W1);
  l2g_T(P.Cp + (size_t)t*4096, W1);
  mm<1,0,0,LDW>(W0, W1, LDW, P.A, NN, nullptr, 0);            // C_t*A
  store_id_sub(P.Dmp + (size_t)t*4096, W0);
  if (tid < 64) {
    float s = 0.f;
    for (int k = 0; k < 64; ++k) s += W1[k*LDW + tid]*P.b[k];
    P.dvnp[t*64 + tid] = -s;
  }
}

// 2 concurrent blocks: 0 = C/F power ladder (incl. scan powers), 1 = Stein solve
__global__ __launch_bounds__(256) void k1y(KP P) {
  __shared__ __align__(16) float W0[LDW*NN], W1[LDW*NN], W2[LDW*NN], W3[LDW*NN], W4[LDW*NN], CH[LDW*NN];
  const int N0 = P.meta[0];
  const float* fPssG = P.fP + (size_t)(N0-1)*4096;
  if (blockIdx.x == 0) {
    mm2<0,0,0,LDW, 0,0,0,LDW>(W1, P.Css,NN, P.Css,NN, nullptr,0,
                              W4, P.Fss,NN, P.Fss,NN, nullptr,0);   // C2 ; F2
    l2g(P.Pw2, W1);
    mm2<0,0,0,LDW, 0,0,0,LDW>(W2, W1,LDW, W1,LDW, nullptr,0,
                              W3, W4,LDW, W4,LDW, nullptr,0);       // C4 ; F4
    l2g(P.Pw4, W2);
    mm2<0,0,0,LDW, 0,0,0,LDW>(W0, W2,LDW, W2,LDW, nullptr,0,
                              W4, W3,LDW, W3,LDW, nullptr,0);       // C8 ; F8
    l2g(P.Pw8, W0);
    mm2<0,0,0,LDW, 0,0,0,LDW>(W1, W0,LDW, W0,LDW, nullptr,0,
                              W3, W4,LDW, W4,LDW, nullptr,0);       // C16 ; F16
    l2g(P.Pw16, W1);
    mm2<0,0,0,LDW, 0,0,0,LDW>(W2, W1,LDW, W1,LDW, nullptr,0,
                              W4, W3,LDW, W3,LDW, nullptr,0);       // C32 ; F32
    l2g2(P.Cpow32, W2, P.Fpow, W4);
    mm2<0,0,0,LDW, 0,0,0,LDW>(W0, W2,LDW, W2,LDW, nullptr,0,
                              W3, W4,LDW, W4,LDW, nullptr,0);       // C64 ; F64
    l2g2(P.Pw64, W0, P.FpwHi, W3);
    mm2<0,0,0,LDW, 0,0,0,LDW>(W1, W0,LDW, W0,LDW, nullptr,0,
                              W4, W3,LDW, W3,LDW, nullptr,0);       // C128 ; F128
    l2g2(P.Pw128, W1, P.FpwHi + 4096, W4);
    mm2<0,0,0,LDW, 0,0,0,LDW>(W2, W1,LDW, W1,LDW, nullptr,0,
                              W3, W4,LDW, W4,LDW, nullptr,0);       // C256 ; F256
    l2g2(P.CpwHi, W2, P.FpwHi + 2*4096, W3);
    mm2<0,0,0,LDW, 0,0,0,LDW>(W0, W2,LDW, W2,LDW, nullptr,0,
                              W4, W3,LDW, W3,LDW, nullptr,0);       // C512 ; F512
    l2g2(P.CpwHi + 4096, W0, P.FpwHi + 3*4096, W4);
    mm2<0,0,0,LDW, 0,0,0,LDW>(W1, W0,LDW, W0,LDW, nullptr,0,
                              W3, W4,LDW, W4,LDW, nullptr,0);       // C1024 ; F1024
    l2g2(P.CpwHi + 2*4096, W1, P.FpwHi + 4*4096, W3);
    mm2<0,0,0,LDW, 0,0,0,LDW>(W2, W1,LDW, W1,LDW, nullptr,0,
                              W4, W3,LDW, W3,LDW, nullptr,0);       // C2048 ; F2048
    l2g2(P.CpwHi + 3*4096, W2, P.FpwHi + 5*4096, W4);
    mm<0,0,0,LDW>(W0, P.Pw16, NN, P.Pw8, NN, nullptr, 0);           // C24
    mm<0,0,0,LDW>(W1, W0, LDW, P.Pw4, NN, nullptr, 0);              // C28
    mm<0,0,0,LDW>(W2, W1, LDW, P.Pw2, NN, nullptr, 0);              // C30
    mm<0,0,0,LDW>(W0, W2, LDW, P.Css, NN, nullptr, 0);              // C31
    l2g(P.Cpow31, W0);
  } else {
    g2l(W1, P.Css);
    g2l(W2, P.CsTss);
    g2l(W0, P.pPss);
    mm<0,0,0,LDW>(CH, W1, LDW, W0, LDW, nullptr, 0);                // C*pPss
    mm<0,0,2,LDW>(W0, CH, LDW, W2, LDW, fPssG, NN);                 // X = fPss - (C pPss) C'
    float *m1 = W1, *m2 = W2, *t1 = W3, *t2 = W4;
    for (int it = 0; it < 7; ++it) {
      mm2<0,0,0,LDW, 0,0,0,LDW>(CH, m1,LDW, W0,LDW, nullptr,0,
                                t1, m1,LDW, m1,LDW, nullptr,0);     // M*X ; M^2
      mm2<0,0,1,LDW, 0,0,0,LDW>(W0, CH,LDW, m2,LDW, W0,LDW,
                                t2, m2,LDW, m2,LDW, nullptr,0);     // X += (MX)M' ; M'^2
      float* tmp = m1; m1 = t1; t1 = tmp;
      tmp = m2; m2 = t2; t2 = tmp;
    }
    l2g(P.sPss, W0);
    rsub_store(P.E0g, fPssG, W0);
  }
}

// smoothed-cov tail + steady middle (merged k1d + k4)
__global__ __launch_bounds__(256) void kTail(KP P) {
  __shared__ __align__(16) float W0[LDW*NN], W1[LDW*NN], W2[LDW*NN];
  const int t = blockIdx.x;
  const int N0 = P.meta[0];
  if (t < N0) return;
  float* dst = P.out_cov + (size_t)t*4096;
  if (t < P.T - N1CAP) {
    for (int e = threadIdx.x*4; e < 4096; e += 1024)
      *(float4*)(dst+e) = *(const float4*)(P.sPss + e);
    return;
  }
  const int k = P.T - 1 - t;
  if (k == 0) {
    const float* src = P.fP + (size_t)(N0-1)*4096;
    for (int e = threadIdx.x*4; e < 4096; e += 1024)
      *(float4*)(dst+e) = *(const float4*)(src+e);
    return;
  }
  const float* pw[8] = {P.Css, P.Pw2, P.Pw4, P.Pw8, P.Pw16, P.Cpow32, P.Pw64, P.Pw128};
  int b = __ffs(k) - 1;
  g2l(W1, pw[b]);
  float* cur = W1; float* oth = W0;
  for (int j = b+1; j < 8; ++j) {
    if ((k >> j) & 1) {
      mm<0,0,0,LDW>(oth, pw[j], NN, cur, LDW, nullptr, 0);
      float* tmp = cur; cur = oth; oth = tmp;
    }
  }
  mm<0,0,0,LDW>(W2, cur, LDW, P.E0g, NN, nullptr, 0);
  mm<0,1,1,LDW>(oth, W2, LDW, cur, LDW, P.sPss, NN);
  l2g(dst, oth);
}

// smoothed-cov prefix suffix-scan
__global__ __launch_bounds__(256) void k1cI(KP P) {
  __shared__ __align__(16) float W1[LDW*NN];
  const int t = blockIdx.x;
  if (t >= P.meta[0]) return;
  const float* Cg = P.Cp + (size_t)t*4096;
  for (int e = threadIdx.x*4; e < 4096; e += 1024)
    *(float4*)(P.scM0 + (size_t)t*4096 + e) = *(const float4*)(Cg + e);
  mm<0,0,0,LDW>(W1, Cg, NN, P.pP + (size_t)(t+1)*4096, NN, nullptr, 0);
  mm<0,0,2,NN>(P.scG0 + (size_t)t*4096, W1, LDW,
               P.CsTp + (size_t)t*4096, NN, P.fP + (size_t)t*4096, NN);
}

__global__ __launch_bounds__(256) void k1cL(KP P, int step, int sidx) {
  __shared__ __align__(16) float W1[LDW*NN];
  const int t = blockIdx.x;
  const int N0 = P.meta[0];
  if (t >= N0) return;
  const float* Msrc = sidx ? P.scM1 : P.scM0;
  const float* Gsrc = sidx ? P.scG1 : P.scG0;
  float* Mdst = sidx ? P.scM0 : P.scM1;
  float* Gdst = sidx ? P.scG0 : P.scG1;
  const int s = t + step;
  if (s >= N0) {
    for (int e = threadIdx.x*4; e < 4096; e += 1024) {
      *(float4*)(Mdst + (size_t)t*4096 + e) = *(const float4*)(Msrc + (size_t)t*4096 + e);
      *(float4*)(Gdst + (size_t)t*4096 + e) = *(const float4*)(Gsrc + (size_t)t*4096 + e);
    }
    return;
  }
  const float* Mt = Msrc + (size_t)t*4096;
  mm2<0,0,0,LDW, 0,0,0,NN>(W1, Mt,NN, Gsrc + (size_t)s*4096,NN, nullptr,0,
                           Mdst + (size_t)t*4096, Mt,NN, Msrc + (size_t)s*4096,NN, nullptr,0);
  mm<0,1,1,NN>(Gdst + (size_t)t*4096, W1, LDW, Mt, NN, Gsrc + (size_t)t*4096, NN);
}

__global__ __launch_bounds__(256) void k1cF(KP P) {
  __shared__ __align__(16) float W1[LDW*NN];
  const int t = blockIdx.x;
  if (t >= P.meta[0]) return;
  const float* Mt = P.scM0 + (size_t)t*4096;
  mm<0,0,0,LDW>(W1, Mt, NN, P.sPss, NN, nullptr, 0);
  mm<0,1,1,NN>(P.out_cov + (size_t)t*4096, W1, LDW, Mt, NN,
               P.scG0 + (size_t)t*4096, NN);
}

// forward mean scan: local pass -> scanF0[c+1]
__global__ __launch_bounds__(256) void k2a(KP P) {
  __shared__ float xv[64], ty[64], red[256];
  const int c = blockIdx.x;
  const int N0 = P.meta[0];
  const int PB = (N0 + LCH - 1)/LCH;
  if (c < PB) return;
  const int tid = threadIdx.x;
  if (tid < 64) xv[tid] = 0.f;
  __syncthreads();
  for (int s = 0; s < LCH; ++s) {
    int t = c*LCH + s;
    if (tid < 64) ty[tid] = P.Y[(size_t)t*64+tid] - P.c[tid];
    __syncthreads();
    matvec2(xv, P.Fss, xv, P.Kss, ty, P.uss, red);
  }
  if (tid < 64) P.scanF0[(size_t)(c+1)*64 + tid] = xv[tid];
}

// forward mean scan: sequential prefix only; seeds scanF0[PB] = x_PB
__global__ __launch_bounds__(256) void k2b(KP P) {
  __shared__ float xv[64], ty[64], hp[64], red[256];
  const int tid = threadIdx.x;
  const int N0 = P.meta[0];
  const int PB = (N0 + LCH - 1)/LCH;
  const int PE = PB*LCH;
  if (tid < 64) xv[tid] = P.pm0[tid];
  __syncthreads();
  matvec256(hp, P.H, xv, nullptr, red);
  if (tid < 64) ty[tid] = P.Y[tid] - hp[tid] - P.c[tid];
  __syncthreads();
  matvec256(xv, P.Kp, ty, xv, red);
  if (tid < 64) P.fm[tid] = xv[tid];
  __syncthreads();
  for (int t = 1; t < PE; ++t) {
    const float* Kt = (t < N0) ? P.Kp + (size_t)t*4096 : P.Kss;
    const float* Ft = (t < N0) ? P.Fp + (size_t)t*4096 : P.Fss;
    const float* ut = (t < N0) ? P.u_pref + t*64 : P.uss;
    if (tid < 64) ty[tid] = P.Y[(size_t)t*64+tid] - P.c[tid];
    __syncthreads();
    matvec2(xv, Ft, xv, Kt, ty, ut, red);
    if (tid < 64) P.fm[(size_t)t*64+tid] = xv[tid];
    __syncthreads();
  }
  if (tid < 64) P.scanF0[(size_t)PB*64 + tid] = xv[tid];
}

// forward chunk-carry scan level j: s[c] += F^(32*2^j) * s[c-2^j]
__global__ __launch_bounds__(64) void k2s(KP P, int j) {
  const int c = blockIdx.x;
  const int N0 = P.meta[0];
  const int PB = (N0 + LCH - 1)/LCH;
  if (c < PB) return;
  const int sidx = j & 1;
  const float* src = sidx ? P.scanF1 : P.scanF0;
  float* dst = sidx ? P.scanF0 : P.scanF1;
  const int off = 1 << j;
  const int r = threadIdx.x;
  float base = src[(size_t)c*64 + r];
  if (c - off >= PB) {
    __shared__ float xv[64];
    xv[r] = src[(size_t)(c-off)*64 + r];
    __syncthreads();
    const float* M = (j == 0) ? P.Fpow : P.FpwHi + (size_t)(j-1)*4096;
    const float* Mr = M + r*64;
    float s = base;
    for (int k = 0; k < 64; k += 4)
      s += Mr[k]*xv[k] + Mr[k+1]*xv[k+1] + Mr[k+2]*xv[k+2] + Mr[k+3]*xv[k+3];
    dst[(size_t)c*64 + r] = s;
  } else {
    dst[(size_t)c*64 + r] = base;
  }
}

// forward mean scan: replay steady chunks (startstate = scanF1[c])
__global__ __launch_bounds__(256) void k2c(KP P) {
  __shared__ float xv[64], ty[64], red[256];
  const int c = blockIdx.x;
  const int N0 = P.meta[0];
  const int PB = (N0 + LCH - 1)/LCH;
  if (c < PB) return;
  const int tid = threadIdx.x;
  if (tid < 64) xv[tid] = P.scanF1[(size_t)c*64 + tid];
  __syncthreads();
  for (int s = 0; s < LCH; ++s) {
    int t = c*LCH + s;
    if (tid < 64) ty[tid] = P.Y[(size_t)t*64+tid] - P.c[tid];
    __syncthreads();
    matvec2(xv, P.Fss, xv, P.Kss, ty, P.uss, red);
    if (tid < 64) P.fm[(size_t)t*64+tid] = xv[tid];
    __syncthreads();
  }
}

__global__ __launch_bounds__(64) void k5(KP P) {
  __shared__ float pmv[64], rv[64];
  const int t = blockIdx.x;
  const int N0 = P.meta[0];
  const int r = threadIdx.x;
  float pm;
  if (t == 0) {
    pm = P.pm0[r];
  } else {
    pmv[r] = P.fm[(size_t)(t-1)*64 + r];
    __syncthreads();
    float s = P.b[r];
    const float* Ar = P.A + r*64;
    for (int k = 0; k < 64; k += 4)
      s += Ar[k]*pmv[k] + Ar[k+1]*pmv[k+1] + Ar[k+2]*pmv[k+2] + Ar[k+3]*pmv[k+3];
    pm = s;
    __syncthreads();
  }
  pmv[r] = pm; __syncthreads();
  float rr = P.Y[(size_t)t*64 + r] - P.c[r];
  const float* Hr = P.H + r*64;
  for (int k = 0; k < 64; ++k) rr -= Hr[k]*pmv[k];
  rv[r] = rr; __syncthreads();
  const float* Sv = ((t < N0) ? P.Sinvp + (size_t)t*4096 : P.Sinvss) + r*64;
  float wv = 0.f;
  for (int k = 0; k < 64; ++k) wv += Sv[k]*rv[k];
  float qq = rr*wv;
  #pragma unroll
  for (int off = 32; off > 0; off >>= 1) qq += __shfl_xor(qq, off, 64);
  if (r == 0) {
    float ldt = (t < N0) ? P.ld_pref[t] : P.metaF[0];
    P.llbuf[t] = -58.8120661250990555 - (double)ldt - 0.5*(double)qq;
  }
}

// backward mean scan: local pass -> scanB0[c] (block NC-1 seeds with Cpow31*fm[T-1])
__global__ __launch_bounds__(256) void k3a(KP P) {
  __shared__ float sv[64], fmv[64], red[256];
  const int c = blockIdx.x;
  const int N0 = P.meta[0];
  const int PB = (N0 + LCH - 1)/LCH;
  if (c < PB) return;
  const int tid = threadIdx.x;
  if (tid < 64) sv[tid] = 0.f;
  __syncthreads();
  int hi = (c == P.NC-1) ? P.T-2 : c*LCH + LCH - 1;
  for (int t = hi; t >= c*LCH; --t) {
    if (tid < 64) fmv[tid] = P.fm[(size_t)t*64+tid];
    __syncthreads();
    matvec2(sv, P.Css, sv, P.Dmss, fmv, P.dvnss, red);
  }
  if (c == P.NC-1) {
    if (tid < 64) fmv[tid] = P.fm[(size_t)(P.T-1)*64 + tid];
    __syncthreads();
    matvec256(sv, P.Cpow31, fmv, sv, red);     // q = Cpow31*fm[T-1] + ub
  }
  if (tid < 64) P.scanB0[(size_t)c*64 + tid] = sv[tid];
}

// backward chunk-carry suffix-scan level j: S[c] += C^(32*2^j) * S[c+2^j]
__global__ __launch_bounds__(64) void k3s(KP P, int j) {
  const int c = blockIdx.x;
  const int N0 = P.meta[0];
  const int PB = (N0 + LCH - 1)/LCH;
  if (c < PB) return;
  const int sidx = j & 1;
  const float* src = sidx ? P.scanB1 : P.scanB0;
  float* dst = sidx ? P.scanB0 : P.scanB1;
  const int off = 1 << j;
  const int r = threadIdx.x;
  float base = src[(size_t)c*64 + r];
  if (c + off <= P.NC - 1) {
    __shared__ float xv[64];
    xv[r] = src[(size_t)(c+off)*64 + r];
    __syncthreads();
    const float* M;
    if (j == 0) M = P.Cpow32;
    else if (j == 1) M = P.Pw64;
    else if (j == 2) M = P.Pw128;
    else M = P.CpwHi + (size_t)(j-3)*4096;
    const float* Mr = M + r*64;
    float s = base;
    for (int k = 0; k < 64; k += 4)
      s += Mr[k]*xv[k] + Mr[k+1]*xv[k+1] + Mr[k+2]*xv[k+2] + Mr[k+3]*xv[k+3];
    dst[(size_t)c*64 + r] = s;
  } else {
    dst[(size_t)c*64 + r] = base;
  }
}

// backward mean scan: sequential prefix only (seed = scanB1[PB])
__global__ __launch_bounds__(256) void k3b(KP P) {
  __shared__ float sv[64], fmv[64], red[256];
  const int tid = threadIdx.x;
  const int N0 = P.meta[0];
  const int PB = (N0 + LCH - 1)/LCH;
  const int PE = PB*LCH;
  if (tid < 64) {
    P.out_mean[(size_t)(P.T-1)*64+tid] = P.fm[(size_t)(P.T-1)*64+tid];
    sv[tid] = P.scanB1[(size_t)PB*64 + tid];
  }
  __syncthreads();
  for (int t = PE-1; t >= 0; --t) {
    const float* Ct  = (t < N0) ? P.Cp  + (size_t)t*4096 : P.Css;
    const float* Dmt = (t < N0) ? P.Dmp + (size_t)t*4096 : P.Dmss;
    const float* dvt = (t < N0) ? P.dvnp + t*64 : P.dvnss;
    if (tid < 64) fmv[tid] = P.fm[(size_t)t*64+tid];
    __syncthreads();
    matvec2(sv, Ct, sv, Dmt, fmv, dvt, red);
    if (tid < 64) P.out_mean[(size_t)t*64+tid] = sv[tid];
    __syncthreads();
  }
}

// backward mean scan: replay steady chunks (endstate[c] = scanB1[c+1], last = fm[T-1])
__global__ __launch_bounds__(256) void k3c(KP P) {
  __shared__ float sv[64], fmv[64], red[256];
  const int c = blockIdx.x;
  const int N0 = P.meta[0];
  const int PB = (N0 + LCH - 1)/LCH;
  if (c < PB) return;
  const int tid = threadIdx.x;
  if (tid < 64) {
    sv[tid] = (c == P.NC-1) ? P.fm[(size_t)(P.T-1)*64+tid]
                            : P.scanB1[(size_t)(c+1)*64 + tid];
  }
  __syncthreads();
  int hi = (c == P.NC-1) ? P.T-2 : c*LCH + LCH - 1;
  for (int t = hi; t >= c*LCH; --t) {
    if (tid < 64) fmv[tid] = P.fm[(size_t)t*64+tid];
    __syncthreads();
    matvec2(sv, P.Css, sv, P.Dmss, fmv, P.dvnss, red);
    if (tid < 64) P.out_mean[(size_t)t*64+tid] = sv[tid];
    __syncthreads();
  }
}

__global__ __launch_bounds__(256) void k6(KP P) {
  __shared__ double rd[256];
  double s = 0.0;
  for (int t = threadIdx.x; t < P.T; t += 256) s += P.llbuf[t];
  rd[threadIdx.x] = s; __syncthreads();
  #pragma unroll
  for (int off = 128; off > 0; off >>= 1) {
    if ((int)threadIdx.x < off) rd[threadIdx.x] += rd[threadIdx.x + off];
    __syncthreads();
  }
  if (threadIdx.x == 0) P.out_ll[0] = (float)rd[0];
}

// ---------- host ----------

extern "C" void kernel_launch(void* const* d_in, const int* in_sizes, int n_in,
                              void* d_out, int out_size, void* d_ws, size_t ws_size,
                              hipStream_t stream) {
  (void)n_in; (void)out_size;
  KP P;
  P.Y   = (const float*)d_in[0];
  P.A   = (const float*)d_in[1];
  P.b   = (const float*)d_in[2];
  P.Q   = (const float*)d_in[3];
  P.H   = (const float*)d_in[4];
  P.c   = (const float*)d_in[5];
  P.R   = (const float*)d_in[6];
  P.pm0 = (const float*)d_in[7];
  P.P0  = (const float*)d_in[8];
  const int T = in_sizes[0] / 64;
  const int NC = T / LCH;
  P.T = T; P.NC = NC;

  float* out = (float*)d_out;
  P.out_mean = out;
  P.out_cov  = out + (size_t)T*64;
  P.out_ll   = out + (size_t)T*64 + (size_t)T*4096;

  float* w = (float*)d_ws;
  size_t off = 0;
  auto alloc = [&](size_t n) { float* p = w + off; off += n; return p; };
  P.meta   = (int*)alloc(8);
  P.metaF  = alloc(8);
  P.llbuf  = (double*)alloc((size_t)2*T);
  P.fm     = alloc((size_t)T*64);
  P.AT = alloc(4096); P.HT = alloc(4096); P.HA = alloc(4096); P.Hb = alloc(64);
  P.Fss = alloc(4096); P.Kss = alloc(4096); P.Sinvss = alloc(4096);
  P.Css = alloc(4096); P.CsTss = alloc(4096); P.pPss = alloc(4096); P.sPss = alloc(4096);
  P.Fpow = alloc(4096); P.Cpow32 = alloc(4096); P.Cpow31 = alloc(4096); P.uss = alloc(64);
  P.Pw2 = alloc(4096); P.Pw4 = alloc(4096); P.Pw8 = alloc(4096); P.Pw16 = alloc(4096);
  P.Pw64 = alloc(4096); P.Pw128 = alloc(4096);
  P.FpwHi = alloc((size_t)6*4096); P.CpwHi = alloc((size_t)4*4096);
  P.Dmss = alloc(4096); P.dvnss = alloc(64);
  P.u_chunk = alloc((size_t)NC*64); P.startstate = alloc((size_t)NC*64);
  P.ub_chunk = alloc((size_t)NC*64); P.endstate = alloc((size_t)NC*64);
  P.scanF0 = alloc((size_t)(NC+1)*64); P.scanF1 = alloc((size_t)(NC+1)*64);
  P.scanB0 = alloc((size_t)NC*64); P.scanB1 = alloc((size_t)NC*64);
  P.E0g = alloc(4096);
  P.EA = alloc((size_t)8*4096); P.EC = alloc((size_t)8*4096);
  P.EJ = alloc((size_t)8*4096); P.EL = alloc((size_t)8*4096);
  P.astat = alloc(256); P.dstat = alloc(256);
  size_t fixed = off;
  size_t per_t = 12*4096 + 128 + 1;
  size_t total_f = ws_size / 4;
  long long avail = (long long)total_f - (long long)fixed - 4096 - 64;
  int cap = (avail > 0) ? (int)(avail / (long long)per_t) : 8;
  if (cap > N0MAX) cap = N0MAX;
  if (cap < 8) cap = 8;
  P.N0cap = cap;
  P.ld_pref = alloc(cap);
  P.u_pref  = alloc((size_t)cap*64);
  P.dvnp    = alloc((size_t)cap*64);
  P.fP    = alloc((size_t)cap*4096);
  P.pP    = alloc((size_t)(cap+1)*4096);
  P.Kp    = alloc((size_t)cap*4096);
  P.Sinvp = alloc((size_t)cap*4096);
  P.Fp    = alloc((size_t)cap*4096);
  P.Cp    = alloc((size_t)cap*4096);
  P.CsTp  = alloc((size_t)cap*4096);
  P.Dmp   = alloc((size_t)cap*4096);
  P.scM0  = alloc((size_t)cap*4096);
  P.scM1  = alloc((size_t)cap*4096);
  P.scG0  = alloc((size_t)cap*4096);
  P.scG1  = alloc((size_t)cap*4096);

  k0<<<1, 256, 0, stream>>>(P);
  kA<<<1, 256, 0, stream>>>(P);
  kB<<<cap, 256, 0, stream>>>(P);
  kC<<<cap, 256, 0, stream>>>(P);
  kN<<<1, 256, 0, stream>>>(P);
  k1x<<<cap+1, 256, 0, stream>>>(P);    // k1b blocks + k1ss part A (concurrent)
  k1y<<<2, 256, 0, stream>>>(P);        // powers block ∥ Stein block
  k1cI<<<cap, 256, 0, stream>>>(P);
  {
    int sidx = 0;
    for (int d = 0; d < 8; ++d) { k1cL<<<cap, 256, 0, stream>>>(P, 1 << d, sidx); sidx ^= 1; }
  }
  k1cF<<<cap, 256, 0, stream>>>(P);
  kTail<<<T, 256, 0, stream>>>(P);      // merged k1d + k4
  k2a<<<NC, 256, 0, stream>>>(P);
  k2b<<<1, 256, 0, stream>>>(P);
  for (int j = 0; j < 7; ++j) k2s<<<NC, 64, 0, stream>>>(P, j);
  k2c<<<NC, 256, 0, stream>>>(P);
  k5<<<T, 64, 0, stream>>>(P);
  k3a<<<NC, 256, 0, stream>>>(P);
  for (int j = 0; j < 7; ++j) k3s<<<NC, 64, 0, stream>>>(P, j);
  k3b<<<1, 256, 0, stream>>>(P);
  k3c<<<NC, 256, 0, stream>>>(P);
  k6<<<1, 256, 0, stream>>>(P);
}

// Round 8
// 1504.673 us; speedup vs baseline: 2.6161x; 1.1923x over previous
//
#include <hip/hip_runtime.h>
#include <math.h>

#define NN 64
#define LDW 68      // padded LDS stride (float4-aligned)
#define LCH 32      // mean-scan chunk length
#define N1CAP 144   // smoother-cov tail length (closed-form, parallel)
#define N0MAX 144   // forward Riccati cap
#define EPS_HARD 1e-5f
#define EPS_GATE 5e-2f
#define STALL_WIN 5
#define STALL_IMP 0.75f

struct KP {
  const float *Y, *A, *b, *Q, *H, *c, *R, *pm0, *P0;
  float *out_mean, *out_cov, *out_ll;
  int *meta; float *metaF;
  float *fm;
  float *AT, *HT, *HA, *Hb;
  float *Fss, *Kss, *Sinvss, *Css, *CsTss, *pPss, *sPss, *Fpow, *Cpow32, *Cpow31, *uss;
  float *Pw2, *Pw4, *Pw8, *Pw16, *Pw64, *Pw128;
  float *FpwHi, *CpwHi;                   // F^(64..2048) [6], C^(256..2048) [4]
  float *Dmss, *dvnss;                    // I - Css*A ; -Css*b (fused backward scan)
  float *scanF0, *scanF1, *scanB0, *scanB1;           // chunk-carry scan buffers
  float *ld_pref, *u_pref;
  double *llbuf;
  float *E0g;
  float *EA, *EC, *EJ, *EL;
  float *astat, *dstat;
  float *scM0, *scM1, *scG0, *scG1;
  float *fP, *pP, *Kp, *Sinvp, *Fp, *Cp, *CsTp, *Dmp, *dvnp;
  int N0cap, T, NC;
};

union F4 { float4 v; float f[4]; };

// ---------- helpers (blockDim.x == 256 unless noted) ----------

__device__ __forceinline__ void g2l(float* W, const float* G) {
  for (int e = threadIdx.x*4; e < 4096; e += 1024) {
    float4 v = *(const float4*)(G + e);
    *(float4*)(W + (e>>6)*LDW + (e&63)) = v;
  }
  __syncthreads();
}
__device__ __forceinline__ void l2g(float* G, const float* W) {
  for (int e = threadIdx.x*4; e < 4096; e += 1024)
    *(float4*)(G + e) = *(const float4*)(W + (e>>6)*LDW + (e&63));
  __syncthreads();
}
__device__ __forceinline__ void l2g2(float* G1, const float* Wa,
                                     float* G2, const float* Wb) {
  for (int e = threadIdx.x*4; e < 4096; e += 1024) {
    int base = (e>>6)*LDW + (e&63);
    *(float4*)(G1 + e) = *(const float4*)(Wa + base);
    *(float4*)(G2 + e) = *(const float4*)(Wb + base);
  }
  __syncthreads();
}
__device__ __forceinline__ void l2g3(float* G1, const float* Wa,
                                     float* G2, const float* Wb,
                                     float* G3, const float* Wc) {
  for (int e = threadIdx.x*4; e < 4096; e += 1024) {
    int base = (e>>6)*LDW + (e&63);
    *(float4*)(G1 + e) = *(const float4*)(Wa + base);
    *(float4*)(G2 + e) = *(const float4*)(Wb + base);
    *(float4*)(G3 + e) = *(const float4*)(Wc + base);
  }
  __syncthreads();
}
__device__ __forceinline__ void l2g_T(float* G, const float* W) {
  for (int e = threadIdx.x; e < 4096; e += 256)
    G[e] = W[(e&63)*LDW + (e>>6)];
  __syncthreads();
}
__device__ __forceinline__ void copyW(float* D, const float* S) {
  for (int e = threadIdx.x*4; e < 4096; e += 1024) {
    int base = (e>>6)*LDW + (e&63);
    *(float4*)(D + base) = *(const float4*)(S + base);
  }
  __syncthreads();
}
__device__ __forceinline__ void set_id(float* W) {
  for (int e = threadIdx.x; e < 4096; e += 256)
    W[(e>>6)*LDW + (e&63)] = ((e>>6) == (e&63)) ? 1.f : 0.f;
  __syncthreads();
}
// G = I - W (LDS -> global)
__device__ __forceinline__ void store_id_sub(float* G, const float* W) {
  for (int e = threadIdx.x; e < 4096; e += 256)
    G[e] = (((e>>6) == (e&63)) ? 1.f : 0.f) - W[(e>>6)*LDW + (e&63)];
  __syncthreads();
}
// G_dst = G_src - W
__device__ __forceinline__ void rsub_store(float* Gd, const float* Gs, const float* W) {
  for (int e = threadIdx.x*4; e < 4096; e += 1024) {
    int base = (e>>6)*LDW + (e&63);
    F4 a, g; a.v = *(const float4*)(W + base); g.v = *(const float4*)(Gs + e);
    F4 o; o.f[0]=g.f[0]-a.f[0]; o.f[1]=g.f[1]-a.f[1]; o.f[2]=g.f[2]-a.f[2]; o.f[3]=g.f[3]-a.f[3];
    *(float4*)(Gd + e) = o.v;
  }
  __syncthreads();
}

__device__ __forceinline__ void redpair(float& ma, float& md, float* red) {
  #pragma unroll
  for (int off = 32; off; off >>= 1) {
    ma = fmaxf(ma, __shfl_xor(ma, off, 64));
    md = fmaxf(md, __shfl_xor(md, off, 64));
  }
  const int w = threadIdx.x >> 6;
  if ((threadIdx.x & 63) == 0) { red[w] = ma; red[4 + w] = md; }
  __syncthreads();
  ma = fmaxf(fmaxf(red[0], red[1]), fmaxf(red[2], red[3]));
  md = fmaxf(fmaxf(red[4], red[5]), fmaxf(red[6], red[7]));
  __syncthreads();
}

// D(stride LDD) = [ADD +/-] op(A)*op(B)
template<int TRANSA, int TRANSB, int MODE, int LDD>
__device__ __forceinline__ void mm(float* __restrict__ D,
    const float* __restrict__ A, int lda,
    const float* __restrict__ B, int ldb,
    const float* __restrict__ ADD, int ldadd)
{
  const int tid = threadIdx.x;
  const int i0 = (tid >> 4) << 2, j0 = (tid & 15) << 2;
  float acc[4][4] = {};
  for (int k0 = 0; k0 < NN; k0 += 4) {
    F4 av[4], bv[4];
    #pragma unroll
    for (int u = 0; u < 4; ++u) {
      bv[u].v = TRANSB ? *(const float4*)(B + (j0+u)*ldb + k0)
                       : *(const float4*)(B + (k0+u)*ldb + j0);
      av[u].v = TRANSA ? *(const float4*)(A + (k0+u)*lda + i0)
                       : *(const float4*)(A + (i0+u)*lda + k0);
    }
    #pragma unroll
    for (int kk = 0; kk < 4; ++kk) {
      #pragma unroll
      for (int di = 0; di < 4; ++di) {
        float a = TRANSA ? av[kk].f[di] : av[di].f[kk];
        #pragma unroll
        for (int dj = 0; dj < 4; ++dj) {
          float bb = TRANSB ? bv[dj].f[kk] : bv[kk].f[dj];
          acc[di][dj] += a * bb;
        }
      }
    }
  }
  #pragma unroll
  for (int di = 0; di < 4; ++di) {
    if (MODE == 0 && (LDD & 3) == 0) {
      F4 o;
      #pragma unroll
      for (int dj = 0; dj < 4; ++dj) o.f[dj] = acc[di][dj];
      *(float4*)(D + (i0+di)*LDD + j0) = o.v;
    } else {
      #pragma unroll
      for (int dj = 0; dj < 4; ++dj) {
        float v = acc[di][dj];
        if (MODE == 1) v = ADD[(i0+di)*ldadd + j0+dj] + v;
        if (MODE == 2) v = ADD[(i0+di)*ldadd + j0+dj] - v;
        D[(i0+di)*LDD + j0+dj] = v;
      }
    }
  }
  __syncthreads();
}

// two INDEPENDENT matmuls in one barrier region
template<int TA1,int TB1,int MO1,int LD1, int TA2,int TB2,int MO2,int LD2>
__device__ __forceinline__ void mm2(
    float* __restrict__ D1, const float* __restrict__ A1, int lda1,
    const float* __restrict__ B1, int ldb1, const float* __restrict__ AD1, int ldad1,
    float* __restrict__ D2, const float* __restrict__ A2, int lda2,
    const float* __restrict__ B2, int ldb2, const float* __restrict__ AD2, int ldad2)
{
  const int tid = threadIdx.x;
  const int i0 = (tid >> 4) << 2, j0 = (tid & 15) << 2;
  float acc1[4][4] = {}, acc2[4][4] = {};
  for (int k0 = 0; k0 < NN; k0 += 4) {
    F4 av1[4], bv1[4], av2[4], bv2[4];
    #pragma unroll
    for (int u = 0; u < 4; ++u) {
      bv1[u].v = TB1 ? *(const float4*)(B1 + (j0+u)*ldb1 + k0)
                     : *(const float4*)(B1 + (k0+u)*ldb1 + j0);
      av1[u].v = TA1 ? *(const float4*)(A1 + (k0+u)*lda1 + i0)
                     : *(const float4*)(A1 + (i0+u)*lda1 + k0);
      bv2[u].v = TB2 ? *(const float4*)(B2 + (j0+u)*ldb2 + k0)
                     : *(const float4*)(B2 + (k0+u)*ldb2 + j0);
      av2[u].v = TA2 ? *(const float4*)(A2 + (k0+u)*lda2 + i0)
                     : *(const float4*)(A2 + (i0+u)*lda2 + k0);
    }
    #pragma unroll
    for (int kk = 0; kk < 4; ++kk) {
      #pragma unroll
      for (int di = 0; di < 4; ++di) {
        float a1 = TA1 ? av1[kk].f[di] : av1[di].f[kk];
        float a2 = TA2 ? av2[kk].f[di] : av2[di].f[kk];
        #pragma unroll
        for (int dj = 0; dj < 4; ++dj) {
          acc1[di][dj] += a1 * (TB1 ? bv1[dj].f[kk] : bv1[kk].f[dj]);
          acc2[di][dj] += a2 * (TB2 ? bv2[dj].f[kk] : bv2[kk].f[dj]);
        }
      }
    }
  }
  #pragma unroll
  for (int di = 0; di < 4; ++di) {
    if (MO1 == 0 && (LD1 & 3) == 0) {
      F4 o;
      #pragma unroll
      for (int dj = 0; dj < 4; ++dj) o.f[dj] = acc1[di][dj];
      *(float4*)(D1 + (i0+di)*LD1 + j0) = o.v;
    } else {
      #pragma unroll
      for (int dj = 0; dj < 4; ++dj) {
        float v = acc1[di][dj];
        if (MO1 == 1) v = AD1[(i0+di)*ldad1 + j0+dj] + v;
        if (MO1 == 2) v = AD1[(i0+di)*ldad1 + j0+dj] - v;
        D1[(i0+di)*LD1 + j0+dj] = v;
      }
    }
  }
  #pragma unroll
  for (int di = 0; di < 4; ++di) {
    if (MO2 == 0 && (LD2 & 3) == 0) {
      F4 o;
      #pragma unroll
      for (int dj = 0; dj < 4; ++dj) o.f[dj] = acc2[di][dj];
      *(float4*)(D2 + (i0+di)*LD2 + j0) = o.v;
    } else {
      #pragma unroll
      for (int dj = 0; dj < 4; ++dj) {
        float v = acc2[di][dj];
        if (MO2 == 1) v = AD2[(i0+di)*ldad2 + j0+dj] + v;
        if (MO2 == 2) v = AD2[(i0+di)*ldad2 + j0+dj] - v;
        D2[(i0+di)*LD2 + j0+dj] = v;
      }
    }
  }
  __syncthreads();
}

// panel-16 Cholesky in stride-LDW buffer (256 threads). upper zeroed.
template<bool WANTLOG>
__device__ __forceinline__ void chol68(float* __restrict__ Sm, float* part, float* invd) {
  const int tid = threadIdx.x;
  const int lane = tid & 63;
  #pragma unroll
  for (int p = 0; p < 4; ++p) {
    const int j0 = p * 16;
    if (p > 0) {
      const int i = tid & 63;
      const int jq = (tid >> 6) * 4;
      float acc[4] = {0.f, 0.f, 0.f, 0.f};
      for (int kb = 0; kb < j0; kb += 4) {
        F4 av; av.v = *(const float4*)(Sm + i*LDW + kb);
        #pragma unroll
        for (int q = 0; q < 4; ++q) {
          F4 bv; bv.v = *(const float4*)(Sm + (j0 + jq + q)*LDW + kb);
          acc[q] += av.f[0]*bv.f[0] + av.f[1]*bv.f[1] + av.f[2]*bv.f[2] + av.f[3]*bv.f[3];
        }
      }
      #pragma unroll
      for (int q = 0; q < 4; ++q)
        Sm[i*LDW + j0 + jq + q] -= acc[q];
      __syncthreads();
    }
    if (tid < 64) {
      float t[16];
      F4 tv;
      #pragma unroll
      for (int q4 = 0; q4 < 4; ++q4) {
        tv.v = *(const float4*)(Sm + lane*LDW + j0 + 4*q4);
        t[4*q4] = tv.f[0]; t[4*q4+1] = tv.f[1]; t[4*q4+2] = tv.f[2]; t[4*q4+3] = tv.f[3];
      }
      #pragma unroll
      for (int jj = 0; jj < 16; ++jj) {
        float acc = t[jj];
        #pragma unroll
        for (int kk = 0; kk < jj; ++kk)
          acc -= __shfl(t[kk], j0 + jj, 64) * t[kk];
        float piv = __shfl(acc, j0 + jj, 64);
        float sq = sqrtf(fmaxf(piv, 1e-30f));
        float inv = 1.0f / sq;
        if (lane == j0 + jj) {
          t[jj] = sq;
          invd[j0 + jj] = inv;
          if (WANTLOG) part[j0 + jj] = logf(sq);
        } else {
          t[jj] = (lane > j0 + jj) ? acc * inv : 0.f;
        }
      }
      #pragma unroll
      for (int q4 = 0; q4 < 4; ++q4) {
        tv.f[0] = t[4*q4]; tv.f[1] = t[4*q4+1]; tv.f[2] = t[4*q4+2]; tv.f[3] = t[4*q4+3];
        *(float4*)(Sm + lane*LDW + j0 + 4*q4) = tv.v;
      }
    }
    __syncthreads();
  }
}

// forward triangular solve DST <- L^-1 op(SRC); TR=1 reads SRC transposed.
template<int TR>
__device__ __forceinline__ void tri_fwd_ld(const float* __restrict__ L,
                                           const float* __restrict__ invd,
                                           const float* __restrict__ SRC, int lds,
                                           float* __restrict__ DST, int ldd) {
  const int col = threadIdx.x >> 2, p = threadIdx.x & 3;
  const int gbase = (threadIdx.x & 63) & ~3;
  float xr[16];
  #pragma unroll
  for (int u = 0; u < 16; ++u)
    xr[u] = TR ? SRC[col*lds + (4*u+p)] : SRC[(4*u+p)*lds + col];
  #pragma unroll
  for (int i = 0; i < NN; ++i) {
    const int idx = i >> 2, ow = i & 3;
    float yi = xr[idx] * invd[i];
    yi = __shfl(yi, gbase + ow, 64);
    if (p == ow) xr[idx] = yi;
    else if (p > ow) xr[idx] -= L[(4*idx+p)*LDW + i] * yi;
    #pragma unroll
    for (int u = idx+1; u < 16; ++u)
      xr[u] -= L[(4*u+p)*LDW + i] * yi;
  }
  #pragma unroll
  for (int u = 0; u < 16; ++u) DST[(4*u+p)*ldd + col] = xr[u];
  __syncthreads();
}

// TWO independent forward solves in one barrier region
template<int TR1,int TR2>
__device__ __forceinline__ void tri_fwd2(
    const float* __restrict__ L1, const float* __restrict__ ivd1,
    const float* __restrict__ S1, int lds1, float* __restrict__ D1, int ldd1,
    const float* __restrict__ L2, const float* __restrict__ ivd2,
    const float* __restrict__ S2, int lds2, float* __restrict__ D2, int ldd2)
{
  const int col = threadIdx.x >> 2, p = threadIdx.x & 3;
  const int gbase = (threadIdx.x & 63) & ~3;
  float xr[16], xs[16];
  #pragma unroll
  for (int u = 0; u < 16; ++u) {
    xr[u] = TR1 ? S1[col*lds1 + (4*u+p)] : S1[(4*u+p)*lds1 + col];
    xs[u] = TR2 ? S2[col*lds2 + (4*u+p)] : S2[(4*u+p)*lds2 + col];
  }
  #pragma unroll
  for (int i = 0; i < NN; ++i) {
    const int idx = i >> 2, ow = i & 3;
    float yi = xr[idx] * ivd1[i];
    yi = __shfl(yi, gbase + ow, 64);
    float zi = xs[idx] * ivd2[i];
    zi = __shfl(zi, gbase + ow, 64);
    if (p == ow) xr[idx] = yi;
    else if (p > ow) xr[idx] -= L1[(4*idx+p)*LDW + i] * yi;
    if (p == ow) xs[idx] = zi;
    else if (p > ow) xs[idx] -= L2[(4*idx+p)*LDW + i] * zi;
    #pragma unroll
    for (int u = idx+1; u < 16; ++u) {
      xr[u] -= L1[(4*u+p)*LDW + i] * yi;
      xs[u] -= L2[(4*u+p)*LDW + i] * zi;
    }
  }
  #pragma unroll
  for (int u = 0; u < 16; ++u) {
    D1[(4*u+p)*ldd1 + col] = xr[u];
    D2[(4*u+p)*ldd2 + col] = xs[u];
  }
  __syncthreads();
}

// backward triangular solve DST <- L^-T SRC
__device__ __forceinline__ void tri_bwd_ld(const float* __restrict__ L,
                                           const float* __restrict__ invd,
                                           const float* __restrict__ SRC, int lds,
                                           float* __restrict__ DST, int ldd) {
  const int col = threadIdx.x >> 2, p = threadIdx.x & 3;
  const int gbase = (threadIdx.x & 63) & ~3;
  float xr[16];
  #pragma unroll
  for (int u = 0; u < 16; ++u) xr[u] = SRC[(4*u+p)*lds + col];
  #pragma unroll
  for (int i = NN-1; i >= 0; --i) {
    const int idx = i >> 2, ow = i & 3;
    float zi = xr[idx] * invd[i];
    zi = __shfl(zi, gbase + ow, 64);
    if (p == ow) xr[idx] = zi;
    else if (p < ow) xr[idx] -= L[i*LDW + 4*idx+p] * zi;
    #pragma unroll
    for (int u = 0; u < idx; ++u)
      xr[u] -= L[i*LDW + 4*u+p] * zi;
  }
  #pragma unroll
  for (int u = 0; u < 16; ++u) DST[(4*u+p)*ldd + col] = xr[u];
  __syncthreads();
}

// one forward + one backward solve (same L), interleaved
__device__ __forceinline__ void tri_fb2(
    const float* __restrict__ L, const float* __restrict__ ivd,
    const float* __restrict__ Sf, int ldsf, float* __restrict__ Df, int lddf,
    const float* __restrict__ Sb, int ldsb, float* __restrict__ Db, int lddb)
{
  const int col = threadIdx.x >> 2, p = threadIdx.x & 3;
  const int gbase = (threadIdx.x & 63) & ~3;
  float xf[16], xb[16];
  #pragma unroll
  for (int u = 0; u < 16; ++u) {
    xf[u] = Sf[(4*u+p)*ldsf + col];
    xb[u] = Sb[(4*u+p)*ldsb + col];
  }
  #pragma unroll
  for (int k = 0; k < NN; ++k) {
    {
      const int i = k, idx = i >> 2, ow = i & 3;
      float yi = xf[idx] * ivd[i];
      yi = __shfl(yi, gbase + ow, 64);
      if (p == ow) xf[idx] = yi;
      else if (p > ow) xf[idx] -= L[(4*idx+p)*LDW + i] * yi;
      #pragma unroll
      for (int u = idx+1; u < 16; ++u)
        xf[u] -= L[(4*u+p)*LDW + i] * yi;
    }
    {
      const int i = NN-1-k, idx = i >> 2, ow = i & 3;
      float zi = xb[idx] * ivd[i];
      zi = __shfl(zi, gbase + ow, 64);
      if (p == ow) xb[idx] = zi;
      else if (p < ow) xb[idx] -= L[i*LDW + 4*idx+p] * zi;
      #pragma unroll
      for (int u = 0; u < idx; ++u)
        xb[u] -= L[i*LDW + 4*u+p] * zi;
    }
  }
  #pragma unroll
  for (int u = 0; u < 16; ++u) {
    Df[(4*u+p)*lddf + col] = xf[u];
    Db[(4*u+p)*lddb + col] = xb[u];
  }
  __syncthreads();
}

// two-sided triangular solve: DST <- L^-T L^-1 SRC
__device__ __forceinline__ void tri_solve2(const float* __restrict__ L,
                                           const float* __restrict__ invd,
                                           const float* __restrict__ SRC,
                                           float* __restrict__ DST) {
  const int col = threadIdx.x >> 2, p = threadIdx.x & 3;
  const int gbase = (threadIdx.x & 63) & ~3;
  float xr[16];
  #pragma unroll
  for (int u = 0; u < 16; ++u) xr[u] = SRC[(4*u+p)*LDW + col];
  #pragma unroll
  for (int i = 0; i < NN; ++i) {
    const int idx = i >> 2, ow = i & 3;
    float yi = xr[idx] * invd[i];
    yi = __shfl(yi, gbase + ow, 64);
    if (p == ow) xr[idx] = yi;
    else if (p > ow) xr[idx] -= L[(4*idx+p)*LDW + i] * yi;
    #pragma unroll
    for (int u = idx+1; u < 16; ++u)
      xr[u] -= L[(4*u+p)*LDW + i] * yi;
  }
  #pragma unroll
  for (int i = NN-1; i >= 0; --i) {
    const int idx = i >> 2, ow = i & 3;
    float zi = xr[idx] * invd[i];
    zi = __shfl(zi, gbase + ow, 64);
    if (p == ow) xr[idx] = zi;
    else if (p < ow) xr[idx] -= L[i*LDW + 4*idx+p] * zi;
    #pragma unroll
    for (int u = 0; u < idx; ++u)
      xr[u] -= L[i*LDW + 4*u+p] * zi;
  }
  #pragma unroll
  for (int u = 0; u < 16; ++u) DST[(4*u+p)*LDW + col] = xr[u];
  __syncthreads();
}

// TWO independent two-sided solves (same L), in-place, stride LDW
__device__ __forceinline__ void tri_s2x2(const float* __restrict__ L,
                                         const float* __restrict__ invd,
                                         float* __restrict__ X1,
                                         float* __restrict__ X2) {
  const int col = threadIdx.x >> 2, p = threadIdx.x & 3;
  const int gbase = (threadIdx.x & 63) & ~3;
  float xr[16], xs[16];
  #pragma unroll
  for (int u = 0; u < 16; ++u) {
    xr[u] = X1[(4*u+p)*LDW + col];
    xs[u] = X2[(4*u+p)*LDW + col];
  }
  #pragma unroll
  for (int i = 0; i < NN; ++i) {
    const int idx = i >> 2, ow = i & 3;
    float yi = xr[idx] * invd[i];
    yi = __shfl(yi, gbase + ow, 64);
    float zi = xs[idx] * invd[i];
    zi = __shfl(zi, gbase + ow, 64);
    if (p == ow) xr[idx] = yi;
    else if (p > ow) xr[idx] -= L[(4*idx+p)*LDW + i] * yi;
    if (p == ow) xs[idx] = zi;
    else if (p > ow) xs[idx] -= L[(4*idx+p)*LDW + i] * zi;
    #pragma unroll
    for (int u = idx+1; u < 16; ++u) {
      xr[u] -= L[(4*u+p)*LDW + i] * yi;
      xs[u] -= L[(4*u+p)*LDW + i] * zi;
    }
  }
  #pragma unroll
  for (int i = NN-1; i >= 0; --i) {
    const int idx = i >> 2, ow = i & 3;
    float yi = xr[idx] * invd[i];
    yi = __shfl(yi, gbase + ow, 64);
    float zi = xs[idx] * invd[i];
    zi = __shfl(zi, gbase + ow, 64);
    if (p == ow) xr[idx] = yi;
    else if (p < ow) xr[idx] -= L[i*LDW + 4*idx+p] * yi;
    if (p == ow) xs[idx] = zi;
    else if (p < ow) xs[idx] -= L[i*LDW + 4*idx+p] * zi;
    #pragma unroll
    for (int u = 0; u < idx; ++u) {
      xr[u] -= L[i*LDW + 4*u+p] * yi;
      xs[u] -= L[i*LDW + 4*u+p] * zi;
    }
  }
  #pragma unroll
  for (int u = 0; u < 16; ++u) {
    X1[(4*u+p)*LDW + col] = xr[u];
    X2[(4*u+p)*LDW + col] = xs[u];
  }
  __syncthreads();
}

// y(64) = M1*x1 + M2*x2 + addv. 256 threads. y may alias x1/x2/addv.
__device__ __forceinline__ void matvec2(float* __restrict__ y,
    const float* __restrict__ M1, const float* __restrict__ x1,
    const float* __restrict__ M2, const float* __restrict__ x2,
    const float* __restrict__ addv, float* __restrict__ red) {
  const int r = threadIdx.x & 63, p = threadIdx.x >> 6;
  const int kb = p*16;
  float s = 0.f;
  #pragma unroll
  for (int q = 0; q < 4; ++q) {
    F4 mv; mv.v = *(const float4*)(M1 + r*NN + kb + q*4);
    s += mv.f[0]*x1[kb+q*4] + mv.f[1]*x1[kb+q*4+1] + mv.f[2]*x1[kb+q*4+2] + mv.f[3]*x1[kb+q*4+3];
    F4 nv; nv.v = *(const float4*)(M2 + r*NN + kb + q*4);
    s += nv.f[0]*x2[kb+q*4] + nv.f[1]*x2[kb+q*4+1] + nv.f[2]*x2[kb+q*4+2] + nv.f[3]*x2[kb+q*4+3];
  }
  red[p*64 + r] = s;
  __syncthreads();
  if (threadIdx.x < 64) {
    float t = red[r] + red[64+r] + red[128+r] + red[192+r];
    y[r] = t + addv[r];
  }
  __syncthreads();
}

// y = Mg*x + addv (nullable). 256 threads.
__device__ __forceinline__ void matvec256(float* __restrict__ y, const float* __restrict__ Mg,
    const float* __restrict__ x, const float* __restrict__ addv, float* __restrict__ red) {
  const int r = threadIdx.x & 63, p = threadIdx.x >> 6;
  const int kb = p*16;
  float s = 0.f;
  #pragma unroll
  for (int q = 0; q < 4; ++q) {
    F4 mv; mv.v = *(const float4*)(Mg + r*NN + kb + q*4);
    s += mv.f[0]*x[kb+q*4] + mv.f[1]*x[kb+q*4+1] + mv.f[2]*x[kb+q*4+2] + mv.f[3]*x[kb+q*4+3];
  }
  red[p*64 + r] = s;
  __syncthreads();
  if (threadIdx.x < 64) {
    float t = red[r] + red[64+r] + red[128+r] + red[192+r];
    y[r] = t + (addv ? addv[r] : 0.f);
  }
  __syncthreads();
}

// ---------- kernels ----------

__global__ __launch_bounds__(256) void k0(KP P) {
  __shared__ __align__(16) float W0[LDW*NN];
  const int tid = threadIdx.x;
  for (int e = tid; e < 4096; e += 256) {
    int r = e>>6, cc = e&63;
    P.AT[e] = P.A[cc*64+r];
    P.HT[e] = P.H[cc*64+r];
  }
  if (tid < 64) {
    float s = 0.f;
    for (int k = 0; k < 64; ++k) s += P.H[tid*64+k]*P.b[k];
    P.Hb[tid] = s;
  }
  __syncthreads();
  mm<0,0,0,LDW>(W0, P.H, NN, P.A, NN, nullptr, 0);   // HA = H*A
  l2g(P.HA, W0);
}

// kA: leaf + fP0 + 5 doublings (E^2..E^32; kB decomposes t = 32q + bits)
__global__ __launch_bounds__(256) void kA(KP P) {
  __shared__ __align__(16) float LA[LDW*NN], LC[LDW*NN], LJ[LDW*NN], LL[LDW*NN];
  __shared__ __align__(16) float W0[LDW*NN], W1[LDW*NN], W2[LDW*NN], W3[LDW*NN], W4[LDW*NN];
  __shared__ float part[64], iv1[64], iv2[64];
  const int tid = threadIdx.x;
  mm2<0,0,0,LDW, 0,0,0,LDW>(W0, P.H,NN, P.Q,NN, nullptr,0,
                            W2, P.H,NN, P.P0,NN, nullptr,0);      // T = H Q ; HP0
  mm2<0,1,1,LDW, 0,1,1,LDW>(W1, W0,LDW, P.H,NN, P.R,NN,
                            W3, W2,LDW, P.H,NN, P.R,NN);          // St ; S0
  chol68<false>(W1, part, iv1);
  chol68<false>(W3, part, iv2);
  tri_fwd2<0,0>(W1, iv1, P.HA,NN, W4,LDW,
                W3, iv2, W2,LDW,  W2,LDW);                         // U ; U0
  mm2<1,0,0,LDW, 1,0,2,LDW>(LJ, W4,LDW, W4,LDW, nullptr,0,
                            W3, W2,LDW, W2,LDW, P.P0,NN);          // Jt ; fP0
  l2g(P.fP, W3);
  copyW(LL, LJ);
  chol68<false>(LL, part, iv2);                                    // Lt
  tri_fb2(W1, iv1, W0,LDW, W3,LDW,  W4,LDW, W4,LDW);               // V ; X
  mm2<1,0,2,LDW, 1,0,2,LDW>(LA, W0,LDW, W4,LDW, P.A,NN,
                            LC, W3,LDW, W3,LDW, P.Q,NN);           // At ; Ct
  l2g3(P.EA, LA, P.EC, LC, P.EL, LL);
  for (int j = 0; j < 5 && (2 << j) <= P.N0cap - 1; ++j) {
    mm2<0,0,0,LDW, 1,0,0,LDW>(W0, LC,LDW, LL,LDW, nullptr,0,
                              W2, LL,LDW, LA,LDW, nullptr,0);      // Pm ; T1
    mm<1,0,0,LDW>(W1, LL,LDW, W0,LDW, nullptr,0);                  // W
    if (tid < 64) W1[tid*LDW + tid] += 1.f;
    __syncthreads();
    chol68<false>(W1, part, iv1);                                   // Lw
    tri_fwd2<0,1>(W1, iv1, W2,LDW, W2,LDW,
                  W1, iv1, W0,LDW, W3,LDW);                         // T2f ; T5
    mm2<1,0,1,LDW, 1,0,2,LDW>(LJ, W2,LDW, W2,LDW, LJ,LDW,
                              W4, W3,LDW, W3,LDW, LC,LDW);          // Jn ; ZC
    copyW(LL, LJ);
    chol68<false>(LL, part, iv2);                                   // Ln
    tri_bwd_ld(W1, iv1, W2,LDW, W2,LDW);                            // T2
    mm<0,0,2,LDW>(W3, W0,LDW, W2,LDW, LA,LDW);                      // ZA
    mm2<0,0,0,LDW, 0,0,0,LDW>(W2, LA,LDW, W3,LDW, nullptr,0,
                              W0, LA,LDW, W4,LDW, nullptr,0);       // An ; T7
    mm<0,1,1,LDW>(LC, W0,LDW, LA,LDW, LC,LDW);                      // Cn
    copyW(LA, W2);
    l2g3(P.EA+(size_t)(j+1)*4096, LA, P.EC+(size_t)(j+1)*4096, LC,
         P.EL+(size_t)(j+1)*4096, LL);
  }
}

// block t: fP_t via greedy decomposition; also pP_{t+1}
__global__ __launch_bounds__(256) void kB(KP P) {
  __shared__ __align__(16) float Wc[LDW*NN], W0[LDW*NN], W1[LDW*NN], W2[LDW*NN];
  __shared__ float part[64], ivw[64];
  const int t = blockIdx.x;
  if (t == 0) {
    for (int e = threadIdx.x*4; e < 4096; e += 1024)
      *(float4*)(P.pP + e) = *(const float4*)(P.P0 + e);
    __syncthreads();
    mm<0,0,0,LDW>(W1, P.A, NN, P.fP, NN, nullptr, 0);
    mm<0,0,1,LDW>(W0, W1, LDW, P.AT, NN, P.Q, NN);
    l2g(P.pP + 4096, W0);
    return;
  }
  g2l(Wc, P.fP);
  int rem = t;
  for (int j = 5; j >= 0; --j) {
    const int pw = 1 << j;
    if (j > 0 && pw > P.N0cap - 1) continue;
    while (rem >= pw) {
      const float* Ag = P.EA + j*4096;
      const float* Cg = P.EC + j*4096;
      const float* Lg = P.EL + j*4096;
      mm<0,0,0,LDW>(W0, Wc, LDW, Lg, NN, nullptr, 0);     // Pm = C L
      mm<1,0,0,LDW>(W1, Lg, NN, W0, LDW, nullptr, 0);     // W = L^T Pm
      if (threadIdx.x < 64) W1[threadIdx.x*LDW + threadIdx.x] += 1.f;
      __syncthreads();
      chol68<false>(W1, part, ivw);
      tri_fwd_ld<1>(W1, ivw, W0, LDW, W2, LDW);           // T5
      mm<1,0,2,LDW>(W1, W2, LDW, W2, LDW, Wc, LDW);       // ZC
      mm<0,0,0,LDW>(W0, Ag, NN, W1, LDW, nullptr, 0);     // T7
      mm<0,1,1,LDW>(Wc, W0, LDW, Ag, NN, Cg, NN);         // C'
      rem -= pw;
    }
  }
  l2g(P.fP + (size_t)t*4096, Wc);
  mm<0,0,0,LDW>(W0, P.A, NN, Wc, LDW, nullptr, 0);
  mm<0,0,1,LDW>(W1, W0, LDW, P.AT, NN, P.Q, NN);
  l2g(P.pP + (size_t)(t+1)*4096, W1);
}

__global__ __launch_bounds__(256) void kC(KP P) {
  __shared__ float red[16];
  const int t = blockIdx.x;
  const float* cur = P.fP + (size_t)t*4096;
  const float* prv = P.fP + (size_t)(t > 0 ? t-1 : 0)*4096;
  float a = 0.f, d = 0.f;
  for (int e = threadIdx.x*4; e < 4096; e += 1024) {
    F4 v, pv; v.v = *(const float4*)(cur + e); pv.v = *(const float4*)(prv + e);
    #pragma unroll
    for (int q = 0; q < 4; ++q) {
      a = fmaxf(a, fabsf(v.f[q]));
      d = fmaxf(d, fabsf(v.f[q] - pv.f[q]));
    }
  }
  redpair(a, d, red);
  if (threadIdx.x == 0) { P.astat[t] = a; P.dstat[t] = (t > 0) ? d : 0.f; }
}

__global__ __launch_bounds__(256) void kN(KP P) {
  __shared__ float as_[N0MAX], ds_[N0MAX];
  const int cap = P.N0cap;
  for (int i = threadIdx.x; i < cap; i += 256) { as_[i] = P.astat[i]; ds_[i] = P.dstat[i]; }
  __syncthreads();
  if (threadIdx.x == 0) {
    float mabs = 1e-20f, dref = 1e30f;
    int tref = 0, N0 = cap;
    bool conv = false;
    for (int t = 0; t < cap; ++t) {
      mabs = fmaxf(mabs, as_[t]);
      if (t > 0) {
        float d = ds_[t];
        if (d <= EPS_HARD*mabs) { N0 = t+1; conv = true; }
        if (d < STALL_IMP*dref) { dref = d; tref = t; }
        else if (t - tref >= STALL_WIN && t >= 12 && d < EPS_GATE*mabs) { N0 = t+1; conv = true; }
      }
      if (conv) break;
    }
    P.meta[0] = N0; P.metaF[1] = mabs;
  }
}

// merged: blocks 0..cap-1 = per-t derived quantities; last block = steady-state part A
__global__ __launch_bounds__(256) void k1x(KP P) {
  __shared__ __align__(16) float W0[LDW*NN], W1[LDW*NN], W2[LDW*NN], CH[LDW*NN];
  __shared__ float part[64], invd[64];
  const int tid = threadIdx.x;
  const int N0 = P.meta[0];
  if ((int)blockIdx.x == (int)gridDim.x - 1) {
    const float* fPssG = P.fP + (size_t)(N0-1)*4096;
    g2l(CH, fPssG);
    mm<0,0,0,LDW>(W1, P.A, NN, CH, LDW, nullptr, 0);
    mm<0,0,1,LDW>(W0, W1, LDW, P.AT, NN, P.Q, NN);            // pPss
    l2g(P.pPss, W0);
    mm<0,0,0,LDW>(W1, P.H, NN, W0, LDW, nullptr, 0);          // HP
    mm<0,0,1,LDW>(CH, W1, LDW, P.HT, NN, P.R, NN);            // S
    chol68<true>(CH, part, invd);
    if (tid == 0) { float s=0.f; for (int j=0;j<64;++j) s += part[j]; P.metaF[0] = s; }
    set_id(W0);
    tri_s2x2(CH, invd, W1, W0);                               // X ; Sinv
    l2g_T(P.Kss, W1);
    if (tid < 64) {
      float s = P.b[tid];
      for (int k = 0; k < 64; ++k) s -= W1[k*LDW + tid]*P.Hb[k];
      P.uss[tid] = s;
    }
    __syncthreads();
    l2g(P.Sinvss, W0);
    mm<1,0,2,LDW>(W0, W1, LDW, P.HA, NN, P.A, NN);            // F_ss
    l2g(P.Fss, W0);
    mm<0,0,0,LDW>(W1, P.A, NN, fPssG, NN, nullptr, 0);        // AF
    g2l(CH, P.pPss);
    chol68<false>(CH, part, invd);
    tri_solve2(CH, invd, W1, W1);                             // X2 = Css^T
    l2g(P.CsTss, W1);
    l2g_T(P.Css, W1);
    mm<1,0,0,LDW>(W2, W1, LDW, P.A, NN, nullptr, 0);          // Css*A
    store_id_sub(P.Dmss, W2);
    if (tid < 64) {
      float s = 0.f;
      for (int k = 0; k < 64; ++k) s += W1[k*LDW + tid]*P.b[k];
      P.dvnss[tid] = -s;
    }
    return;
  }
  const int t = blockIdx.x;
  if (t >= N0) return;
  mm<0,0,0,LDW>(W1, P.H, NN, P.pP + (size_t)t*4096, NN, nullptr, 0);
  mm<0,0,1,LDW>(CH, W1, LDW, P.HT, NN, P.R, NN);
  chol68<true>(CH, part, invd);
  if (tid == 0) { float s=0.f; for (int j=0;j<64;++j) s += part[j]; P.ld_pref[t] = s; }
  set_id(W0);
  tri_s2x2(CH, invd, W1, W0);
  l2g_T(P.Kp + (size_t)t*4096, W1);
  if (tid < 64) {
    float s = P.b[tid];
    for (int k = 0; k < 64; ++k) s -= W1[k*LDW + tid]*P.Hb[k];
    P.u_pref[t*64 + tid] = s;
  }
  __syncthreads();
  l2g(P.Sinvp + (size_t)t*4096, W0);
  mm<1,0,2,LDW>(W0, W1, LDW, P.HA, NN, P.A, NN);
  l2g(P.Fp + (size_t)t*4096, W0);
  mm<0,0,0,LDW>(W1, P.A, NN, P.fP + (size_t)t*4096, NN, nullptr, 0);
  g2l(CH, P.pP + (size_t)(t+1)*4096);
  chol68<false>(CH, part, invd);
  tri_solve2(CH, invd, W1, W1);                               // X2 = C_t^T
  l2g(P.CsTp + (size_t)t*4096, W1);
  l2g_T(P.Cp + (size_t)t*4096, W1);
  mm<1,0,0,LDW>(W0, W1, LDW, P.A, NN, nullptr, 0);            // C_t*A
  store_id_sub(P.Dmp + (size_t)t*4096, W0);
  if (tid < 64) {
    float s = 0.f;
    for (int k = 0; k < 64; ++k) s += W1[k*LDW + tid]*P.b[k];
    P.dvnp[t*64 + tid] = -s;
  }
}

// ---------------------------------------------------------------------------
// mega0 (after k1x): bid0 = k2b (serial fm prefix, LONG) ; bid1,2 = k1y roles;
// bid 3..3+NC-1 = k2a ; bid 3+NC.. = k1cI.  All depend only on k1x & earlier.
// ---------------------------------------------------------------------------
__global__ __launch_bounds__(256) void mega0(KP P) {
  __shared__ __align__(16) float W0[LDW*NN], W1[LDW*NN], W2[LDW*NN], W3[LDW*NN], W4[LDW*NN], CH[LDW*NN];
  __shared__ float xv[64], ty[64], hp[64], red[256];
  const int tid = threadIdx.x;
  const int bid = blockIdx.x;
  const int N0 = P.meta[0];
  const int PB = (N0 + LCH - 1)/LCH;
  if (bid == 0) {
    // ---- k2b: sequential fm prefix; seeds scanF0[PB] ----
    const int PE = PB*LCH;
    if (tid < 64) xv[tid] = P.pm0[tid];
    __syncthreads();
    matvec256(hp, P.H, xv, nullptr, red);
    if (tid < 64) ty[tid] = P.Y[tid] - hp[tid] - P.c[tid];
    __syncthreads();
    matvec256(xv, P.Kp, ty, xv, red);
    if (tid < 64) P.fm[tid] = xv[tid];
    __syncthreads();
    for (int t = 1; t < PE; ++t) {
      const float* Kt = (t < N0) ? P.Kp + (size_t)t*4096 : P.Kss;
      const float* Ft = (t < N0) ? P.Fp + (size_t)t*4096 : P.Fss;
      const float* ut = (t < N0) ? P.u_pref + t*64 : P.uss;
      if (tid < 64) ty[tid] = P.Y[(size_t)t*64+tid] - P.c[tid];
      __syncthreads();
      matvec2(xv, Ft, xv, Kt, ty, ut, red);
      if (tid < 64) P.fm[(size_t)t*64+tid] = xv[tid];
      __syncthreads();
    }
    if (tid < 64) P.scanF0[(size_t)PB*64 + tid] = xv[tid];
  } else if (bid <= 2) {
    // ---- k1y roles ----
    const float* fPssG = P.fP + (size_t)(N0-1)*4096;
    if (bid == 1) {
      mm2<0,0,0,LDW, 0,0,0,LDW>(W1, P.Css,NN, P.Css,NN, nullptr,0,
                                W4, P.Fss,NN, P.Fss,NN, nullptr,0);   // C2 ; F2
      l2g(P.Pw2, W1);
      mm2<0,0,0,LDW, 0,0,0,LDW>(W2, W1,LDW, W1,LDW, nullptr,0,
                                W3, W4,LDW, W4,LDW, nullptr,0);       // C4 ; F4
      l2g(P.Pw4, W2);
      mm2<0,0,0,LDW, 0,0,0,LDW>(W0, W2,LDW, W2,LDW, nullptr,0,
                                W4, W3,LDW, W3,LDW, nullptr,0);       // C8 ; F8
      l2g(P.Pw8, W0);
      mm2<0,0,0,LDW, 0,0,0,LDW>(W1, W0,LDW, W0,LDW, nullptr,0,
                                W3, W4,LDW, W4,LDW, nullptr,0);       // C16 ; F16
      l2g(P.Pw16, W1);
      mm2<0,0,0,LDW, 0,0,0,LDW>(W2, W1,LDW, W1,LDW, nullptr,0,
                                W4, W3,LDW, W3,LDW, nullptr,0);       // C32 ; F32
      l2g2(P.Cpow32, W2, P.Fpow, W4);
      mm2<0,0,0,LDW, 0,0,0,LDW>(W0, W2,LDW, W2,LDW, nullptr,0,
                                W3, W4,LDW, W4,LDW, nullptr,0);       // C64 ; F64
      l2g2(P.Pw64, W0, P.FpwHi, W3);
      mm2<0,0,0,LDW, 0,0,0,LDW>(W1, W0,LDW, W0,LDW, nullptr,0,
                                W4, W3,LDW, W3,LDW, nullptr,0);       // C128 ; F128
      l2g2(P.Pw128, W1, P.FpwHi + 4096, W4);
      mm2<0,0,0,LDW, 0,0,0,LDW>(W2, W1,LDW, W1,LDW, nullptr,0,
                                W3, W4,LDW, W4,LDW, nullptr,0);       // C256 ; F256
      l2g2(P.CpwHi, W2, P.FpwHi + 2*4096, W3);
      mm2<0,0,0,LDW, 0,0,0,LDW>(W0, W2,LDW, W2,LDW, nullptr,0,
                                W4, W3,LDW, W3,LDW, nullptr,0);       // C512 ; F512
      l2g2(P.CpwHi + 4096, W0, P.FpwHi + 3*4096, W4);
      mm2<0,0,0,LDW, 0,0,0,LDW>(W1, W0,LDW, W0,LDW, nullptr,0,
                                W3, W4,LDW, W4,LDW, nullptr,0);       // C1024 ; F1024
      l2g2(P.CpwHi + 2*4096, W1, P.FpwHi + 4*4096, W3);
      mm2<0,0,0,LDW, 0,0,0,LDW>(W2, W1,LDW, W1,LDW, nullptr,0,
                                W4, W3,LDW, W3,LDW, nullptr,0);       // C2048 ; F2048
      l2g2(P.CpwHi + 3*4096, W2, P.FpwHi + 5*4096, W4);
      mm<0,0,0,LDW>(W0, P.Pw16, NN, P.Pw8, NN, nullptr, 0);           // C24
      mm<0,0,0,LDW>(W1, W0, LDW, P.Pw4, NN, nullptr, 0);              // C28
      mm<0,0,0,LDW>(W2, W1, LDW, P.Pw2, NN, nullptr, 0);              // C30
      mm<0,0,0,LDW>(W0, W2, LDW, P.Css, NN, nullptr, 0);              // C31
      l2g(P.Cpow31, W0);
    } else {
      g2l(W1, P.Css);
      g2l(W2, P.CsTss);
      g2l(W0, P.pPss);
      mm<0,0,0,LDW>(CH, W1, LDW, W0, LDW, nullptr, 0);                // C*pPss
      mm<0,0,2,LDW>(W0, CH, LDW, W2, LDW, fPssG, NN);                 // X = fPss - (C pPss) C'
      float *m1 = W1, *m2 = W2, *t1 = W3, *t2 = W4;
      for (int it = 0; it < 7; ++it) {
        mm2<0,0,0,LDW, 0,0,0,LDW>(CH, m1,LDW, W0,LDW, nullptr,0,
                                  t1, m1,LDW, m1,LDW, nullptr,0);     // M*X ; M^2
        mm2<0,0,1,LDW, 0,0,0,LDW>(W0, CH,LDW, m2,LDW, W0,LDW,
                                  t2, m2,LDW, m2,LDW, nullptr,0);     // X += (MX)M' ; M'^2
        float* tmp = m1; m1 = t1; t1 = tmp;
        tmp = m2; m2 = t2; t2 = tmp;
      }
      l2g(P.sPss, W0);
      rsub_store(P.E0g, fPssG, W0);
    }
  } else if (bid < 3 + P.NC) {
    // ---- k2a: steady-chunk local pass ----
    const int c = bid - 3;
    if (c < PB) return;
    if (tid < 64) xv[tid] = 0.f;
    __syncthreads();
    for (int s = 0; s < LCH; ++s) {
      int t = c*LCH + s;
      if (tid < 64) ty[tid] = P.Y[(size_t)t*64+tid] - P.c[tid];
      __syncthreads();
      matvec2(xv, P.Fss, xv, P.Kss, ty, P.uss, red);
    }
    if (tid < 64) P.scanF0[(size_t)(c+1)*64 + tid] = xv[tid];
  } else {
    // ---- k1cI: smoothed-cov scan init ----
    const int t = bid - 3 - P.NC;
    if (t >= N0) return;
    const float* Cg = P.Cp + (size_t)t*4096;
    for (int e = tid*4; e < 4096; e += 1024)
      *(float4*)(P.scM0 + (size_t)t*4096 + e) = *(const float4*)(Cg + e);
    mm<0,0,0,LDW>(W1, Cg, NN, P.pP + (size_t)(t+1)*4096, NN, nullptr, 0);
    mm<0,0,2,NN>(P.scG0 + (size_t)t*4096, W1, LDW,
                 P.CsTp + (size_t)t*4096, NN, P.fP + (size_t)t*4096, NN);
  }
}

// megaL (level d < 7): bid<cap = k1cL level d ; rest = k2s level d
__global__ __launch_bounds__(256) void megaL(KP P, int d) {
  __shared__ __align__(16) float W1[LDW*NN];
  __shared__ float xv[64];
  const int tid = threadIdx.x;
  const int bid = blockIdx.x;
  const int cap = P.N0cap;
  const int N0 = P.meta[0];
  if (bid < cap) {
    const int t = bid;
    if (t >= N0) return;
    const int step = 1 << d, sidx = d & 1;
    const float* Msrc = sidx ? P.scM1 : P.scM0;
    const float* Gsrc = sidx ? P.scG1 : P.scG0;
    float* Mdst = sidx ? P.scM0 : P.scM1;
    float* Gdst = sidx ? P.scG0 : P.scG1;
    const int s = t + step;
    if (s >= N0) {
      for (int e = tid*4; e < 4096; e += 1024) {
        *(float4*)(Mdst + (size_t)t*4096 + e) = *(const float4*)(Msrc + (size_t)t*4096 + e);
        *(float4*)(Gdst + (size_t)t*4096 + e) = *(const float4*)(Gsrc + (size_t)t*4096 + e);
      }
      return;
    }
    const float* Mt = Msrc + (size_t)t*4096;
    mm2<0,0,0,LDW, 0,0,0,NN>(W1, Mt,NN, Gsrc + (size_t)s*4096,NN, nullptr,0,
                             Mdst + (size_t)t*4096, Mt,NN, Msrc + (size_t)s*4096,NN, nullptr,0);
    mm<0,1,1,NN>(Gdst + (size_t)t*4096, W1, LDW, Mt, NN, Gsrc + (size_t)t*4096, NN);
  } else {
    // k2s level d (forward chunk-carry)
    const int c = bid - cap;
    const int PB = (N0 + LCH - 1)/LCH;
    if (c < PB) return;
    const int sidx = d & 1;
    const float* src = sidx ? P.scanF1 : P.scanF0;
    float* dst = sidx ? P.scanF0 : P.scanF1;
    const int off = 1 << d;
    const int r = tid;
    if (c - off >= PB) {
      if (r < 64) xv[r] = src[(size_t)(c-off)*64 + r];
      __syncthreads();
      if (r < 64) {
        const float* M = (d == 0) ? P.Fpow : P.FpwHi + (size_t)(d-1)*4096;
        const float* Mr = M + r*64;
        float s = src[(size_t)c*64 + r];
        for (int k = 0; k < 64; k += 4)
          s += Mr[k]*xv[k] + Mr[k+1]*xv[k+1] + Mr[k+2]*xv[k+2] + Mr[k+3]*xv[k+3];
        dst[(size_t)c*64 + r] = s;
      }
    } else {
      if (r < 64) dst[(size_t)c*64 + r] = src[(size_t)c*64 + r];
    }
  }
}

// megaL7: bid<NC = k2c (steady-chunk replay, LONG) ; rest = k1cL level 7
__global__ __launch_bounds__(256) void megaL7(KP P) {
  __shared__ __align__(16) float W1[LDW*NN];
  __shared__ float xv[64], ty[64], red[256];
  const int tid = threadIdx.x;
  const int bid = blockIdx.x;
  const int N0 = P.meta[0];
  const int PB = (N0 + LCH - 1)/LCH;
  if (bid < P.NC) {
    const int c = bid;
    if (c < PB) return;
    if (tid < 64) xv[tid] = P.scanF1[(size_t)c*64 + tid];
    __syncthreads();
    for (int s = 0; s < LCH; ++s) {
      int t = c*LCH + s;
      if (tid < 64) ty[tid] = P.Y[(size_t)t*64+tid] - P.c[tid];
      __syncthreads();
      matvec2(xv, P.Fss, xv, P.Kss, ty, P.uss, red);
      if (tid < 64) P.fm[(size_t)t*64+tid] = xv[tid];
      __syncthreads();
    }
  } else {
    const int t = bid - P.NC;
    if (t >= N0) return;
    const int step = 128, sidx = 1;
    const float* Msrc = sidx ? P.scM1 : P.scM0;
    const float* Gsrc = sidx ? P.scG1 : P.scG0;
    float* Mdst = sidx ? P.scM0 : P.scM1;
    float* Gdst = sidx ? P.scG0 : P.scG1;
    const int s = t + step;
    if (s >= N0) {
      for (int e = tid*4; e < 4096; e += 1024) {
        *(float4*)(Mdst + (size_t)t*4096 + e) = *(const float4*)(Msrc + (size_t)t*4096 + e);
        *(float4*)(Gdst + (size_t)t*4096 + e) = *(const float4*)(Gsrc + (size_t)t*4096 + e);
      }
      return;
    }
    const float* Mt = Msrc + (size_t)t*4096;
    mm2<0,0,0,LDW, 0,0,0,NN>(W1, Mt,NN, Gsrc + (size_t)s*4096,NN, nullptr,0,
                             Mdst + (size_t)t*4096, Mt,NN, Msrc + (size_t)s*4096,NN, nullptr,0);
    mm<0,1,1,NN>(Gdst + (size_t)t*4096, W1, LDW, Mt, NN, Gsrc + (size_t)t*4096, NN);
  }
}

// mega2: bid<NC = k3a (LONG) ; next T = kTail ; next cap = k1cF ; last T = k5
__global__ __launch_bounds__(256) void mega2(KP P) {
  __shared__ __align__(16) float W0[LDW*NN], W1[LDW*NN], W2[LDW*NN];
  __shared__ float sv[64], fmv[64], red[256];
  const int tid = threadIdx.x;
  const int bid = blockIdx.x;
  const int NC = P.NC, cap = P.N0cap, T = P.T;
  const int N0 = P.meta[0];
  const int PB = (N0 + LCH - 1)/LCH;
  if (bid < NC) {
    // ---- k3a: backward local pass ----
    const int c = bid;
    if (c < PB) return;
    if (tid < 64) sv[tid] = 0.f;
    __syncthreads();
    int hi = (c == NC-1) ? T-2 : c*LCH + LCH - 1;
    for (int t = hi; t >= c*LCH; --t) {
      if (tid < 64) fmv[tid] = P.fm[(size_t)t*64+tid];
      __syncthreads();
      matvec2(sv, P.Css, sv, P.Dmss, fmv, P.dvnss, red);
    }
    if (c == NC-1) {
      if (tid < 64) fmv[tid] = P.fm[(size_t)(T-1)*64 + tid];
      __syncthreads();
      matvec256(sv, P.Cpow31, fmv, sv, red);     // q = Cpow31*fm[T-1] + ub
    }
    if (tid < 64) P.scanB0[(size_t)c*64 + tid] = sv[tid];
  } else if (bid < NC + T) {
    // ---- kTail: steady middle + closed-form tail of smoothed covs ----
    const int t = bid - NC;
    if (t < N0) return;
    float* dst = P.out_cov + (size_t)t*4096;
    if (t < T - N1CAP) {
      for (int e = tid*4; e < 4096; e += 1024)
        *(float4*)(dst+e) = *(const float4*)(P.sPss + e);
      return;
    }
    const int k = T - 1 - t;
    if (k == 0) {
      const float* src = P.fP + (size_t)(N0-1)*4096;
      for (int e = tid*4; e < 4096; e += 1024)
        *(float4*)(dst+e) = *(const float4*)(src+e);
      return;
    }
    const float* pw[8] = {P.Css, P.Pw2, P.Pw4, P.Pw8, P.Pw16, P.Cpow32, P.Pw64, P.Pw128};
    int b = __ffs(k) - 1;
    g2l(W1, pw[b]);
    float* cur = W1; float* oth = W0;
    for (int j = b+1; j < 8; ++j) {
      if ((k >> j) & 1) {
        mm<0,0,0,LDW>(oth, pw[j], NN, cur, LDW, nullptr, 0);
        float* tmp = cur; cur = oth; oth = tmp;
      }
    }
    mm<0,0,0,LDW>(W2, cur, LDW, P.E0g, NN, nullptr, 0);
    mm<0,1,1,LDW>(oth, W2, LDW, cur, LDW, P.sPss, NN);
    l2g(dst, oth);
  } else if (bid < NC + T + cap) {
    // ---- k1cF: smoothed-cov prefix finalize ----
    const int t = bid - NC - T;
    if (t >= N0) return;
    const float* Mt = P.scM0 + (size_t)t*4096;
    mm<0,0,0,LDW>(W1, Mt, NN, P.sPss, NN, nullptr, 0);
    mm<0,1,1,NN>(P.out_cov + (size_t)t*4096, W1, LDW, Mt, NN,
                 P.scG0 + (size_t)t*4096, NN);
  } else {
    // ---- k5: per-t log-likelihood term (tid<64 active) ----
    const int t = bid - NC - T - cap;
    const int r = tid;
    if (t == 0) {
      if (r < 64) fmv[r] = P.pm0[r];      // fmv = pm vector
      __syncthreads();
    } else {
      if (r < 64) sv[r] = P.fm[(size_t)(t-1)*64 + r];
      __syncthreads();
      if (r < 64) {
        float s = P.b[r];
        const float* Ar = P.A + r*64;
        for (int k = 0; k < 64; k += 4)
          s += Ar[k]*sv[k] + Ar[k+1]*sv[k+1] + Ar[k+2]*sv[k+2] + Ar[k+3]*sv[k+3];
        fmv[r] = s;
      }
      __syncthreads();
    }
    float qq = 0.f;
    if (r < 64) {
      float rr = P.Y[(size_t)t*64 + r] - P.c[r];
      const float* Hr = P.H + r*64;
      for (int k = 0; k < 64; ++k) rr -= Hr[k]*fmv[k];
      sv[r] = rr;
    }
    __syncthreads();
    if (r < 64) {
      const float* Sv = ((t < N0) ? P.Sinvp + (size_t)t*4096 : P.Sinvss) + r*64;
      float wv = 0.f;
      for (int k = 0; k < 64; ++k) wv += Sv[k]*sv[k];
      qq = sv[r]*wv;
      #pragma unroll
      for (int off = 32; off > 0; off >>= 1) qq += __shfl_xor(qq, off, 64);
      if (r == 0) {
        float ldt = (t < N0) ? P.ld_pref[t] : P.metaF[0];
        P.llbuf[t] = -58.8120661250990555 - (double)ldt - 0.5*(double)qq;
      }
    }
  }
}

// backward chunk-carry suffix-scan level j: S[c] += C^(32*2^j) * S[c+2^j]
__global__ __launch_bounds__(64) void k3s(KP P, int j) {
  const int c = blockIdx.x;
  const int N0 = P.meta[0];
  const int PB = (N0 + LCH - 1)/LCH;
  if (c < PB) return;
  const int sidx = j & 1;
  const float* src = sidx ? P.scanB1 : P.scanB0;
  float* dst = sidx ? P.scanB0 : P.scanB1;
  const int off = 1 << j;
  const int r = threadIdx.x;
  float base = src[(size_t)c*64 + r];
  if (c + off <= P.NC - 1) {
    __shared__ float xv[64];
    xv[r] = src[(size_t)(c+off)*64 + r];
    __syncthreads();
    const float* M;
    if (j == 0) M = P.Cpow32;
    else if (j == 1) M = P.Pw64;
    else if (j == 2) M = P.Pw128;
    else M = P.CpwHi + (size_t)(j-3)*4096;
    const float* Mr = M + r*64;
    float s = base;
    for (int k = 0; k < 64; k += 4)
      s += Mr[k]*xv[k] + Mr[k+1]*xv[k+1] + Mr[k+2]*xv[k+2] + Mr[k+3]*xv[k+3];
    dst[(size_t)c*64 + r] = s;
  } else {
    dst[(size_t)c*64 + r] = base;
  }
}

// mega3: bid0 = k3b (LONG) ; bid 1..NC = k3c ; last = k6
__global__ __launch_bounds__(256) void mega3(KP P) {
  __shared__ float sv[64], fmv[64], red[256];
  __shared__ double rd[256];
  const int tid = threadIdx.x;
  const int bid = blockIdx.x;
  const int N0 = P.meta[0];
  const int PB = (N0 + LCH - 1)/LCH;
  if (bid == 0) {
    // ---- k3b: sequential prefix ----
    const int PE = PB*LCH;
    if (tid < 64) {
      P.out_mean[(size_t)(P.T-1)*64+tid] = P.fm[(size_t)(P.T-1)*64+tid];
      sv[tid] = P.scanB1[(size_t)PB*64 + tid];
    }
    __syncthreads();
    for (int t = PE-1; t >= 0; --t) {
      const float* Ct  = (t < N0) ? P.Cp  + (size_t)t*4096 : P.Css;
      const float* Dmt = (t < N0) ? P.Dmp + (size_t)t*4096 : P.Dmss;
      const float* dvt = (t < N0) ? P.dvnp + t*64 : P.dvnss;
      if (tid < 64) fmv[tid] = P.fm[(size_t)t*64+tid];
      __syncthreads();
      matvec2(sv, Ct, sv, Dmt, fmv, dvt, red);
      if (tid < 64) P.out_mean[(size_t)t*64+tid] = sv[tid];
      __syncthreads();
    }
  } else if (bid <= P.NC) {
    // ---- k3c: steady-chunk replay ----
    const int c = bid - 1;
    if (c < PB) return;
    if (tid < 64) {
      sv[tid] = (c == P.NC-1) ? P.fm[(size_t)(P.T-1)*64+tid]
                              : P.scanB1[(size_t)(c+1)*64 + tid];
    }
    __syncthreads();
    int hi = (c == P.NC-1) ? P.T-2 : c*LCH + LCH - 1;
    for (int t = hi; t >= c*LCH; --t) {
      if (tid < 64) fmv[tid] = P.fm[(size_t)t*64+tid];
      __syncthreads();
      matvec2(sv, P.Css, sv, P.Dmss, fmv, P.dvnss, red);
      if (tid < 64) P.out_mean[(size_t)t*64+tid] = sv[tid];
      __syncthreads();
    }
  } else {
    // ---- k6: reduce ll ----
    double s = 0.0;
    for (int t = tid; t < P.T; t += 256) s += P.llbuf[t];
    rd[tid] = s; __syncthreads();
    #pragma unroll
    for (int off = 128; off > 0; off >>= 1) {
      if (tid < off) rd[tid] += rd[tid + off];
      __syncthreads();
    }
    if (tid == 0) P.out_ll[0] = (float)rd[0];
  }
}

// ---------- host ----------

extern "C" void kernel_launch(void* const* d_in, const int* in_sizes, int n_in,
                              void* d_out, int out_size, void* d_ws, size_t ws_size,
                              hipStream_t stream) {
  (void)n_in; (void)out_size;
  KP P;
  P.Y   = (const float*)d_in[0];
  P.A   = (const float*)d_in[1];
  P.b   = (const float*)d_in[2];
  P.Q   = (const float*)d_in[3];
  P.H   = (const float*)d_in[4];
  P.c   = (const float*)d_in[5];
  P.R   = (const float*)d_in[6];
  P.pm0 = (const float*)d_in[7];
  P.P0  = (const float*)d_in[8];
  const int T = in_sizes[0] / 64;
  const int NC = T / LCH;
  P.T = T; P.NC = NC;

  float* out = (float*)d_out;
  P.out_mean = out;
  P.out_cov  = out + (size_t)T*64;
  P.out_ll   = out + (size_t)T*64 + (size_t)T*4096;

  float* w = (float*)d_ws;
  size_t off = 0;
  auto alloc = [&](size_t n) { float* p = w + off; off += n; return p; };
  P.meta   = (int*)alloc(8);
  P.metaF  = alloc(8);
  P.llbuf  = (double*)alloc((size_t)2*T);
  P.fm     = alloc((size_t)T*64);
  P.AT = alloc(4096); P.HT = alloc(4096); P.HA = alloc(4096); P.Hb = alloc(64);
  P.Fss = alloc(4096); P.Kss = alloc(4096); P.Sinvss = alloc(4096);
  P.Css = alloc(4096); P.CsTss = alloc(4096); P.pPss = alloc(4096); P.sPss = alloc(4096);
  P.Fpow = alloc(4096); P.Cpow32 = alloc(4096); P.Cpow31 = alloc(4096); P.uss = alloc(64);
  P.Pw2 = alloc(4096); P.Pw4 = alloc(4096); P.Pw8 = alloc(4096); P.Pw16 = alloc(4096);
  P.Pw64 = alloc(4096); P.Pw128 = alloc(4096);
  P.FpwHi = alloc((size_t)6*4096); P.CpwHi = alloc((size_t)4*4096);
  P.Dmss = alloc(4096); P.dvnss = alloc(64);
  P.scanF0 = alloc((size_t)(NC+1)*64); P.scanF1 = alloc((size_t)(NC+1)*64);
  P.scanB0 = alloc((size_t)NC*64); P.scanB1 = alloc((size_t)NC*64);
  P.E0g = alloc(4096);
  P.EA = alloc((size_t)8*4096); P.EC = alloc((size_t)8*4096);
  P.EJ = alloc((size_t)8*4096); P.EL = alloc((size_t)8*4096);
  P.astat = alloc(256); P.dstat = alloc(256);
  size_t fixed = off;
  size_t per_t = 12*4096 + 128 + 1;
  size_t total_f = ws_size / 4;
  long long avail = (long long)total_f - (long long)fixed - 4096 - 64;
  int cap = (avail > 0) ? (int)(avail / (long long)per_t) : 8;
  if (cap > N0MAX) cap = N0MAX;
  if (cap < 8) cap = 8;
  P.N0cap = cap;
  P.ld_pref = alloc(cap);
  P.u_pref  = alloc((size_t)cap*64);
  P.dvnp    = alloc((size_t)cap*64);
  P.fP    = alloc((size_t)cap*4096);
  P.pP    = alloc((size_t)(cap+1)*4096);
  P.Kp    = alloc((size_t)cap*4096);
  P.Sinvp = alloc((size_t)cap*4096);
  P.Fp    = alloc((size_t)cap*4096);
  P.Cp    = alloc((size_t)cap*4096);
  P.CsTp  = alloc((size_t)cap*4096);
  P.Dmp   = alloc((size_t)cap*4096);
  P.scM0  = alloc((size_t)cap*4096);
  P.scM1  = alloc((size_t)cap*4096);
  P.scG0  = alloc((size_t)cap*4096);
  P.scG1  = alloc((size_t)cap*4096);

  k0<<<1, 256, 0, stream>>>(P);
  kA<<<1, 256, 0, stream>>>(P);
  kB<<<cap, 256, 0, stream>>>(P);
  kC<<<cap, 256, 0, stream>>>(P);
  kN<<<1, 256, 0, stream>>>(P);
  k1x<<<cap+1, 256, 0, stream>>>(P);
  mega0<<<3 + NC + cap, 256, 0, stream>>>(P);       // k2b ∥ k1y ∥ k2a ∥ k1cI
  for (int d = 0; d < 7; ++d)
    megaL<<<cap + NC, 256, 0, stream>>>(P, d);      // k1cL[d] ∥ k2s[d]
  megaL7<<<NC + cap, 256, 0, stream>>>(P);          // k2c ∥ k1cL[7]
  mega2<<<NC + T + cap + T, 256, 0, stream>>>(P);   // k3a ∥ kTail ∥ k1cF ∥ k5
  for (int j = 0; j < 7; ++j)
    k3s<<<NC, 64, 0, stream>>>(P, j);
  mega3<<<NC + 2, 256, 0, stream>>>(P);             // k3b ∥ k3c ∥ k6
}